// Round 7
// baseline (1522.903 us; speedup 1.0000x reference)
//
#include <hip/hip_runtime.h>
#include <hip/hip_bf16.h>

// ---------------- constants ----------------
constexpr int CB   = 2;     // batch
constexpr int CS   = 2048;  // seq
constexpr int CH   = 2048;  // hidden
constexpr int CNH  = 16;    // heads
constexpr int CHD  = 128;   // head dim
constexpr int CE   = 8;     // experts
constexpr int CI   = 2048;  // ffn inner
constexpr int CT   = CB * CS;      // 4096 tokens
constexpr int CQKV = 3 * CH;       // 6144

typedef __attribute__((ext_vector_type(8))) short short8;
typedef __attribute__((ext_vector_type(4))) float float4v;
typedef __attribute__((ext_vector_type(4))) unsigned short ushort4v;
typedef unsigned int uint32;

__device__ __forceinline__ float bf2f(unsigned short u) {
    union { unsigned int i; float f; } x; x.i = ((unsigned int)u) << 16; return x.f;
}
__device__ __forceinline__ unsigned short f2bf(float f) {
    union { float f; unsigned int i; } x; x.f = f;
    unsigned int r = x.i + 0x7fffu + ((x.i >> 16) & 1u);
    return (unsigned short)(r >> 16);
}
__device__ __forceinline__ uint32 packpair(uint32 r0, uint32 r1) {
    return __builtin_amdgcn_perm(r1, r0, 0x07060302u);
}
__device__ __forceinline__ uint32 rnebits(float f) {
    uint32 u = __float_as_uint(f);
    return u + 0x7fffu + ((u >> 16) & 1u);
}
__device__ __forceinline__ void split2(float f0, float f1, uint32& h, uint32& l) {
    uint32 r0 = rnebits(f0), r1 = rnebits(f1);
    h = packpair(r0, r1);
    float d0 = f0 - __uint_as_float(r0 & 0xffff0000u);
    float d1 = f1 - __uint_as_float(r1 & 0xffff0000u);
    l = packpair(rnebits(d0), rnebits(d1));
}
__device__ __forceinline__ void rne16_store(const float* fv, unsigned short* dst) {
    uint32 h[8];
    #pragma unroll
    for (int p = 0; p < 8; p++) h[p] = packpair(rnebits(fv[2 * p]), rnebits(fv[2 * p + 1]));
    ((uint4*)dst)[0] = make_uint4(h[0], h[1], h[2], h[3]);
    ((uint4*)dst)[1] = make_uint4(h[4], h[5], h[6], h[7]);
}

// ---------------- RMSNorm. MODE 0: hi/lo split out. MODE 1: bf16 out ----------
template<int MODE>
__global__ __launch_bounds__(256) void rmsnorm_k(const float* __restrict__ x,
                                                 const float* __restrict__ w,
                                                 unsigned short* __restrict__ o1,
                                                 unsigned short* __restrict__ o2) {
    const int row = blockIdx.x;
    const float* xr = x + (size_t)row * CH;
    const int base = threadIdx.x * 8;
    float4 v0 = *(const float4*)(xr + base);
    float4 v1 = *(const float4*)(xr + base + 4);
    float ss = v0.x*v0.x + v0.y*v0.y + v0.z*v0.z + v0.w*v0.w
             + v1.x*v1.x + v1.y*v1.y + v1.z*v1.z + v1.w*v1.w;
    #pragma unroll
    for (int o = 1; o < 64; o <<= 1) ss += __shfl_xor(ss, o);
    __shared__ float ps[4];
    if ((threadIdx.x & 63) == 0) ps[threadIdx.x >> 6] = ss;
    __syncthreads();
    const float scale = rsqrtf((ps[0] + ps[1] + ps[2] + ps[3]) / (float)CH + 1e-5f);
    float4 w0 = *(const float4*)(w + base);
    float4 w1 = *(const float4*)(w + base + 4);
    float r[8] = {v0.x * scale * w0.x, v0.y * scale * w0.y, v0.z * scale * w0.z, v0.w * scale * w0.w,
                  v1.x * scale * w1.x, v1.y * scale * w1.y, v1.z * scale * w1.z, v1.w * scale * w1.w};
    if (MODE == 1) {
        rne16_store(r, o1 + (size_t)row * CH + base);
    } else {
        uint32 h[4], l[4];
        #pragma unroll
        for (int p = 0; p < 4; p++) split2(r[2 * p], r[2 * p + 1], h[p], l[p]);
        *(uint4*)(o1 + (size_t)row * CH + base) = make_uint4(h[0], h[1], h[2], h[3]);
        *(uint4*)(o2 + (size_t)row * CH + base) = make_uint4(l[0], l[1], l[2], l[3]);
    }
}

// ---------------- RoPE table (replicating np's fp32 rounding) ----
__global__ void rope_tab_k(float2* __restrict__ tab) {
    int i = blockIdx.x * 256 + threadIdx.x;   // 2048*64
    int p = i >> 6, j = i & 63;
    double inv = pow(10000.0, -(double)j / 64.0);
    float invf = (float)inv;
    float angf = (float)p * invf;
    double da = (double)angf;
    tab[i] = make_float2((float)cos(da), (float)sin(da));
}

// ---------------- RoPE (in-place on hi/lo split q,k) ----------------
__global__ __launch_bounds__(256) void rope_k(unsigned short* __restrict__ qh,
                                              unsigned short* __restrict__ ql,
                                              const int* __restrict__ pos,
                                              const float2* __restrict__ tab) {
    int i = blockIdx.x * 256 + threadIdx.x;  // CT*16*64
    if (i >= CT * CNH * 64) return;
    int t = i >> 10, hj = i & 1023, hh = hj >> 6, j = hj & 63;
    float2 cs = tab[(size_t)pos[t] * 64 + j];
    unsigned short* qhp = qh + (size_t)t * CQKV + hh * CHD;
    unsigned short* qlp = ql + (size_t)t * CQKV + hh * CHD;
    #pragma unroll
    for (int s = 0; s < 2; s++) {
        unsigned short* hp = qhp + s * CH;   // q then k
        unsigned short* lp = qlp + s * CH;
        float x1 = bf2f(hp[j]) + bf2f(lp[j]);
        float x2 = bf2f(hp[j + 64]) + bf2f(lp[j + 64]);
        float y1 = x1 * cs.x - x2 * cs.y;
        float y2 = x2 * cs.x + x1 * cs.y;
        uint32 r1 = rnebits(y1), r2 = rnebits(y2);
        hp[j]      = (unsigned short)(r1 >> 16);
        hp[j + 64] = (unsigned short)(r2 >> 16);
        lp[j]      = f2bf(y1 - __uint_as_float(r1 & 0xffff0000u));
        lp[j + 64] = f2bf(y2 - __uint_as_float(r2 & 0xffff0000u));
    }
}

// ---------------- weight transpose+convert: src[K][N] f32 -> dst[N][K] bf16 ----
// NMAT=2: interleave two mats' columns (MoE w1/w3). NMAT=1: single.
template<int NMAT>
__global__ __launch_bounds__(256) void conv_k(const float* __restrict__ S0,
                                              const float* __restrict__ S1,
                                              unsigned short* __restrict__ D) {
    __shared__ float t[64][65];
    const int n0 = blockIdx.x * 64, k0 = blockIdx.y * 64, e = blockIdx.z;
    const size_t esrc = (size_t)e * 2048 * 2048;
    const int cc = threadIdx.x & 63, r4 = threadIdx.x >> 6;
    const int nl = threadIdx.x >> 2, q = threadIdx.x & 3;
    #pragma unroll
    for (int s = 0; s < NMAT; s++) {
        const float* S = s ? S1 : S0;
        __syncthreads();
        #pragma unroll
        for (int j = 0; j < 16; j++) {
            const int row = j * 4 + r4;
            t[cc][row] = S[esrc + (size_t)(k0 + row) * 2048 + n0 + cc];
        }
        __syncthreads();
        const int orow = (NMAT == 2) ? (2 * (n0 + nl) + s) : (n0 + nl);
        unsigned short* dp = D + (size_t)e * (NMAT * 2048) * 2048 + (size_t)orow * 2048 + k0 + q * 16;
        float fv[16];
        #pragma unroll
        for (int j = 0; j < 16; j++) fv[j] = t[nl][q * 16 + j];
        rne16_store(fv, dp);
    }
}

// ---------------- weight transpose + hi/lo SPLIT convert --------------------
// src[K][2048] f32 (z selects matrix for NMAT=3) -> Dh/Dl [z*2048+n][K] bf16
template<int NMAT>
__global__ __launch_bounds__(256) void convs_k(const float* __restrict__ S0,
                                               const float* __restrict__ S1,
                                               const float* __restrict__ S2,
                                               unsigned short* __restrict__ Dh,
                                               unsigned short* __restrict__ Dl) {
    __shared__ float t[64][65];
    const int n0 = blockIdx.x * 64, k0 = blockIdx.y * 64, z = blockIdx.z;
    const float* S = S0;
    if (NMAT == 3) S = (z == 0) ? S0 : ((z == 1) ? S1 : S2);
    const int cc = threadIdx.x & 63, r4 = threadIdx.x >> 6;
    #pragma unroll
    for (int j = 0; j < 16; j++) {
        const int row = j * 4 + r4;
        t[cc][row] = S[(size_t)(k0 + row) * 2048 + n0 + cc];
    }
    __syncthreads();
    const int nl = threadIdx.x >> 2, q = threadIdx.x & 3;
    float fv[16];
    #pragma unroll
    for (int j = 0; j < 16; j++) fv[j] = t[nl][q * 16 + j];
    uint32 h[8], l[8];
    #pragma unroll
    for (int p = 0; p < 8; p++) split2(fv[2 * p], fv[2 * p + 1], h[p], l[p]);
    const size_t off = (size_t)(z * 2048 + n0 + nl) * 2048 + k0 + q * 16;
    ((uint4*)(Dh + off))[0] = make_uint4(h[0], h[1], h[2], h[3]);
    ((uint4*)(Dh + off))[1] = make_uint4(h[4], h[5], h[6], h[7]);
    ((uint4*)(Dl + off))[0] = make_uint4(l[0], l[1], l[2], l[3]);
    ((uint4*)(Dl + off))[1] = make_uint4(l[4], l[5], l[6], l[7]);
}

// ---------------- precise split-bf16 GEMM, all operands pre-split bf16 ---------
// A: hi/lo [M][K]; B: hi/lo pre-transposed [N][K]. 3-product MFMA.
// MODE 0: out split hi/lo bf16 (QKV). MODE 1: out f32 + resid, dual-store (O-proj).
template<int MODE>
__global__ __launch_bounds__(256) void sgemm_k(
    const unsigned short* __restrict__ Ahg, const unsigned short* __restrict__ Alg, int lda,
    const unsigned short* __restrict__ Bhg, const unsigned short* __restrict__ Blg, int K,
    unsigned short* __restrict__ Ch, unsigned short* __restrict__ Cl,
    float* __restrict__ Cf, int ldc,
    const float* __restrict__ resid, float* __restrict__ C2) {
    __shared__ unsigned short AhS[128][40], AlS[128][40], BhS[128][40], BlS[128][40];
    const int mt = blockIdx.x, nt = blockIdx.y, tid = threadIdx.x;
    const int m0 = mt * 128;
    const int srow = tid >> 1, shalf = tid & 1;
    const unsigned short* ah = Ahg + (size_t)(m0 + srow) * lda + shalf * 16;
    const unsigned short* al = Alg + (size_t)(m0 + srow) * lda + shalf * 16;
    const unsigned short* bhp = Bhg + (size_t)(nt * 128 + srow) * K + shalf * 16;
    const unsigned short* blp = Blg + (size_t)(nt * 128 + srow) * K + shalf * 16;
    const int lane = tid & 63, lr = lane & 15, lg = lane >> 4;
    const int wr = (tid >> 7) & 1, wc = (tid >> 6) & 1;

    float4v acc[4][4];
    #pragma unroll
    for (int m = 0; m < 4; m++)
        #pragma unroll
        for (int n = 0; n < 4; n++) acc[m][n] = (float4v){0.f, 0.f, 0.f, 0.f};

    short8 rah0 = *(const short8*)(ah),     rah1 = *(const short8*)(ah + 8);
    short8 ral0 = *(const short8*)(al),     ral1 = *(const short8*)(al + 8);
    short8 rbh0 = *(const short8*)(bhp),    rbh1 = *(const short8*)(bhp + 8);
    short8 rbl0 = *(const short8*)(blp),    rbl1 = *(const short8*)(blp + 8);

    for (int k0 = 0; k0 < K; k0 += 32) {
        __syncthreads();
        *(short8*)(&AhS[srow][shalf * 16])     = rah0;
        *(short8*)(&AhS[srow][shalf * 16 + 8]) = rah1;
        *(short8*)(&AlS[srow][shalf * 16])     = ral0;
        *(short8*)(&AlS[srow][shalf * 16 + 8]) = ral1;
        *(short8*)(&BhS[srow][shalf * 16])     = rbh0;
        *(short8*)(&BhS[srow][shalf * 16 + 8]) = rbh1;
        *(short8*)(&BlS[srow][shalf * 16])     = rbl0;
        *(short8*)(&BlS[srow][shalf * 16 + 8]) = rbl1;
        if (k0 + 32 < K) {
            rah0 = *(const short8*)(ah + k0 + 32);  rah1 = *(const short8*)(ah + k0 + 40);
            ral0 = *(const short8*)(al + k0 + 32);  ral1 = *(const short8*)(al + k0 + 40);
            rbh0 = *(const short8*)(bhp + k0 + 32); rbh1 = *(const short8*)(bhp + k0 + 40);
            rbl0 = *(const short8*)(blp + k0 + 32); rbl1 = *(const short8*)(blp + k0 + 40);
        }
        __syncthreads();
        short8 fah[4], fal[4], fbh[4], fbl[4];
        #pragma unroll
        for (int m = 0; m < 4; m++) {
            fah[m] = *(const short8*)(&AhS[wr * 64 + m * 16 + lr][lg * 8]);
            fal[m] = *(const short8*)(&AlS[wr * 64 + m * 16 + lr][lg * 8]);
        }
        #pragma unroll
        for (int n = 0; n < 4; n++) {
            fbh[n] = *(const short8*)(&BhS[wc * 64 + n * 16 + lr][lg * 8]);
            fbl[n] = *(const short8*)(&BlS[wc * 64 + n * 16 + lr][lg * 8]);
        }
        #pragma unroll
        for (int n = 0; n < 4; n++)
            #pragma unroll
            for (int m = 0; m < 4; m++) {
                acc[m][n] = __builtin_amdgcn_mfma_f32_16x16x32_bf16(fal[m], fbh[n], acc[m][n], 0, 0, 0);
                acc[m][n] = __builtin_amdgcn_mfma_f32_16x16x32_bf16(fah[m], fbl[n], acc[m][n], 0, 0, 0);
                acc[m][n] = __builtin_amdgcn_mfma_f32_16x16x32_bf16(fah[m], fbh[n], acc[m][n], 0, 0, 0);
            }
    }
    #pragma unroll
    for (int m = 0; m < 4; m++) {
        const int rb = wr * 64 + m * 16 + lg * 4;
        #pragma unroll
        for (int n = 0; n < 4; n++) {
            const int ccol = nt * 128 + wc * 64 + n * 16 + lr;
            #pragma unroll
            for (int r = 0; r < 4; r++) {
                const size_t idx = (size_t)(m0 + rb + r) * ldc + ccol;
                if (MODE == 1) {
                    const float v = acc[m][n][r] + resid[idx];
                    Cf[idx] = v;
                    C2[idx] = v;
                } else {
                    const float v = acc[m][n][r];
                    uint32 rr = rnebits(v);
                    Ch[idx] = (unsigned short)(rr >> 16);
                    Cl[idx] = f2bf(v - __uint_as_float(rr & 0xffff0000u));
                }
            }
        }
    }
}

// ---------------- MoE GEMM: A bf16 row-major, B bf16 pre-transposed [Ne][K] ----
// Grid: x = nt, y = mt, z = e.
// MODE 2: up: A gathered by token list, B = wt13 interleaved, SwiGLU -> bf16 H
// MODE 3: down: A = Hbuf rows, epilogue gate*val atomicAdd into out
template<int MODE>
__global__ __launch_bounds__(256) void gemm_k(
    const unsigned short* __restrict__ A, int lda,
    const unsigned short* __restrict__ Bt, int K, int Ne,
    void* __restrict__ Cp, int ldc,
    const int* __restrict__ cnt, const int* __restrict__ tokl,
    const float* __restrict__ gatel, const int* __restrict__ pb) {
    __shared__ unsigned short As[128][40];
    __shared__ unsigned short Bs[128][40];
    const int nt = blockIdx.x, mt = blockIdx.y, e = blockIdx.z;
    const int m0 = mt * 128;
    const int c = cnt[e];
    if (m0 >= c) return;
    const int valid = (c - m0 < 128) ? (c - m0) : 128;
    const int tid = threadIdx.x;
    const int srow = tid >> 1, shalf = tid & 1;
    size_t gr;
    if (MODE == 2) {
        const int idx = m0 + (srow < valid ? srow : valid - 1);
        gr = (size_t)tokl[e * 4096 + idx];
    } else {
        const int rr = m0 + srow;
        gr = (size_t)(pb[e] + (rr < c ? rr : c - 1));
    }
    const unsigned short* a_src = A + gr * (size_t)lda + shalf * 16;
    const unsigned short* b_src = Bt + (size_t)e * Ne * K + (size_t)(nt * 128 + srow) * K + shalf * 16;
    const int lane = tid & 63, lr = lane & 15, lg = lane >> 4;
    const int wr = (tid >> 7) & 1, wc = (tid >> 6) & 1;

    float4v acc[4][4];
    #pragma unroll
    for (int m = 0; m < 4; m++)
        #pragma unroll
        for (int n = 0; n < 4; n++) acc[m][n] = (float4v){0.f, 0.f, 0.f, 0.f};

    short8 ra0 = *(const short8*)(a_src);
    short8 ra1 = *(const short8*)(a_src + 8);
    short8 rb0 = *(const short8*)(b_src);
    short8 rb1 = *(const short8*)(b_src + 8);

    for (int k0 = 0; k0 < K; k0 += 32) {
        __syncthreads();
        *(short8*)(&As[srow][shalf * 16])     = ra0;
        *(short8*)(&As[srow][shalf * 16 + 8]) = ra1;
        *(short8*)(&Bs[srow][shalf * 16])     = rb0;
        *(short8*)(&Bs[srow][shalf * 16 + 8]) = rb1;
        if (k0 + 32 < K) {
            ra0 = *(const short8*)(a_src + k0 + 32);
            ra1 = *(const short8*)(a_src + k0 + 40);
            rb0 = *(const short8*)(b_src + k0 + 32);
            rb1 = *(const short8*)(b_src + k0 + 40);
        }
        __syncthreads();
        short8 af[4], bf[4];
        #pragma unroll
        for (int m = 0; m < 4; m++) af[m] = *(const short8*)(&As[wr * 64 + m * 16 + lr][lg * 8]);
        #pragma unroll
        for (int n = 0; n < 4; n++) bf[n] = *(const short8*)(&Bs[wc * 64 + n * 16 + lr][lg * 8]);
        #pragma unroll
        for (int n = 0; n < 4; n++)
            #pragma unroll
            for (int m = 0; m < 4; m++)
                acc[m][n] = __builtin_amdgcn_mfma_f32_16x16x32_bf16(af[m], bf[n], acc[m][n], 0, 0, 0);
    }

    #pragma unroll
    for (int m = 0; m < 4; m++) {
        const int rb = wr * 64 + m * 16 + lg * 4;
        #pragma unroll
        for (int n = 0; n < 4; n++) {
            const int col = nt * 128 + wc * 64 + n * 16 + lr;
            #pragma unroll
            for (int r = 0; r < 4; r++) {
                const int row = rb + r;
                const float v = acc[m][n][r];
                if (MODE == 2) {
                    const float other = __shfl_xor(v, 1);
                    if (!(lr & 1) && row < valid) {
                        const float g1 = v, g3 = other;
                        const float hsw = (g1 / (1.f + __expf(-g1))) * g3;
                        ((unsigned short*)Cp)[(size_t)(pb[e] + m0 + row) * ldc + (col >> 1)] = f2bf(hsw);
                    }
                } else {
                    if (row < valid) {
                        const int t = tokl[e * 4096 + m0 + row];
                        const float g = gatel[e * 4096 + m0 + row];
                        atomicAdd(((float*)Cp) + (size_t)t * ldc + col, v * g);
                    }
                }
            }
        }
    }
}

// ---------------- flash attention, split-bf16 in/out ----------
__global__ __launch_bounds__(256) void attn_k(const unsigned short* __restrict__ qh,
                                              const unsigned short* __restrict__ ql,
                                              unsigned short* __restrict__ ch,
                                              unsigned short* __restrict__ cl) {
    __shared__ unsigned short Ksh[32][136], Ksl[32][136];
    __shared__ unsigned short Vth[128][40], Vtl[128][40];
    const int qb = blockIdx.x;
    const int h  = blockIdx.y;
    const int b  = blockIdx.z;
    const int tid = threadIdx.x;
    const int wave = tid >> 6, lane = tid & 63, lr = lane & 15, lg = lane >> 4;
    const size_t tb = (size_t)b * CS;
    const int q0 = qb * 64 + wave * 16;

    short8 qfh[4], qfl[4];
    {
        const size_t off = (tb + q0 + lr) * CQKV + h * CHD;
        #pragma unroll
        for (int c = 0; c < 4; c++) {
            qfh[c] = *(const short8*)(qh + off + c * 32 + lg * 8);
            qfl[c] = *(const short8*)(ql + off + c * 32 + lg * 8);
        }
    }
    float4v o[8];
    #pragma unroll
    for (int d = 0; d < 8; d++) o[d] = (float4v){0.f, 0.f, 0.f, 0.f};
    float m = -1e30f, l = 0.f;
    const float scl = 0.08838834764831845f;  // 1/sqrt(128)
    const int ntiles = (qb * 64 + 64 + 31) >> 5;
    const int kk = tid >> 3, slot = tid & 7;
    const int vd = tid & 127, vhalf = tid >> 7;

    for (int kt = 0; kt < ntiles; ++kt) {
        const int kv0 = kt * 32;
        __syncthreads();
        {
            const size_t koff = (tb + kv0 + kk) * CQKV + CH + h * CHD + slot * 16;
            *(short8*)(&Ksh[kk][slot * 16])     = *(const short8*)(qh + koff);
            *(short8*)(&Ksh[kk][slot * 16 + 8]) = *(const short8*)(qh + koff + 8);
            *(short8*)(&Ksl[kk][slot * 16])     = *(const short8*)(ql + koff);
            *(short8*)(&Ksl[kk][slot * 16 + 8]) = *(const short8*)(ql + koff + 8);
            // V: column-strip loads (transposed write)
            const size_t voff = (tb + kv0 + vhalf * 16) * CQKV + 2 * CH + h * CHD + vd;
            unsigned short th[16], tl[16];
            #pragma unroll
            for (int j = 0; j < 16; j++) {
                th[j] = qh[voff + (size_t)j * CQKV];
                tl[j] = ql[voff + (size_t)j * CQKV];
            }
            #pragma unroll
            for (int p = 0; p < 2; p++) {
                *(ushort4v*)(&Vth[vd][vhalf * 16 + p * 8])     = *(ushort4v*)(&th[p * 8]);
                *(ushort4v*)(&Vth[vd][vhalf * 16 + p * 8 + 4]) = *(ushort4v*)(&th[p * 8 + 4]);
                *(ushort4v*)(&Vtl[vd][vhalf * 16 + p * 8])     = *(ushort4v*)(&tl[p * 8]);
                *(ushort4v*)(&Vtl[vd][vhalf * 16 + p * 8 + 4]) = *(ushort4v*)(&tl[p * 8 + 4]);
            }
        }
        __syncthreads();

        float4v st0 = (float4v){0.f,0.f,0.f,0.f}, st1 = st0;
        #pragma unroll
        for (int c = 0; c < 4; c++) {
            short8 kah = *(const short8*)(&Ksh[lr][c * 32 + lg * 8]);
            short8 kal = *(const short8*)(&Ksl[lr][c * 32 + lg * 8]);
            short8 kbh = *(const short8*)(&Ksh[16 + lr][c * 32 + lg * 8]);
            short8 kbl = *(const short8*)(&Ksl[16 + lr][c * 32 + lg * 8]);
            st0 = __builtin_amdgcn_mfma_f32_16x16x32_bf16(kal, qfh[c], st0, 0, 0, 0);
            st0 = __builtin_amdgcn_mfma_f32_16x16x32_bf16(kah, qfl[c], st0, 0, 0, 0);
            st0 = __builtin_amdgcn_mfma_f32_16x16x32_bf16(kah, qfh[c], st0, 0, 0, 0);
            st1 = __builtin_amdgcn_mfma_f32_16x16x32_bf16(kbl, qfh[c], st1, 0, 0, 0);
            st1 = __builtin_amdgcn_mfma_f32_16x16x32_bf16(kbh, qfl[c], st1, 0, 0, 0);
            st1 = __builtin_amdgcn_mfma_f32_16x16x32_bf16(kbh, qfh[c], st1, 0, 0, 0);
        }
        float pv[8]; float pmax = -1e30f;
        const int qg = q0 + lr;
        #pragma unroll
        for (int f = 0; f < 2; f++) {
            #pragma unroll
            for (int r = 0; r < 4; r++) {
                const int kg = kv0 + f * 16 + lg * 4 + r;
                const float s = (kg <= qg) ? ((f ? st1[r] : st0[r]) * scl) : -1e30f;
                pv[f * 4 + r] = s;
                pmax = fmaxf(pmax, s);
            }
        }
        pmax = fmaxf(pmax, __shfl_xor(pmax, 16));
        pmax = fmaxf(pmax, __shfl_xor(pmax, 32));
        const float mnew = fmaxf(m, pmax);
        const float alpha = __expf(m - mnew);
        float sum = 0.f;
        #pragma unroll
        for (int i = 0; i < 8; i++) { const float p = __expf(pv[i] - mnew); pv[i] = p; sum += p; }
        sum += __shfl_xor(sum, 16);
        sum += __shfl_xor(sum, 32);
        l = l * alpha + sum;
        m = mnew;
        #pragma unroll
        for (int d = 0; d < 8; d++) o[d] *= alpha;
        short8 pfh, pfl;
        unsigned short* pfhp = (unsigned short*)&pfh;
        unsigned short* pflp = (unsigned short*)&pfl;
        #pragma unroll
        for (int j = 0; j < 8; j++) {
            const int srcl = (((lg & 1) * 2 + (j >> 2)) << 4) | lr;
            const float a0 = __shfl(pv[j & 3], srcl);
            const float a1 = __shfl(pv[4 + (j & 3)], srcl);
            const float sel = (lg >= 2) ? a1 : a0;
            uint32 r = rnebits(sel);
            pfhp[j] = (unsigned short)(r >> 16);
            float d = sel - __uint_as_float(r & 0xffff0000u);
            pflp[j] = (unsigned short)(rnebits(d) >> 16);
        }
        #pragma unroll
        for (int dt = 0; dt < 8; dt++) {
            short8 vh = *(const short8*)(&Vth[dt * 16 + lr][lg * 8]);
            short8 vl = *(const short8*)(&Vtl[dt * 16 + lr][lg * 8]);
            o[dt] = __builtin_amdgcn_mfma_f32_16x16x32_bf16(vl, pfh, o[dt], 0, 0, 0);
            o[dt] = __builtin_amdgcn_mfma_f32_16x16x32_bf16(vh, pfl, o[dt], 0, 0, 0);
            o[dt] = __builtin_amdgcn_mfma_f32_16x16x32_bf16(vh, pfh, o[dt], 0, 0, 0);
        }
    }
    const float inv = 1.f / l;
    const size_t coff = (tb + q0 + lr) * CH + h * CHD + lg * 4;
    #pragma unroll
    for (int dt = 0; dt < 8; dt++) {
        ushort4v wh, wl;
        #pragma unroll
        for (int r = 0; r < 4; r++) {
            const float v = o[dt][r] * inv;
            uint32 rr = rnebits(v);
            wh[r] = (unsigned short)(rr >> 16);
            wl[r] = f2bf(v - __uint_as_float(rr & 0xffff0000u));
        }
        *(ushort4v*)(ch + coff + dt * 16) = wh;
        *(ushort4v*)(cl + coff + dt * 16) = wl;
    }
}

// ---------------- router: fp64 logits + top2 ----------------
__global__ __launch_bounds__(64) void router_k(const float* __restrict__ x,
                                               const float* __restrict__ wn,
                                               const float* __restrict__ rw,
                                               int* __restrict__ cnt, int* __restrict__ tok,
                                               float* __restrict__ gate) {
    const int t = blockIdx.x;
    const int lane = threadIdx.x;
    const float* xr = x + (size_t)t * CH;
    double ss = 0.0;
    double acc[8] = {0,0,0,0,0,0,0,0};
    for (int i = lane * 4; i < CH; i += 256) {
        float4 v = *(const float4*)(xr + i);
        float4 wv = *(const float4*)(wn + i);
        ss += (double)v.x*v.x + (double)v.y*v.y + (double)v.z*v.z + (double)v.w*v.w;
        float xs[4] = {v.x, v.y, v.z, v.w};
        float ws4[4] = {wv.x, wv.y, wv.z, wv.w};
        #pragma unroll
        for (int dd = 0; dd < 4; dd++) {
            const double xn = (double)xs[dd] * (double)ws4[dd];
            const float* rr = rw + (size_t)(i + dd) * CE;
            #pragma unroll
            for (int e2 = 0; e2 < 8; e2++) acc[e2] += xn * (double)rr[e2];
        }
    }
    #pragma unroll
    for (int o = 1; o < 64; o <<= 1) ss += __shfl_xor(ss, o);
    #pragma unroll
    for (int e2 = 0; e2 < 8; e2++) {
        #pragma unroll
        for (int o = 1; o < 64; o <<= 1) acc[e2] += __shfl_xor(acc[e2], o);
    }
    if (lane == 0) {
        const double scale = rsqrt(ss / (double)CH + 1e-5);
        int e0 = 0;
        #pragma unroll
        for (int e2 = 1; e2 < 8; e2++) if (acc[e2] > acc[e0]) e0 = e2;
        int e1 = (e0 == 0) ? 1 : 0;
        #pragma unroll
        for (int e2 = 0; e2 < 8; e2++) if (e2 != e0 && acc[e2] > acc[e1]) e1 = e2;
        const double dl = scale * (acc[e1] - acc[e0]);   // <= 0
        const double p1r = exp(dl);
        const float g0 = (float)(1.0 / (1.0 + p1r));
        const float g1 = (float)(p1r / (1.0 + p1r));
        int pos0 = atomicAdd(&cnt[e0], 1);
        tok[e0 * 4096 + pos0] = t; gate[e0 * 4096 + pos0] = g0;
        int pos1 = atomicAdd(&cnt[e1], 1);
        tok[e1 * 4096 + pos1] = t; gate[e1 * 4096 + pos1] = g1;
    }
}

__global__ void prefix_k(const int* __restrict__ cnt, int* __restrict__ pb) {
    if (threadIdx.x == 0 && blockIdx.x == 0) {
        int s = 0;
        for (int e = 0; e < CE; e++) { pb[e] = s; s += cnt[e]; }
    }
}

// ---------------- launch ----------------
extern "C" void kernel_launch(void* const* d_in, const int* in_sizes, int n_in,
                              void* d_out, int out_size, void* d_ws, size_t ws_size,
                              hipStream_t stream) {
    (void)in_sizes; (void)n_in; (void)out_size; (void)ws_size;
    const float* hidden = (const float*)d_in[0];
    const int*   posids = (const int*)d_in[1];
    const float* rms1w  = (const float*)d_in[2];
    const float* rms2w  = (const float*)d_in[3];
    const float* qw     = (const float*)d_in[4];
    const float* kw     = (const float*)d_in[5];
    const float* vw     = (const float*)d_in[6];
    const float* ow     = (const float*)d_in[7];
    const float* rw     = (const float*)d_in[8];
    const float* w1     = (const float*)d_in[9];
    const float* w2     = (const float*)d_in[10];
    const float* w3     = (const float*)d_in[11];
    float* out = (float*)d_out;

    char* ws = (char*)d_ws;
    // lifetime overlays (bytes):
    // [0,16.8M):   h1h  -> woh+wol (after QKV) -> h2 (after O-proj)
    // [16.8,33.6M): h1l -> tok/gate/cnt/pb (after router setup)
    // [33.6,134.2M): qkvh+qkvl (dead after attn) -> wt13 -> wt2
    // [134.2,184.5M): wqkvh+wqkvl (dead after QKV) -> ctxh/ctxl at [134.2,167.8)
    // [167.8,201.4M): (tail of wqkvl, dead) -> res2 f32 -> Hbuf bf16
    // [201.4,202.4M): rope table
    unsigned short* h1h = (unsigned short*)ws;
    unsigned short* h1l = (unsigned short*)(ws + 16777216);
    unsigned short* woh = (unsigned short*)ws;
    unsigned short* wol = (unsigned short*)(ws + 8388608);
    unsigned short* h2  = (unsigned short*)ws;
    int*   tok  = (int*)(ws + 16777216);
    float* gate = (float*)(ws + 16777216 + 131072);
    int*   cnt  = (int*)(ws + 16777216 + 262144);
    int*   pb   = cnt + 16;
    unsigned short* qkvh = (unsigned short*)(ws + 33554432);
    unsigned short* qkvl = (unsigned short*)(ws + 83886080);
    unsigned short* wt13 = (unsigned short*)(ws + 33554432);
    unsigned short* wt2  = (unsigned short*)(ws + 33554432);
    unsigned short* wqkvh = (unsigned short*)(ws + 134217728);
    unsigned short* wqkvl = (unsigned short*)(ws + 134217728 + 25165824);
    unsigned short* ctxh = (unsigned short*)(ws + 134217728);
    unsigned short* ctxl = (unsigned short*)(ws + 150994944);
    float*          res2 = (float*)(ws + 167772160);
    unsigned short* Hbuf = (unsigned short*)(ws + 167772160);
    float2*         rtab = (float2*)(ws + 201326592);

    rope_tab_k<<<512, 256, 0, stream>>>(rtab);
    rmsnorm_k<0><<<CT, 256, 0, stream>>>(hidden, rms1w, h1h, h1l);
    // pre-split-transpose q|k|v weights -> [6144][2048] hi/lo bf16
    convs_k<3><<<dim3(32, 32, 3), 256, 0, stream>>>(qw, kw, vw, wqkvh, wqkvl);
    sgemm_k<0><<<dim3(32, 48), 256, 0, stream>>>(h1h, h1l, CH, wqkvh, wqkvl, CH,
                                                 qkvh, qkvl, nullptr, CQKV, nullptr, nullptr);
    rope_k<<<16384, 256, 0, stream>>>(qkvh, qkvl, posids, rtab);
    // o_w -> [2048][2048] hi/lo (overlays dead h1)
    convs_k<1><<<dim3(32, 32, 1), 256, 0, stream>>>(ow, nullptr, nullptr, woh, wol);
    attn_k<<<dim3(32, CNH, CB), 256, 0, stream>>>(qkvh, qkvl, ctxh, ctxl);
    sgemm_k<1><<<dim3(32, 16), 256, 0, stream>>>(ctxh, ctxl, CH, woh, wol, CH,
                                                 nullptr, nullptr, res2, CH, hidden, out);
    rmsnorm_k<1><<<CT, 256, 0, stream>>>(res2, rms2w, h2, nullptr);
    hipMemsetAsync(cnt, 0, 8 * sizeof(int), stream);
    router_k<<<CT, 64, 0, stream>>>(res2, rms2w, rw, cnt, tok, gate);
    prefix_k<<<1, 64, 0, stream>>>(cnt, pb);
    // convert w1,w3 -> wt13 (interleaved, transposed, bf16); overlays dead qkv
    conv_k<2><<<dim3(32, 32, CE), 256, 0, stream>>>(w1, w3, wt13);
    gemm_k<2><<<dim3(32, 32, CE), 256, 0, stream>>>(h2, CH, wt13, CH, 2 * CI, Hbuf, CI,
                                                    cnt, tok, gate, pb);
    // convert w2 -> wt2 (transposed, bf16); overlays dead wt13
    conv_k<1><<<dim3(32, 32, CE), 256, 0, stream>>>(w2, nullptr, wt2);
    gemm_k<3><<<dim3(16, 32, CE), 256, 0, stream>>>(Hbuf, CI, wt2, CI, CH, out, CH,
                                                    cnt, tok, gate, pb);
}

// Round 8
// 1439.999 us; speedup vs baseline: 1.0576x; 1.0576x over previous
//
#include <hip/hip_runtime.h>
#include <hip/hip_bf16.h>

// ---------------- constants ----------------
constexpr int CB   = 2;     // batch
constexpr int CS   = 2048;  // seq
constexpr int CH   = 2048;  // hidden
constexpr int CNH  = 16;    // heads
constexpr int CHD  = 128;   // head dim
constexpr int CE   = 8;     // experts
constexpr int CI   = 2048;  // ffn inner
constexpr int CT   = CB * CS;      // 4096 tokens
constexpr int CQKV = 3 * CH;       // 6144

typedef __attribute__((ext_vector_type(8))) short short8;
typedef __attribute__((ext_vector_type(4))) float float4v;
typedef __attribute__((ext_vector_type(4))) unsigned short ushort4v;
typedef unsigned int uint32;

__device__ __forceinline__ float bf2f(unsigned short u) {
    union { unsigned int i; float f; } x; x.i = ((unsigned int)u) << 16; return x.f;
}
__device__ __forceinline__ unsigned short f2bf(float f) {
    union { float f; unsigned int i; } x; x.f = f;
    unsigned int r = x.i + 0x7fffu + ((x.i >> 16) & 1u);
    return (unsigned short)(r >> 16);
}
__device__ __forceinline__ uint32 packpair(uint32 r0, uint32 r1) {
    return __builtin_amdgcn_perm(r1, r0, 0x07060302u);
}
__device__ __forceinline__ uint32 rnebits(float f) {
    uint32 u = __float_as_uint(f);
    return u + 0x7fffu + ((u >> 16) & 1u);
}
__device__ __forceinline__ void split2(float f0, float f1, uint32& h, uint32& l) {
    uint32 r0 = rnebits(f0), r1 = rnebits(f1);
    h = packpair(r0, r1);
    float d0 = f0 - __uint_as_float(r0 & 0xffff0000u);
    float d1 = f1 - __uint_as_float(r1 & 0xffff0000u);
    l = packpair(rnebits(d0), rnebits(d1));
}
__device__ __forceinline__ void rne16_store(const float* fv, unsigned short* dst) {
    uint32 h[8];
    #pragma unroll
    for (int p = 0; p < 8; p++) h[p] = packpair(rnebits(fv[2 * p]), rnebits(fv[2 * p + 1]));
    ((uint4*)dst)[0] = make_uint4(h[0], h[1], h[2], h[3]);
    ((uint4*)dst)[1] = make_uint4(h[4], h[5], h[6], h[7]);
}

// ---------------- RMSNorm. MODE 0: hi/lo split out. MODE 1: bf16 out ----------
template<int MODE>
__global__ __launch_bounds__(256) void rmsnorm_k(const float* __restrict__ x,
                                                 const float* __restrict__ w,
                                                 unsigned short* __restrict__ o1,
                                                 unsigned short* __restrict__ o2) {
    const int row = blockIdx.x;
    const float* xr = x + (size_t)row * CH;
    const int base = threadIdx.x * 8;
    float4 v0 = *(const float4*)(xr + base);
    float4 v1 = *(const float4*)(xr + base + 4);
    float ss = v0.x*v0.x + v0.y*v0.y + v0.z*v0.z + v0.w*v0.w
             + v1.x*v1.x + v1.y*v1.y + v1.z*v1.z + v1.w*v1.w;
    #pragma unroll
    for (int o = 1; o < 64; o <<= 1) ss += __shfl_xor(ss, o);
    __shared__ float ps[4];
    if ((threadIdx.x & 63) == 0) ps[threadIdx.x >> 6] = ss;
    __syncthreads();
    const float scale = rsqrtf((ps[0] + ps[1] + ps[2] + ps[3]) / (float)CH + 1e-5f);
    float4 w0 = *(const float4*)(w + base);
    float4 w1 = *(const float4*)(w + base + 4);
    float r[8] = {v0.x * scale * w0.x, v0.y * scale * w0.y, v0.z * scale * w0.z, v0.w * scale * w0.w,
                  v1.x * scale * w1.x, v1.y * scale * w1.y, v1.z * scale * w1.z, v1.w * scale * w1.w};
    if (MODE == 1) {
        rne16_store(r, o1 + (size_t)row * CH + base);
    } else {
        uint32 h[4], l[4];
        #pragma unroll
        for (int p = 0; p < 4; p++) split2(r[2 * p], r[2 * p + 1], h[p], l[p]);
        *(uint4*)(o1 + (size_t)row * CH + base) = make_uint4(h[0], h[1], h[2], h[3]);
        *(uint4*)(o2 + (size_t)row * CH + base) = make_uint4(l[0], l[1], l[2], l[3]);
    }
}

// ---------------- RoPE table (replicating np's fp32 rounding) ----
__global__ void rope_tab_k(float2* __restrict__ tab) {
    int i = blockIdx.x * 256 + threadIdx.x;   // 2048*64
    int p = i >> 6, j = i & 63;
    double inv = pow(10000.0, -(double)j / 64.0);
    float invf = (float)inv;
    float angf = (float)p * invf;
    double da = (double)angf;
    tab[i] = make_float2((float)cos(da), (float)sin(da));
}

// ---------------- RoPE (in-place on hi/lo split q,k) ----------------
__global__ __launch_bounds__(256) void rope_k(unsigned short* __restrict__ qh,
                                              unsigned short* __restrict__ ql,
                                              const int* __restrict__ pos,
                                              const float2* __restrict__ tab) {
    int i = blockIdx.x * 256 + threadIdx.x;  // CT*16*64
    if (i >= CT * CNH * 64) return;
    int t = i >> 10, hj = i & 1023, hh = hj >> 6, j = hj & 63;
    float2 cs = tab[(size_t)pos[t] * 64 + j];
    unsigned short* qhp = qh + (size_t)t * CQKV + hh * CHD;
    unsigned short* qlp = ql + (size_t)t * CQKV + hh * CHD;
    #pragma unroll
    for (int s = 0; s < 2; s++) {
        unsigned short* hp = qhp + s * CH;   // q then k
        unsigned short* lp = qlp + s * CH;
        float x1 = bf2f(hp[j]) + bf2f(lp[j]);
        float x2 = bf2f(hp[j + 64]) + bf2f(lp[j + 64]);
        float y1 = x1 * cs.x - x2 * cs.y;
        float y2 = x2 * cs.x + x1 * cs.y;
        uint32 r1 = rnebits(y1), r2 = rnebits(y2);
        hp[j]      = (unsigned short)(r1 >> 16);
        hp[j + 64] = (unsigned short)(r2 >> 16);
        lp[j]      = f2bf(y1 - __uint_as_float(r1 & 0xffff0000u));
        lp[j + 64] = f2bf(y2 - __uint_as_float(r2 & 0xffff0000u));
    }
}

// ---------------- weight transpose+convert: src[K][N] f32 -> dst[N][K] bf16 ----
template<int NMAT>
__global__ __launch_bounds__(256) void conv_k(const float* __restrict__ S0,
                                              const float* __restrict__ S1,
                                              unsigned short* __restrict__ D) {
    __shared__ float t[64][65];
    const int n0 = blockIdx.x * 64, k0 = blockIdx.y * 64, e = blockIdx.z;
    const size_t esrc = (size_t)e * 2048 * 2048;
    const int cc = threadIdx.x & 63, r4 = threadIdx.x >> 6;
    const int nl = threadIdx.x >> 2, q = threadIdx.x & 3;
    #pragma unroll
    for (int s = 0; s < NMAT; s++) {
        const float* S = s ? S1 : S0;
        __syncthreads();
        #pragma unroll
        for (int j = 0; j < 16; j++) {
            const int row = j * 4 + r4;
            t[cc][row] = S[esrc + (size_t)(k0 + row) * 2048 + n0 + cc];
        }
        __syncthreads();
        const int orow = (NMAT == 2) ? (2 * (n0 + nl) + s) : (n0 + nl);
        unsigned short* dp = D + (size_t)e * (NMAT * 2048) * 2048 + (size_t)orow * 2048 + k0 + q * 16;
        float fv[16];
        #pragma unroll
        for (int j = 0; j < 16; j++) fv[j] = t[nl][q * 16 + j];
        rne16_store(fv, dp);
    }
}

// ---------------- weight transpose + hi/lo SPLIT convert --------------------
template<int NMAT>
__global__ __launch_bounds__(256) void convs_k(const float* __restrict__ S0,
                                               const float* __restrict__ S1,
                                               const float* __restrict__ S2,
                                               unsigned short* __restrict__ Dh,
                                               unsigned short* __restrict__ Dl) {
    __shared__ float t[64][65];
    const int n0 = blockIdx.x * 64, k0 = blockIdx.y * 64, z = blockIdx.z;
    const float* S = S0;
    if (NMAT == 3) S = (z == 0) ? S0 : ((z == 1) ? S1 : S2);
    const int cc = threadIdx.x & 63, r4 = threadIdx.x >> 6;
    #pragma unroll
    for (int j = 0; j < 16; j++) {
        const int row = j * 4 + r4;
        t[cc][row] = S[(size_t)(k0 + row) * 2048 + n0 + cc];
    }
    __syncthreads();
    const int nl = threadIdx.x >> 2, q = threadIdx.x & 3;
    float fv[16];
    #pragma unroll
    for (int j = 0; j < 16; j++) fv[j] = t[nl][q * 16 + j];
    uint32 h[8], l[8];
    #pragma unroll
    for (int p = 0; p < 8; p++) split2(fv[2 * p], fv[2 * p + 1], h[p], l[p]);
    const size_t off = (size_t)(z * 2048 + n0 + nl) * 2048 + k0 + q * 16;
    ((uint4*)(Dh + off))[0] = make_uint4(h[0], h[1], h[2], h[3]);
    ((uint4*)(Dh + off))[1] = make_uint4(h[4], h[5], h[6], h[7]);
    ((uint4*)(Dl + off))[0] = make_uint4(l[0], l[1], l[2], l[3]);
    ((uint4*)(Dl + off))[1] = make_uint4(l[4], l[5], l[6], l[7]);
}

// ---------------- precise split-bf16 GEMM, all operands pre-split bf16 ---------
template<int MODE>
__global__ __launch_bounds__(256) void sgemm_k(
    const unsigned short* __restrict__ Ahg, const unsigned short* __restrict__ Alg, int lda,
    const unsigned short* __restrict__ Bhg, const unsigned short* __restrict__ Blg, int K,
    unsigned short* __restrict__ Ch, unsigned short* __restrict__ Cl,
    float* __restrict__ Cf, int ldc,
    const float* __restrict__ resid, float* __restrict__ C2) {
    __shared__ unsigned short AhS[128][40], AlS[128][40], BhS[128][40], BlS[128][40];
    const int mt = blockIdx.x, nt = blockIdx.y, tid = threadIdx.x;
    const int m0 = mt * 128;
    const int srow = tid >> 1, shalf = tid & 1;
    const unsigned short* ah = Ahg + (size_t)(m0 + srow) * lda + shalf * 16;
    const unsigned short* al = Alg + (size_t)(m0 + srow) * lda + shalf * 16;
    const unsigned short* bhp = Bhg + (size_t)(nt * 128 + srow) * K + shalf * 16;
    const unsigned short* blp = Blg + (size_t)(nt * 128 + srow) * K + shalf * 16;
    const int lane = tid & 63, lr = lane & 15, lg = lane >> 4;
    const int wr = (tid >> 7) & 1, wc = (tid >> 6) & 1;

    float4v acc[4][4];
    #pragma unroll
    for (int m = 0; m < 4; m++)
        #pragma unroll
        for (int n = 0; n < 4; n++) acc[m][n] = (float4v){0.f, 0.f, 0.f, 0.f};

    short8 rah0 = *(const short8*)(ah),     rah1 = *(const short8*)(ah + 8);
    short8 ral0 = *(const short8*)(al),     ral1 = *(const short8*)(al + 8);
    short8 rbh0 = *(const short8*)(bhp),    rbh1 = *(const short8*)(bhp + 8);
    short8 rbl0 = *(const short8*)(blp),    rbl1 = *(const short8*)(blp + 8);

    for (int k0 = 0; k0 < K; k0 += 32) {
        __syncthreads();
        *(short8*)(&AhS[srow][shalf * 16])     = rah0;
        *(short8*)(&AhS[srow][shalf * 16 + 8]) = rah1;
        *(short8*)(&AlS[srow][shalf * 16])     = ral0;
        *(short8*)(&AlS[srow][shalf * 16 + 8]) = ral1;
        *(short8*)(&BhS[srow][shalf * 16])     = rbh0;
        *(short8*)(&BhS[srow][shalf * 16 + 8]) = rbh1;
        *(short8*)(&BlS[srow][shalf * 16])     = rbl0;
        *(short8*)(&BlS[srow][shalf * 16 + 8]) = rbl1;
        if (k0 + 32 < K) {
            rah0 = *(const short8*)(ah + k0 + 32);  rah1 = *(const short8*)(ah + k0 + 40);
            ral0 = *(const short8*)(al + k0 + 32);  ral1 = *(const short8*)(al + k0 + 40);
            rbh0 = *(const short8*)(bhp + k0 + 32); rbh1 = *(const short8*)(bhp + k0 + 40);
            rbl0 = *(const short8*)(blp + k0 + 32); rbl1 = *(const short8*)(blp + k0 + 40);
        }
        __syncthreads();
        short8 fah[4], fal[4], fbh[4], fbl[4];
        #pragma unroll
        for (int m = 0; m < 4; m++) {
            fah[m] = *(const short8*)(&AhS[wr * 64 + m * 16 + lr][lg * 8]);
            fal[m] = *(const short8*)(&AlS[wr * 64 + m * 16 + lr][lg * 8]);
        }
        #pragma unroll
        for (int n = 0; n < 4; n++) {
            fbh[n] = *(const short8*)(&BhS[wc * 64 + n * 16 + lr][lg * 8]);
            fbl[n] = *(const short8*)(&BlS[wc * 64 + n * 16 + lr][lg * 8]);
        }
        #pragma unroll
        for (int n = 0; n < 4; n++)
            #pragma unroll
            for (int m = 0; m < 4; m++) {
                acc[m][n] = __builtin_amdgcn_mfma_f32_16x16x32_bf16(fal[m], fbh[n], acc[m][n], 0, 0, 0);
                acc[m][n] = __builtin_amdgcn_mfma_f32_16x16x32_bf16(fah[m], fbl[n], acc[m][n], 0, 0, 0);
                acc[m][n] = __builtin_amdgcn_mfma_f32_16x16x32_bf16(fah[m], fbh[n], acc[m][n], 0, 0, 0);
            }
    }
    #pragma unroll
    for (int m = 0; m < 4; m++) {
        const int rb = wr * 64 + m * 16 + lg * 4;
        #pragma unroll
        for (int n = 0; n < 4; n++) {
            const int ccol = nt * 128 + wc * 64 + n * 16 + lr;
            #pragma unroll
            for (int r = 0; r < 4; r++) {
                const size_t idx = (size_t)(m0 + rb + r) * ldc + ccol;
                if (MODE == 1) {
                    const float v = acc[m][n][r] + resid[idx];
                    Cf[idx] = v;
                    C2[idx] = v;
                } else {
                    const float v = acc[m][n][r];
                    uint32 rr = rnebits(v);
                    Ch[idx] = (unsigned short)(rr >> 16);
                    Cl[idx] = f2bf(v - __uint_as_float(rr & 0xffff0000u));
                }
            }
        }
    }
}

// ---------------- MoE GEMM: A bf16 row-major, B bf16 pre-transposed [Ne][K] ----
template<int MODE>
__global__ __launch_bounds__(256) void gemm_k(
    const unsigned short* __restrict__ A, int lda,
    const unsigned short* __restrict__ Bt, int K, int Ne,
    void* __restrict__ Cp, int ldc,
    const int* __restrict__ cnt, const int* __restrict__ tokl,
    const float* __restrict__ gatel, const int* __restrict__ pb) {
    __shared__ unsigned short As[128][40];
    __shared__ unsigned short Bs[128][40];
    const int nt = blockIdx.x, mt = blockIdx.y, e = blockIdx.z;
    const int m0 = mt * 128;
    const int c = cnt[e];
    if (m0 >= c) return;
    const int valid = (c - m0 < 128) ? (c - m0) : 128;
    const int tid = threadIdx.x;
    const int srow = tid >> 1, shalf = tid & 1;
    size_t gr;
    if (MODE == 2) {
        const int idx = m0 + (srow < valid ? srow : valid - 1);
        gr = (size_t)tokl[e * 4096 + idx];
    } else {
        const int rr = m0 + srow;
        gr = (size_t)(pb[e] + (rr < c ? rr : c - 1));
    }
    const unsigned short* a_src = A + gr * (size_t)lda + shalf * 16;
    const unsigned short* b_src = Bt + (size_t)e * Ne * K + (size_t)(nt * 128 + srow) * K + shalf * 16;
    const int lane = tid & 63, lr = lane & 15, lg = lane >> 4;
    const int wr = (tid >> 7) & 1, wc = (tid >> 6) & 1;

    float4v acc[4][4];
    #pragma unroll
    for (int m = 0; m < 4; m++)
        #pragma unroll
        for (int n = 0; n < 4; n++) acc[m][n] = (float4v){0.f, 0.f, 0.f, 0.f};

    short8 ra0 = *(const short8*)(a_src);
    short8 ra1 = *(const short8*)(a_src + 8);
    short8 rb0 = *(const short8*)(b_src);
    short8 rb1 = *(const short8*)(b_src + 8);

    for (int k0 = 0; k0 < K; k0 += 32) {
        __syncthreads();
        *(short8*)(&As[srow][shalf * 16])     = ra0;
        *(short8*)(&As[srow][shalf * 16 + 8]) = ra1;
        *(short8*)(&Bs[srow][shalf * 16])     = rb0;
        *(short8*)(&Bs[srow][shalf * 16 + 8]) = rb1;
        if (k0 + 32 < K) {
            ra0 = *(const short8*)(a_src + k0 + 32);
            ra1 = *(const short8*)(a_src + k0 + 40);
            rb0 = *(const short8*)(b_src + k0 + 32);
            rb1 = *(const short8*)(b_src + k0 + 40);
        }
        __syncthreads();
        short8 af[4], bf[4];
        #pragma unroll
        for (int m = 0; m < 4; m++) af[m] = *(const short8*)(&As[wr * 64 + m * 16 + lr][lg * 8]);
        #pragma unroll
        for (int n = 0; n < 4; n++) bf[n] = *(const short8*)(&Bs[wc * 64 + n * 16 + lr][lg * 8]);
        #pragma unroll
        for (int n = 0; n < 4; n++)
            #pragma unroll
            for (int m = 0; m < 4; m++)
                acc[m][n] = __builtin_amdgcn_mfma_f32_16x16x32_bf16(af[m], bf[n], acc[m][n], 0, 0, 0);
    }

    #pragma unroll
    for (int m = 0; m < 4; m++) {
        const int rb = wr * 64 + m * 16 + lg * 4;
        #pragma unroll
        for (int n = 0; n < 4; n++) {
            const int col = nt * 128 + wc * 64 + n * 16 + lr;
            #pragma unroll
            for (int r = 0; r < 4; r++) {
                const int row = rb + r;
                const float v = acc[m][n][r];
                if (MODE == 2) {
                    const float other = __shfl_xor(v, 1);
                    if (!(lr & 1) && row < valid) {
                        const float g1 = v, g3 = other;
                        const float hsw = (g1 / (1.f + __expf(-g1))) * g3;
                        ((unsigned short*)Cp)[(size_t)(pb[e] + m0 + row) * ldc + (col >> 1)] = f2bf(hsw);
                    }
                } else {
                    if (row < valid) {
                        const int t = tokl[e * 4096 + m0 + row];
                        const float g = gatel[e * 4096 + m0 + row];
                        atomicAdd(((float*)Cp) + (size_t)t * ldc + col, v * g);
                    }
                }
            }
        }
    }
}

// ---------------- flash attention, split-bf16, XCD-pinned + reg double-buffer --
__global__ __launch_bounds__(256) void attn_k(const unsigned short* __restrict__ qh,
                                              const unsigned short* __restrict__ ql,
                                              unsigned short* __restrict__ ch,
                                              unsigned short* __restrict__ cl) {
    __shared__ unsigned short Ksh[32][136], Ksl[32][136];
    __shared__ unsigned short Vth[128][40], Vtl[128][40];
    // XCD-pinned decode: all 32 qb-blocks of one (b,h) land on one XCD,
    // qb descending so the longest blocks start first.
    const int bid = blockIdx.x;          // 1024 blocks
    const int xcd = bid & 7, jj = bid >> 3;
    const int bh  = xcd * 4 + (jj >> 5);
    const int qb  = 31 - (jj & 31);
    const int h   = bh & 15, b = bh >> 4;
    const int tid = threadIdx.x;
    const int wave = tid >> 6, lane = tid & 63, lr = lane & 15, lg = lane >> 4;
    const size_t tb = (size_t)b * CS;
    const int q0 = qb * 64 + wave * 16;

    short8 qfh[4], qfl[4];
    {
        const size_t off = (tb + q0 + lr) * CQKV + h * CHD;
        #pragma unroll
        for (int c = 0; c < 4; c++) {
            qfh[c] = *(const short8*)(qh + off + c * 32 + lg * 8);
            qfl[c] = *(const short8*)(ql + off + c * 32 + lg * 8);
        }
    }
    float4v o[8];
    #pragma unroll
    for (int d = 0; d < 8; d++) o[d] = (float4v){0.f, 0.f, 0.f, 0.f};
    float m = -1e30f, l = 0.f;
    const float scl = 0.08838834764831845f;  // 1/sqrt(128)
    const int ntiles = 2 * (qb + 1);
    const int kk = tid >> 3, slot = tid & 7;
    const int vd = tid & 127, vhalf = tid >> 7;

    // prefetch registers for next K/V tile
    short8 pkh0, pkh1, pkl0, pkl1;
    unsigned short pth[16], ptl[16];
    {
        const size_t koff = (tb + kk) * CQKV + CH + h * CHD + slot * 16;
        pkh0 = *(const short8*)(qh + koff);
        pkh1 = *(const short8*)(qh + koff + 8);
        pkl0 = *(const short8*)(ql + koff);
        pkl1 = *(const short8*)(ql + koff + 8);
        const size_t voff = (tb + vhalf * 16) * CQKV + 2 * CH + h * CHD + vd;
        #pragma unroll
        for (int j = 0; j < 16; j++) {
            pth[j] = qh[voff + (size_t)j * CQKV];
            ptl[j] = ql[voff + (size_t)j * CQKV];
        }
    }

    for (int kt = 0; kt < ntiles; ++kt) {
        const int kv0 = kt * 32;
        __syncthreads();
        // store prefetched tile to LDS
        *(short8*)(&Ksh[kk][slot * 16])     = pkh0;
        *(short8*)(&Ksh[kk][slot * 16 + 8]) = pkh1;
        *(short8*)(&Ksl[kk][slot * 16])     = pkl0;
        *(short8*)(&Ksl[kk][slot * 16 + 8]) = pkl1;
        #pragma unroll
        for (int p = 0; p < 2; p++) {
            *(ushort4v*)(&Vth[vd][vhalf * 16 + p * 8])     = *(ushort4v*)(&pth[p * 8]);
            *(ushort4v*)(&Vth[vd][vhalf * 16 + p * 8 + 4]) = *(ushort4v*)(&pth[p * 8 + 4]);
            *(ushort4v*)(&Vtl[vd][vhalf * 16 + p * 8])     = *(ushort4v*)(&ptl[p * 8]);
            *(ushort4v*)(&Vtl[vd][vhalf * 16 + p * 8 + 4]) = *(ushort4v*)(&ptl[p * 8 + 4]);
        }
        // issue next tile's global loads (latency hides under compute below)
        if (kt + 1 < ntiles) {
            const int nv0 = kv0 + 32;
            const size_t koff = (tb + nv0 + kk) * CQKV + CH + h * CHD + slot * 16;
            pkh0 = *(const short8*)(qh + koff);
            pkh1 = *(const short8*)(qh + koff + 8);
            pkl0 = *(const short8*)(ql + koff);
            pkl1 = *(const short8*)(ql + koff + 8);
            const size_t voff = (tb + nv0 + vhalf * 16) * CQKV + 2 * CH + h * CHD + vd;
            #pragma unroll
            for (int j = 0; j < 16; j++) {
                pth[j] = qh[voff + (size_t)j * CQKV];
                ptl[j] = ql[voff + (size_t)j * CQKV];
            }
        }
        __syncthreads();

        float4v st0 = (float4v){0.f,0.f,0.f,0.f}, st1 = st0;
        #pragma unroll
        for (int c = 0; c < 4; c++) {
            short8 kah = *(const short8*)(&Ksh[lr][c * 32 + lg * 8]);
            short8 kal = *(const short8*)(&Ksl[lr][c * 32 + lg * 8]);
            short8 kbh = *(const short8*)(&Ksh[16 + lr][c * 32 + lg * 8]);
            short8 kbl = *(const short8*)(&Ksl[16 + lr][c * 32 + lg * 8]);
            st0 = __builtin_amdgcn_mfma_f32_16x16x32_bf16(kal, qfh[c], st0, 0, 0, 0);
            st0 = __builtin_amdgcn_mfma_f32_16x16x32_bf16(kah, qfl[c], st0, 0, 0, 0);
            st0 = __builtin_amdgcn_mfma_f32_16x16x32_bf16(kah, qfh[c], st0, 0, 0, 0);
            st1 = __builtin_amdgcn_mfma_f32_16x16x32_bf16(kbl, qfh[c], st1, 0, 0, 0);
            st1 = __builtin_amdgcn_mfma_f32_16x16x32_bf16(kbh, qfl[c], st1, 0, 0, 0);
            st1 = __builtin_amdgcn_mfma_f32_16x16x32_bf16(kbh, qfh[c], st1, 0, 0, 0);
        }
        float pv[8]; float pmax = -1e30f;
        const int qg = q0 + lr;
        #pragma unroll
        for (int f = 0; f < 2; f++) {
            #pragma unroll
            for (int r = 0; r < 4; r++) {
                const int kg = kv0 + f * 16 + lg * 4 + r;
                const float s = (kg <= qg) ? ((f ? st1[r] : st0[r]) * scl) : -1e30f;
                pv[f * 4 + r] = s;
                pmax = fmaxf(pmax, s);
            }
        }
        pmax = fmaxf(pmax, __shfl_xor(pmax, 16));
        pmax = fmaxf(pmax, __shfl_xor(pmax, 32));
        const float mnew = fmaxf(m, pmax);
        const float alpha = __expf(m - mnew);
        float sum = 0.f;
        #pragma unroll
        for (int i = 0; i < 8; i++) { const float p = __expf(pv[i] - mnew); pv[i] = p; sum += p; }
        sum += __shfl_xor(sum, 16);
        sum += __shfl_xor(sum, 32);
        l = l * alpha + sum;
        m = mnew;
        #pragma unroll
        for (int d = 0; d < 8; d++) o[d] *= alpha;
        short8 pfh, pfl;
        unsigned short* pfhp = (unsigned short*)&pfh;
        unsigned short* pflp = (unsigned short*)&pfl;
        #pragma unroll
        for (int j = 0; j < 8; j++) {
            const int srcl = (((lg & 1) * 2 + (j >> 2)) << 4) | lr;
            const float a0 = __shfl(pv[j & 3], srcl);
            const float a1 = __shfl(pv[4 + (j & 3)], srcl);
            const float sel = (lg >= 2) ? a1 : a0;
            uint32 r = rnebits(sel);
            pfhp[j] = (unsigned short)(r >> 16);
            float d = sel - __uint_as_float(r & 0xffff0000u);
            pflp[j] = (unsigned short)(rnebits(d) >> 16);
        }
        #pragma unroll
        for (int dt = 0; dt < 8; dt++) {
            short8 vh = *(const short8*)(&Vth[dt * 16 + lr][lg * 8]);
            short8 vl = *(const short8*)(&Vtl[dt * 16 + lr][lg * 8]);
            o[dt] = __builtin_amdgcn_mfma_f32_16x16x32_bf16(vl, pfh, o[dt], 0, 0, 0);
            o[dt] = __builtin_amdgcn_mfma_f32_16x16x32_bf16(vh, pfl, o[dt], 0, 0, 0);
            o[dt] = __builtin_amdgcn_mfma_f32_16x16x32_bf16(vh, pfh, o[dt], 0, 0, 0);
        }
    }
    const float inv = 1.f / l;
    const size_t coff = (tb + q0 + lr) * CH + h * CHD + lg * 4;
    #pragma unroll
    for (int dt = 0; dt < 8; dt++) {
        ushort4v wh, wl;
        #pragma unroll
        for (int r = 0; r < 4; r++) {
            const float v = o[dt][r] * inv;
            uint32 rr = rnebits(v);
            wh[r] = (unsigned short)(rr >> 16);
            wl[r] = f2bf(v - __uint_as_float(rr & 0xffff0000u));
        }
        *(ushort4v*)(ch + coff + dt * 16) = wh;
        *(ushort4v*)(cl + coff + dt * 16) = wl;
    }
}

// ---------------- router: fp64 logits + top2 ----------------
__global__ __launch_bounds__(64) void router_k(const float* __restrict__ x,
                                               const float* __restrict__ wn,
                                               const float* __restrict__ rw,
                                               int* __restrict__ cnt, int* __restrict__ tok,
                                               float* __restrict__ gate) {
    const int t = blockIdx.x;
    const int lane = threadIdx.x;
    const float* xr = x + (size_t)t * CH;
    double ss = 0.0;
    double acc[8] = {0,0,0,0,0,0,0,0};
    for (int i = lane * 4; i < CH; i += 256) {
        float4 v = *(const float4*)(xr + i);
        float4 wv = *(const float4*)(wn + i);
        ss += (double)v.x*v.x + (double)v.y*v.y + (double)v.z*v.z + (double)v.w*v.w;
        float xs[4] = {v.x, v.y, v.z, v.w};
        float ws4[4] = {wv.x, wv.y, wv.z, wv.w};
        #pragma unroll
        for (int dd = 0; dd < 4; dd++) {
            const double xn = (double)xs[dd] * (double)ws4[dd];
            const float* rr = rw + (size_t)(i + dd) * CE;
            #pragma unroll
            for (int e2 = 0; e2 < 8; e2++) acc[e2] += xn * (double)rr[e2];
        }
    }
    #pragma unroll
    for (int o = 1; o < 64; o <<= 1) ss += __shfl_xor(ss, o);
    #pragma unroll
    for (int e2 = 0; e2 < 8; e2++) {
        #pragma unroll
        for (int o = 1; o < 64; o <<= 1) acc[e2] += __shfl_xor(acc[e2], o);
    }
    if (lane == 0) {
        const double scale = rsqrt(ss / (double)CH + 1e-5);
        int e0 = 0;
        #pragma unroll
        for (int e2 = 1; e2 < 8; e2++) if (acc[e2] > acc[e0]) e0 = e2;
        int e1 = (e0 == 0) ? 1 : 0;
        #pragma unroll
        for (int e2 = 0; e2 < 8; e2++) if (e2 != e0 && acc[e2] > acc[e1]) e1 = e2;
        const double dl = scale * (acc[e1] - acc[e0]);   // <= 0
        const double p1r = exp(dl);
        const float g0 = (float)(1.0 / (1.0 + p1r));
        const float g1 = (float)(p1r / (1.0 + p1r));
        int pos0 = atomicAdd(&cnt[e0], 1);
        tok[e0 * 4096 + pos0] = t; gate[e0 * 4096 + pos0] = g0;
        int pos1 = atomicAdd(&cnt[e1], 1);
        tok[e1 * 4096 + pos1] = t; gate[e1 * 4096 + pos1] = g1;
    }
}

__global__ void prefix_k(const int* __restrict__ cnt, int* __restrict__ pb) {
    if (threadIdx.x == 0 && blockIdx.x == 0) {
        int s = 0;
        for (int e = 0; e < CE; e++) { pb[e] = s; s += cnt[e]; }
    }
}

// ---------------- launch ----------------
extern "C" void kernel_launch(void* const* d_in, const int* in_sizes, int n_in,
                              void* d_out, int out_size, void* d_ws, size_t ws_size,
                              hipStream_t stream) {
    (void)in_sizes; (void)n_in; (void)out_size; (void)ws_size;
    const float* hidden = (const float*)d_in[0];
    const int*   posids = (const int*)d_in[1];
    const float* rms1w  = (const float*)d_in[2];
    const float* rms2w  = (const float*)d_in[3];
    const float* qw     = (const float*)d_in[4];
    const float* kw     = (const float*)d_in[5];
    const float* vw     = (const float*)d_in[6];
    const float* ow     = (const float*)d_in[7];
    const float* rw     = (const float*)d_in[8];
    const float* w1     = (const float*)d_in[9];
    const float* w2     = (const float*)d_in[10];
    const float* w3     = (const float*)d_in[11];
    float* out = (float*)d_out;

    char* ws = (char*)d_ws;
    unsigned short* h1h = (unsigned short*)ws;
    unsigned short* h1l = (unsigned short*)(ws + 16777216);
    unsigned short* woh = (unsigned short*)ws;
    unsigned short* wol = (unsigned short*)(ws + 8388608);
    unsigned short* h2  = (unsigned short*)ws;
    int*   tok  = (int*)(ws + 16777216);
    float* gate = (float*)(ws + 16777216 + 131072);
    int*   cnt  = (int*)(ws + 16777216 + 262144);
    int*   pb   = cnt + 16;
    unsigned short* qkvh = (unsigned short*)(ws + 33554432);
    unsigned short* qkvl = (unsigned short*)(ws + 83886080);
    unsigned short* wt13 = (unsigned short*)(ws + 33554432);
    unsigned short* wt2  = (unsigned short*)(ws + 33554432);
    unsigned short* wqkvh = (unsigned short*)(ws + 134217728);
    unsigned short* wqkvl = (unsigned short*)(ws + 134217728 + 25165824);
    unsigned short* ctxh = (unsigned short*)(ws + 134217728);
    unsigned short* ctxl = (unsigned short*)(ws + 150994944);
    float*          res2 = (float*)(ws + 167772160);
    unsigned short* Hbuf = (unsigned short*)(ws + 167772160);
    float2*         rtab = (float2*)(ws + 201326592);

    rope_tab_k<<<512, 256, 0, stream>>>(rtab);
    rmsnorm_k<0><<<CT, 256, 0, stream>>>(hidden, rms1w, h1h, h1l);
    convs_k<3><<<dim3(32, 32, 3), 256, 0, stream>>>(qw, kw, vw, wqkvh, wqkvl);
    sgemm_k<0><<<dim3(32, 48), 256, 0, stream>>>(h1h, h1l, CH, wqkvh, wqkvl, CH,
                                                 qkvh, qkvl, nullptr, CQKV, nullptr, nullptr);
    rope_k<<<16384, 256, 0, stream>>>(qkvh, qkvl, posids, rtab);
    convs_k<1><<<dim3(32, 32, 1), 256, 0, stream>>>(ow, nullptr, nullptr, woh, wol);
    attn_k<<<1024, 256, 0, stream>>>(qkvh, qkvl, ctxh, ctxl);
    sgemm_k<1><<<dim3(32, 16), 256, 0, stream>>>(ctxh, ctxl, CH, woh, wol, CH,
                                                 nullptr, nullptr, res2, CH, hidden, out);
    rmsnorm_k<1><<<CT, 256, 0, stream>>>(res2, rms2w, h2, nullptr);
    hipMemsetAsync(cnt, 0, 8 * sizeof(int), stream);
    router_k<<<CT, 64, 0, stream>>>(res2, rms2w, rw, cnt, tok, gate);
    prefix_k<<<1, 64, 0, stream>>>(cnt, pb);
    conv_k<2><<<dim3(32, 32, CE), 256, 0, stream>>>(w1, w3, wt13);
    gemm_k<2><<<dim3(32, 32, CE), 256, 0, stream>>>(h2, CH, wt13, CH, 2 * CI, Hbuf, CI,
                                                    cnt, tok, gate, pb);
    conv_k<1><<<dim3(32, 32, CE), 256, 0, stream>>>(w2, nullptr, wt2);
    gemm_k<3><<<dim3(16, 32, CE), 256, 0, stream>>>(Hbuf, CI, wt2, CI, CH, out, CH,
                                                    cnt, tok, gate, pb);
}

// Round 9
// 1406.115 us; speedup vs baseline: 1.0831x; 1.0241x over previous
//
#include <hip/hip_runtime.h>
#include <hip/hip_bf16.h>

// ---------------- constants ----------------
constexpr int CB   = 2;     // batch
constexpr int CS   = 2048;  // seq
constexpr int CH   = 2048;  // hidden
constexpr int CNH  = 16;    // heads
constexpr int CHD  = 128;   // head dim
constexpr int CE   = 8;     // experts
constexpr int CI   = 2048;  // ffn inner
constexpr int CT   = CB * CS;      // 4096 tokens
constexpr int CQKV = 3 * CH;       // 6144

typedef __attribute__((ext_vector_type(8))) short short8;
typedef __attribute__((ext_vector_type(4))) float float4v;
typedef __attribute__((ext_vector_type(4))) unsigned short ushort4v;
typedef unsigned int uint32;

__device__ __forceinline__ float bf2f(unsigned short u) {
    union { unsigned int i; float f; } x; x.i = ((unsigned int)u) << 16; return x.f;
}
__device__ __forceinline__ unsigned short f2bf(float f) {
    union { float f; unsigned int i; } x; x.f = f;
    unsigned int r = x.i + 0x7fffu + ((x.i >> 16) & 1u);
    return (unsigned short)(r >> 16);
}
__device__ __forceinline__ uint32 packpair(uint32 r0, uint32 r1) {
    return __builtin_amdgcn_perm(r1, r0, 0x07060302u);
}
__device__ __forceinline__ uint32 rnebits(float f) {
    uint32 u = __float_as_uint(f);
    return u + 0x7fffu + ((u >> 16) & 1u);
}
__device__ __forceinline__ void split2(float f0, float f1, uint32& h, uint32& l) {
    uint32 r0 = rnebits(f0), r1 = rnebits(f1);
    h = packpair(r0, r1);
    float d0 = f0 - __uint_as_float(r0 & 0xffff0000u);
    float d1 = f1 - __uint_as_float(r1 & 0xffff0000u);
    l = packpair(rnebits(d0), rnebits(d1));
}
__device__ __forceinline__ void rne16_store(const float* fv, unsigned short* dst) {
    uint32 h[8];
    #pragma unroll
    for (int p = 0; p < 8; p++) h[p] = packpair(rnebits(fv[2 * p]), rnebits(fv[2 * p + 1]));
    ((uint4*)dst)[0] = make_uint4(h[0], h[1], h[2], h[3]);
    ((uint4*)dst)[1] = make_uint4(h[4], h[5], h[6], h[7]);
}

// ---------------- RMSNorm (hi/lo split out) ----------
__global__ __launch_bounds__(256) void rmsnorm_k(const float* __restrict__ x,
                                                 const float* __restrict__ w,
                                                 unsigned short* __restrict__ o1,
                                                 unsigned short* __restrict__ o2) {
    const int row = blockIdx.x;
    const float* xr = x + (size_t)row * CH;
    const int base = threadIdx.x * 8;
    float4 v0 = *(const float4*)(xr + base);
    float4 v1 = *(const float4*)(xr + base + 4);
    float ss = v0.x*v0.x + v0.y*v0.y + v0.z*v0.z + v0.w*v0.w
             + v1.x*v1.x + v1.y*v1.y + v1.z*v1.z + v1.w*v1.w;
    #pragma unroll
    for (int o = 1; o < 64; o <<= 1) ss += __shfl_xor(ss, o);
    __shared__ float ps[4];
    if ((threadIdx.x & 63) == 0) ps[threadIdx.x >> 6] = ss;
    __syncthreads();
    const float scale = rsqrtf((ps[0] + ps[1] + ps[2] + ps[3]) / (float)CH + 1e-5f);
    float4 w0 = *(const float4*)(w + base);
    float4 w1 = *(const float4*)(w + base + 4);
    float r[8] = {v0.x * scale * w0.x, v0.y * scale * w0.y, v0.z * scale * w0.z, v0.w * scale * w0.w,
                  v1.x * scale * w1.x, v1.y * scale * w1.y, v1.z * scale * w1.z, v1.w * scale * w1.w};
    uint32 h[4], l[4];
    #pragma unroll
    for (int p = 0; p < 4; p++) split2(r[2 * p], r[2 * p + 1], h[p], l[p]);
    *(uint4*)(o1 + (size_t)row * CH + base) = make_uint4(h[0], h[1], h[2], h[3]);
    *(uint4*)(o2 + (size_t)row * CH + base) = make_uint4(l[0], l[1], l[2], l[3]);
}

// ---------------- fused RMSNorm2 + router (fp64 logits, top2) ----------------
__global__ __launch_bounds__(256) void rmsrouter_k(const float* __restrict__ x,
                                                   const float* __restrict__ w,
                                                   const float* __restrict__ rw,
                                                   unsigned short* __restrict__ h2,
                                                   int* __restrict__ cnt,
                                                   int* __restrict__ tok,
                                                   float* __restrict__ gate) {
    const int row = blockIdx.x;
    const float* xr = x + (size_t)row * CH;
    const int base = threadIdx.x * 8;
    float4 v0 = *(const float4*)(xr + base);
    float4 v1 = *(const float4*)(xr + base + 4);
    float ss = v0.x*v0.x + v0.y*v0.y + v0.z*v0.z + v0.w*v0.w
             + v1.x*v1.x + v1.y*v1.y + v1.z*v1.z + v1.w*v1.w;
    #pragma unroll
    for (int o = 1; o < 64; o <<= 1) ss += __shfl_xor(ss, o);
    __shared__ float ps[4];
    __shared__ double dacc[4][8];
    const int wave = threadIdx.x >> 6, lane = threadIdx.x & 63;
    if (lane == 0) ps[wave] = ss;
    __syncthreads();
    const float scale = rsqrtf((ps[0] + ps[1] + ps[2] + ps[3]) / (float)CH + 1e-5f);
    float4 w0 = *(const float4*)(w + base);
    float4 w1 = *(const float4*)(w + base + 4);
    float r[8] = {v0.x * scale * w0.x, v0.y * scale * w0.y, v0.z * scale * w0.z, v0.w * scale * w0.w,
                  v1.x * scale * w1.x, v1.y * scale * w1.y, v1.z * scale * w1.z, v1.w * scale * w1.w};
    rne16_store(r, h2 + (size_t)row * CH + base);
    const float vv[8] = {v0.x, v0.y, v0.z, v0.w, v1.x, v1.y, v1.z, v1.w};
    const float ww[8] = {w0.x, w0.y, w0.z, w0.w, w1.x, w1.y, w1.z, w1.w};
    double acc[8] = {0, 0, 0, 0, 0, 0, 0, 0};
    #pragma unroll
    for (int jj = 0; jj < 8; jj++) {
        const double xn = (double)vv[jj] * (double)ww[jj];
        const float* rr = rw + (size_t)(base + jj) * CE;
        #pragma unroll
        for (int e = 0; e < 8; e++) acc[e] += xn * (double)rr[e];
    }
    #pragma unroll
    for (int e = 0; e < 8; e++) {
        #pragma unroll
        for (int o = 1; o < 64; o <<= 1) acc[e] += __shfl_xor(acc[e], o);
    }
    if (lane == 0) {
        #pragma unroll
        for (int e = 0; e < 8; e++) dacc[wave][e] = acc[e];
    }
    __syncthreads();
    if (threadIdx.x == 0) {
        double a[8];
        #pragma unroll
        for (int e = 0; e < 8; e++) a[e] = dacc[0][e] + dacc[1][e] + dacc[2][e] + dacc[3][e];
        int e0 = 0;
        #pragma unroll
        for (int e = 1; e < 8; e++) if (a[e] > a[e0]) e0 = e;
        int e1 = (e0 == 0) ? 1 : 0;
        #pragma unroll
        for (int e = 0; e < 8; e++) if (e != e0 && a[e] > a[e1]) e1 = e;
        const double dl = (double)scale * (a[e1] - a[e0]);   // <= 0
        const double p1r = exp(dl);
        const float g0 = (float)(1.0 / (1.0 + p1r));
        const float g1 = (float)(p1r / (1.0 + p1r));
        int pos0 = atomicAdd(&cnt[e0], 1);
        tok[e0 * 4096 + pos0] = row; gate[e0 * 4096 + pos0] = g0;
        int pos1 = atomicAdd(&cnt[e1], 1);
        tok[e1 * 4096 + pos1] = row; gate[e1 * 4096 + pos1] = g1;
    }
}

// ---------------- RoPE table (replicating np's fp32 rounding) ----
__global__ void rope_tab_k(float2* __restrict__ tab) {
    int i = blockIdx.x * 256 + threadIdx.x;   // 2048*64
    int p = i >> 6, j = i & 63;
    double inv = pow(10000.0, -(double)j / 64.0);
    float invf = (float)inv;
    float angf = (float)p * invf;
    double da = (double)angf;
    tab[i] = make_float2((float)cos(da), (float)sin(da));
}

// ---------------- RoPE vectorized (in-place on hi/lo split q,k) ----------------
__global__ __launch_bounds__(256) void rope_k(unsigned short* __restrict__ qh,
                                              unsigned short* __restrict__ ql,
                                              const int* __restrict__ pos,
                                              const float2* __restrict__ tab) {
    int i = blockIdx.x * 256 + threadIdx.x;  // CT*16*8
    if (i >= CT * CNH * 8) return;
    int t = i >> 7, r = i & 127, hh = r >> 3, jo = (r & 7) << 3;
    const float2* tp = tab + (size_t)pos[t] * 64 + jo;
    float4 tc0 = ((const float4*)tp)[0];
    float4 tc1 = ((const float4*)tp)[1];
    float4 tc2 = ((const float4*)tp)[2];
    float4 tc3 = ((const float4*)tp)[3];
    float cx[8] = {tc0.x, tc0.z, tc1.x, tc1.z, tc2.x, tc2.z, tc3.x, tc3.z};
    float cy[8] = {tc0.y, tc0.w, tc1.y, tc1.w, tc2.y, tc2.w, tc3.y, tc3.w};
    const size_t off = (size_t)t * CQKV + hh * CHD + jo;
    #pragma unroll
    for (int s = 0; s < 2; s++) {
        unsigned short* hp = qh + off + s * CH;   // q then k
        unsigned short* lp = ql + off + s * CH;
        short8 x1h = *(short8*)hp,        x1l = *(short8*)lp;
        short8 x2h = *(short8*)(hp + 64), x2l = *(short8*)(lp + 64);
        const unsigned short* p1h = (const unsigned short*)&x1h;
        const unsigned short* p1l = (const unsigned short*)&x1l;
        const unsigned short* p2h = (const unsigned short*)&x2h;
        const unsigned short* p2l = (const unsigned short*)&x2l;
        short8 y1h, y1l, y2h, y2l;
        unsigned short* q1h = (unsigned short*)&y1h;
        unsigned short* q1l = (unsigned short*)&y1l;
        unsigned short* q2h = (unsigned short*)&y2h;
        unsigned short* q2l = (unsigned short*)&y2l;
        #pragma unroll
        for (int jj = 0; jj < 8; jj++) {
            const float x1 = bf2f(p1h[jj]) + bf2f(p1l[jj]);
            const float x2 = bf2f(p2h[jj]) + bf2f(p2l[jj]);
            const float yy1 = x1 * cx[jj] - x2 * cy[jj];
            const float yy2 = x2 * cx[jj] + x1 * cy[jj];
            const uint32 r1 = rnebits(yy1), r2 = rnebits(yy2);
            q1h[jj] = (unsigned short)(r1 >> 16);
            q2h[jj] = (unsigned short)(r2 >> 16);
            q1l[jj] = f2bf(yy1 - __uint_as_float(r1 & 0xffff0000u));
            q2l[jj] = f2bf(yy2 - __uint_as_float(r2 & 0xffff0000u));
        }
        *(short8*)hp        = y1h;
        *(short8*)(hp + 64) = y2h;
        *(short8*)lp        = y1l;
        *(short8*)(lp + 64) = y2l;
    }
}

// ---------------- weight transpose+convert: src[K][N] f32 -> dst[N][K] bf16 ----
template<int NMAT>
__global__ __launch_bounds__(256) void conv_k(const float* __restrict__ S0,
                                              const float* __restrict__ S1,
                                              unsigned short* __restrict__ D) {
    __shared__ float t[64][65];
    const int n0 = blockIdx.x * 64, k0 = blockIdx.y * 64, e = blockIdx.z;
    const size_t esrc = (size_t)e * 2048 * 2048;
    const int cc = threadIdx.x & 63, r4 = threadIdx.x >> 6;
    const int nl = threadIdx.x >> 2, q = threadIdx.x & 3;
    #pragma unroll
    for (int s = 0; s < NMAT; s++) {
        const float* S = s ? S1 : S0;
        __syncthreads();
        #pragma unroll
        for (int j = 0; j < 16; j++) {
            const int row = j * 4 + r4;
            t[cc][row] = S[esrc + (size_t)(k0 + row) * 2048 + n0 + cc];
        }
        __syncthreads();
        const int orow = (NMAT == 2) ? (2 * (n0 + nl) + s) : (n0 + nl);
        unsigned short* dp = D + (size_t)e * (NMAT * 2048) * 2048 + (size_t)orow * 2048 + k0 + q * 16;
        float fv[16];
        #pragma unroll
        for (int j = 0; j < 16; j++) fv[j] = t[nl][q * 16 + j];
        rne16_store(fv, dp);
    }
}

// ---------------- weight transpose + hi/lo SPLIT convert --------------------
template<int NMAT>
__global__ __launch_bounds__(256) void convs_k(const float* __restrict__ S0,
                                               const float* __restrict__ S1,
                                               const float* __restrict__ S2,
                                               unsigned short* __restrict__ Dh,
                                               unsigned short* __restrict__ Dl) {
    __shared__ float t[64][65];
    const int n0 = blockIdx.x * 64, k0 = blockIdx.y * 64, z = blockIdx.z;
    const float* S = S0;
    if (NMAT == 3) S = (z == 0) ? S0 : ((z == 1) ? S1 : S2);
    const int cc = threadIdx.x & 63, r4 = threadIdx.x >> 6;
    #pragma unroll
    for (int j = 0; j < 16; j++) {
        const int row = j * 4 + r4;
        t[cc][row] = S[(size_t)(k0 + row) * 2048 + n0 + cc];
    }
    __syncthreads();
    const int nl = threadIdx.x >> 2, q = threadIdx.x & 3;
    float fv[16];
    #pragma unroll
    for (int j = 0; j < 16; j++) fv[j] = t[nl][q * 16 + j];
    uint32 h[8], l[8];
    #pragma unroll
    for (int p = 0; p < 8; p++) split2(fv[2 * p], fv[2 * p + 1], h[p], l[p]);
    const size_t off = (size_t)(z * 2048 + n0 + nl) * 2048 + k0 + q * 16;
    ((uint4*)(Dh + off))[0] = make_uint4(h[0], h[1], h[2], h[3]);
    ((uint4*)(Dh + off))[1] = make_uint4(h[4], h[5], h[6], h[7]);
    ((uint4*)(Dl + off))[0] = make_uint4(l[0], l[1], l[2], l[3]);
    ((uint4*)(Dl + off))[1] = make_uint4(l[4], l[5], l[6], l[7]);
}

// ---------------- precise split-bf16 GEMM, depth-2 prefetch -------------------
template<int MODE>
__global__ __launch_bounds__(256) void sgemm_k(
    const unsigned short* __restrict__ Ahg, const unsigned short* __restrict__ Alg, int lda,
    const unsigned short* __restrict__ Bhg, const unsigned short* __restrict__ Blg, int K,
    unsigned short* __restrict__ Ch, unsigned short* __restrict__ Cl,
    float* __restrict__ Cf, int ldc,
    const float* __restrict__ resid, float* __restrict__ C2) {
    __shared__ unsigned short AhS[128][40], AlS[128][40], BhS[128][40], BlS[128][40];
    const int mt = blockIdx.x, nt = blockIdx.y, tid = threadIdx.x;
    const int m0 = mt * 128;
    const int srow = tid >> 1, shalf = tid & 1;
    const unsigned short* ah = Ahg + (size_t)(m0 + srow) * lda + shalf * 16;
    const unsigned short* al = Alg + (size_t)(m0 + srow) * lda + shalf * 16;
    const unsigned short* bhp = Bhg + (size_t)(nt * 128 + srow) * K + shalf * 16;
    const unsigned short* blp = Blg + (size_t)(nt * 128 + srow) * K + shalf * 16;
    const int lane = tid & 63, lr = lane & 15, lg = lane >> 4;
    const int wr = (tid >> 7) & 1, wc = (tid >> 6) & 1;

    float4v acc[4][4];
    #pragma unroll
    for (int m = 0; m < 4; m++)
        #pragma unroll
        for (int n = 0; n < 4; n++) acc[m][n] = (float4v){0.f, 0.f, 0.f, 0.f};

    // depth-2 prefetch: c* = tile k0, n* = tile k0+32
    short8 cah0 = *(const short8*)(ah),      cah1 = *(const short8*)(ah + 8);
    short8 cal0 = *(const short8*)(al),      cal1 = *(const short8*)(al + 8);
    short8 cbh0 = *(const short8*)(bhp),     cbh1 = *(const short8*)(bhp + 8);
    short8 cbl0 = *(const short8*)(blp),     cbl1 = *(const short8*)(blp + 8);
    short8 nah0 = *(const short8*)(ah + 32), nah1 = *(const short8*)(ah + 40);
    short8 nal0 = *(const short8*)(al + 32), nal1 = *(const short8*)(al + 40);
    short8 nbh0 = *(const short8*)(bhp + 32), nbh1 = *(const short8*)(bhp + 40);
    short8 nbl0 = *(const short8*)(blp + 32), nbl1 = *(const short8*)(blp + 40);

    for (int k0 = 0; k0 < K; k0 += 32) {
        __syncthreads();
        *(short8*)(&AhS[srow][shalf * 16])     = cah0;
        *(short8*)(&AhS[srow][shalf * 16 + 8]) = cah1;
        *(short8*)(&AlS[srow][shalf * 16])     = cal0;
        *(short8*)(&AlS[srow][shalf * 16 + 8]) = cal1;
        *(short8*)(&BhS[srow][shalf * 16])     = cbh0;
        *(short8*)(&BhS[srow][shalf * 16 + 8]) = cbh1;
        *(short8*)(&BlS[srow][shalf * 16])     = cbl0;
        *(short8*)(&BlS[srow][shalf * 16 + 8]) = cbl1;
        cah0 = nah0; cah1 = nah1; cal0 = nal0; cal1 = nal1;
        cbh0 = nbh0; cbh1 = nbh1; cbl0 = nbl0; cbl1 = nbl1;
        if (k0 + 64 < K) {
            nah0 = *(const short8*)(ah + k0 + 64);  nah1 = *(const short8*)(ah + k0 + 72);
            nal0 = *(const short8*)(al + k0 + 64);  nal1 = *(const short8*)(al + k0 + 72);
            nbh0 = *(const short8*)(bhp + k0 + 64); nbh1 = *(const short8*)(bhp + k0 + 72);
            nbl0 = *(const short8*)(blp + k0 + 64); nbl1 = *(const short8*)(blp + k0 + 72);
        }
        __syncthreads();
        short8 fah[4], fal[4], fbh[4], fbl[4];
        #pragma unroll
        for (int m = 0; m < 4; m++) {
            fah[m] = *(const short8*)(&AhS[wr * 64 + m * 16 + lr][lg * 8]);
            fal[m] = *(const short8*)(&AlS[wr * 64 + m * 16 + lr][lg * 8]);
        }
        #pragma unroll
        for (int n = 0; n < 4; n++) {
            fbh[n] = *(const short8*)(&BhS[wc * 64 + n * 16 + lr][lg * 8]);
            fbl[n] = *(const short8*)(&BlS[wc * 64 + n * 16 + lr][lg * 8]);
        }
        #pragma unroll
        for (int n = 0; n < 4; n++)
            #pragma unroll
            for (int m = 0; m < 4; m++) {
                acc[m][n] = __builtin_amdgcn_mfma_f32_16x16x32_bf16(fal[m], fbh[n], acc[m][n], 0, 0, 0);
                acc[m][n] = __builtin_amdgcn_mfma_f32_16x16x32_bf16(fah[m], fbl[n], acc[m][n], 0, 0, 0);
                acc[m][n] = __builtin_amdgcn_mfma_f32_16x16x32_bf16(fah[m], fbh[n], acc[m][n], 0, 0, 0);
            }
    }
    #pragma unroll
    for (int m = 0; m < 4; m++) {
        const int rb = wr * 64 + m * 16 + lg * 4;
        #pragma unroll
        for (int n = 0; n < 4; n++) {
            const int ccol = nt * 128 + wc * 64 + n * 16 + lr;
            #pragma unroll
            for (int r = 0; r < 4; r++) {
                const size_t idx = (size_t)(m0 + rb + r) * ldc + ccol;
                if (MODE == 1) {
                    const float v = acc[m][n][r] + resid[idx];
                    Cf[idx] = v;
                    C2[idx] = v;
                } else {
                    const float v = acc[m][n][r];
                    uint32 rr = rnebits(v);
                    Ch[idx] = (unsigned short)(rr >> 16);
                    Cl[idx] = f2bf(v - __uint_as_float(rr & 0xffff0000u));
                }
            }
        }
    }
}

// ---------------- MoE GEMM, depth-2 prefetch ----
template<int MODE>
__global__ __launch_bounds__(256) void gemm_k(
    const unsigned short* __restrict__ A, int lda,
    const unsigned short* __restrict__ Bt, int K, int Ne,
    void* __restrict__ Cp, int ldc,
    const int* __restrict__ cnt, const int* __restrict__ tokl,
    const float* __restrict__ gatel, const int* __restrict__ pb) {
    __shared__ unsigned short As[128][40];
    __shared__ unsigned short Bs[128][40];
    const int nt = blockIdx.x, mt = blockIdx.y, e = blockIdx.z;
    const int m0 = mt * 128;
    const int c = cnt[e];
    if (m0 >= c) return;
    const int valid = (c - m0 < 128) ? (c - m0) : 128;
    const int tid = threadIdx.x;
    const int srow = tid >> 1, shalf = tid & 1;
    size_t gr;
    if (MODE == 2) {
        const int idx = m0 + (srow < valid ? srow : valid - 1);
        gr = (size_t)tokl[e * 4096 + idx];
    } else {
        const int rr = m0 + srow;
        gr = (size_t)(pb[e] + (rr < c ? rr : c - 1));
    }
    const unsigned short* a_src = A + gr * (size_t)lda + shalf * 16;
    const unsigned short* b_src = Bt + (size_t)e * Ne * K + (size_t)(nt * 128 + srow) * K + shalf * 16;
    const int lane = tid & 63, lr = lane & 15, lg = lane >> 4;
    const int wr = (tid >> 7) & 1, wc = (tid >> 6) & 1;

    float4v acc[4][4];
    #pragma unroll
    for (int m = 0; m < 4; m++)
        #pragma unroll
        for (int n = 0; n < 4; n++) acc[m][n] = (float4v){0.f, 0.f, 0.f, 0.f};

    short8 ca0 = *(const short8*)(a_src),      ca1 = *(const short8*)(a_src + 8);
    short8 cb0 = *(const short8*)(b_src),      cb1 = *(const short8*)(b_src + 8);
    short8 na0 = *(const short8*)(a_src + 32), na1 = *(const short8*)(a_src + 40);
    short8 nb0 = *(const short8*)(b_src + 32), nb1 = *(const short8*)(b_src + 40);

    for (int k0 = 0; k0 < K; k0 += 32) {
        __syncthreads();
        *(short8*)(&As[srow][shalf * 16])     = ca0;
        *(short8*)(&As[srow][shalf * 16 + 8]) = ca1;
        *(short8*)(&Bs[srow][shalf * 16])     = cb0;
        *(short8*)(&Bs[srow][shalf * 16 + 8]) = cb1;
        ca0 = na0; ca1 = na1; cb0 = nb0; cb1 = nb1;
        if (k0 + 64 < K) {
            na0 = *(const short8*)(a_src + k0 + 64);
            na1 = *(const short8*)(a_src + k0 + 72);
            nb0 = *(const short8*)(b_src + k0 + 64);
            nb1 = *(const short8*)(b_src + k0 + 72);
        }
        __syncthreads();
        short8 af[4], bf[4];
        #pragma unroll
        for (int m = 0; m < 4; m++) af[m] = *(const short8*)(&As[wr * 64 + m * 16 + lr][lg * 8]);
        #pragma unroll
        for (int n = 0; n < 4; n++) bf[n] = *(const short8*)(&Bs[wc * 64 + n * 16 + lr][lg * 8]);
        #pragma unroll
        for (int n = 0; n < 4; n++)
            #pragma unroll
            for (int m = 0; m < 4; m++)
                acc[m][n] = __builtin_amdgcn_mfma_f32_16x16x32_bf16(af[m], bf[n], acc[m][n], 0, 0, 0);
    }

    #pragma unroll
    for (int m = 0; m < 4; m++) {
        const int rb = wr * 64 + m * 16 + lg * 4;
        #pragma unroll
        for (int n = 0; n < 4; n++) {
            const int col = nt * 128 + wc * 64 + n * 16 + lr;
            #pragma unroll
            for (int r = 0; r < 4; r++) {
                const int row = rb + r;
                const float v = acc[m][n][r];
                if (MODE == 2) {
                    const float other = __shfl_xor(v, 1);
                    if (!(lr & 1) && row < valid) {
                        const float g1 = v, g3 = other;
                        const float hsw = (g1 / (1.f + __expf(-g1))) * g3;
                        ((unsigned short*)Cp)[(size_t)(pb[e] + m0 + row) * ldc + (col >> 1)] = f2bf(hsw);
                    }
                } else {
                    if (row < valid) {
                        const int t = tokl[e * 4096 + m0 + row];
                        const float g = gatel[e * 4096 + m0 + row];
                        atomicAdd(((float*)Cp) + (size_t)t * ldc + col, v * g);
                    }
                }
            }
        }
    }
}

// ---------------- flash attention, split-bf16, XCD-pinned + prefetch ----------
__global__ __launch_bounds__(256) void attn_k(const unsigned short* __restrict__ qh,
                                              const unsigned short* __restrict__ ql,
                                              unsigned short* __restrict__ ch,
                                              unsigned short* __restrict__ cl) {
    __shared__ unsigned short Ksh[32][136], Ksl[32][136];
    __shared__ unsigned short Vth[128][40], Vtl[128][40];
    const int bid = blockIdx.x;          // 1024 blocks
    const int xcd = bid & 7, jj = bid >> 3;
    const int bh  = xcd * 4 + (jj >> 5);
    const int qb  = 31 - (jj & 31);
    const int h   = bh & 15, b = bh >> 4;
    const int tid = threadIdx.x;
    const int wave = tid >> 6, lane = tid & 63, lr = lane & 15, lg = lane >> 4;
    const size_t tb = (size_t)b * CS;
    const int q0 = qb * 64 + wave * 16;

    short8 qfh[4], qfl[4];
    {
        const size_t off = (tb + q0 + lr) * CQKV + h * CHD;
        #pragma unroll
        for (int c = 0; c < 4; c++) {
            qfh[c] = *(const short8*)(qh + off + c * 32 + lg * 8);
            qfl[c] = *(const short8*)(ql + off + c * 32 + lg * 8);
        }
    }
    float4v o[8];
    #pragma unroll
    for (int d = 0; d < 8; d++) o[d] = (float4v){0.f, 0.f, 0.f, 0.f};
    float m = -1e30f, l = 0.f;
    const float scl = 0.08838834764831845f;  // 1/sqrt(128)
    const int ntiles = 2 * (qb + 1);
    const int kk = tid >> 3, slot = tid & 7;
    const int vd = tid & 127, vhalf = tid >> 7;

    short8 pkh0, pkh1, pkl0, pkl1;
    unsigned short pth[16], ptl[16];
    {
        const size_t koff = (tb + kk) * CQKV + CH + h * CHD + slot * 16;
        pkh0 = *(const short8*)(qh + koff);
        pkh1 = *(const short8*)(qh + koff + 8);
        pkl0 = *(const short8*)(ql + koff);
        pkl1 = *(const short8*)(ql + koff + 8);
        const size_t voff = (tb + vhalf * 16) * CQKV + 2 * CH + h * CHD + vd;
        #pragma unroll
        for (int j = 0; j < 16; j++) {
            pth[j] = qh[voff + (size_t)j * CQKV];
            ptl[j] = ql[voff + (size_t)j * CQKV];
        }
    }

    for (int kt = 0; kt < ntiles; ++kt) {
        const int kv0 = kt * 32;
        __syncthreads();
        *(short8*)(&Ksh[kk][slot * 16])     = pkh0;
        *(short8*)(&Ksh[kk][slot * 16 + 8]) = pkh1;
        *(short8*)(&Ksl[kk][slot * 16])     = pkl0;
        *(short8*)(&Ksl[kk][slot * 16 + 8]) = pkl1;
        #pragma unroll
        for (int p = 0; p < 2; p++) {
            *(ushort4v*)(&Vth[vd][vhalf * 16 + p * 8])     = *(ushort4v*)(&pth[p * 8]);
            *(ushort4v*)(&Vth[vd][vhalf * 16 + p * 8 + 4]) = *(ushort4v*)(&pth[p * 8 + 4]);
            *(ushort4v*)(&Vtl[vd][vhalf * 16 + p * 8])     = *(ushort4v*)(&ptl[p * 8]);
            *(ushort4v*)(&Vtl[vd][vhalf * 16 + p * 8 + 4]) = *(ushort4v*)(&ptl[p * 8 + 4]);
        }
        if (kt + 1 < ntiles) {
            const int nv0 = kv0 + 32;
            const size_t koff = (tb + nv0 + kk) * CQKV + CH + h * CHD + slot * 16;
            pkh0 = *(const short8*)(qh + koff);
            pkh1 = *(const short8*)(qh + koff + 8);
            pkl0 = *(const short8*)(ql + koff);
            pkl1 = *(const short8*)(ql + koff + 8);
            const size_t voff = (tb + nv0 + vhalf * 16) * CQKV + 2 * CH + h * CHD + vd;
            #pragma unroll
            for (int j = 0; j < 16; j++) {
                pth[j] = qh[voff + (size_t)j * CQKV];
                ptl[j] = ql[voff + (size_t)j * CQKV];
            }
        }
        __syncthreads();

        float4v st0 = (float4v){0.f,0.f,0.f,0.f}, st1 = st0;
        #pragma unroll
        for (int c = 0; c < 4; c++) {
            short8 kah = *(const short8*)(&Ksh[lr][c * 32 + lg * 8]);
            short8 kal = *(const short8*)(&Ksl[lr][c * 32 + lg * 8]);
            short8 kbh = *(const short8*)(&Ksh[16 + lr][c * 32 + lg * 8]);
            short8 kbl = *(const short8*)(&Ksl[16 + lr][c * 32 + lg * 8]);
            st0 = __builtin_amdgcn_mfma_f32_16x16x32_bf16(kal, qfh[c], st0, 0, 0, 0);
            st0 = __builtin_amdgcn_mfma_f32_16x16x32_bf16(kah, qfl[c], st0, 0, 0, 0);
            st0 = __builtin_amdgcn_mfma_f32_16x16x32_bf16(kah, qfh[c], st0, 0, 0, 0);
            st1 = __builtin_amdgcn_mfma_f32_16x16x32_bf16(kbl, qfh[c], st1, 0, 0, 0);
            st1 = __builtin_amdgcn_mfma_f32_16x16x32_bf16(kbh, qfl[c], st1, 0, 0, 0);
            st1 = __builtin_amdgcn_mfma_f32_16x16x32_bf16(kbh, qfh[c], st1, 0, 0, 0);
        }
        float pv[8]; float pmax = -1e30f;
        const int qg = q0 + lr;
        #pragma unroll
        for (int f = 0; f < 2; f++) {
            #pragma unroll
            for (int r = 0; r < 4; r++) {
                const int kg = kv0 + f * 16 + lg * 4 + r;
                const float s = (kg <= qg) ? ((f ? st1[r] : st0[r]) * scl) : -1e30f;
                pv[f * 4 + r] = s;
                pmax = fmaxf(pmax, s);
            }
        }
        pmax = fmaxf(pmax, __shfl_xor(pmax, 16));
        pmax = fmaxf(pmax, __shfl_xor(pmax, 32));
        // defer-max: if no row's max grew, alpha would be exactly 1 — skip rescale.
        if (!__all(pmax <= m)) {
            const float mnew = fmaxf(m, pmax);
            const float alpha = __expf(m - mnew);
            l *= alpha;
            #pragma unroll
            for (int d = 0; d < 8; d++) o[d] *= alpha;
            m = mnew;
        }
        float sum = 0.f;
        #pragma unroll
        for (int i = 0; i < 8; i++) { const float p = __expf(pv[i] - m); pv[i] = p; sum += p; }
        sum += __shfl_xor(sum, 16);
        sum += __shfl_xor(sum, 32);
        l += sum;
        short8 pfh, pfl;
        unsigned short* pfhp = (unsigned short*)&pfh;
        unsigned short* pflp = (unsigned short*)&pfl;
        #pragma unroll
        for (int j = 0; j < 8; j++) {
            const int srcl = (((lg & 1) * 2 + (j >> 2)) << 4) | lr;
            const float a0 = __shfl(pv[j & 3], srcl);
            const float a1 = __shfl(pv[4 + (j & 3)], srcl);
            const float sel = (lg >= 2) ? a1 : a0;
            uint32 r = rnebits(sel);
            pfhp[j] = (unsigned short)(r >> 16);
            float d = sel - __uint_as_float(r & 0xffff0000u);
            pflp[j] = (unsigned short)(rnebits(d) >> 16);
        }
        #pragma unroll
        for (int dt = 0; dt < 8; dt++) {
            short8 vh = *(const short8*)(&Vth[dt * 16 + lr][lg * 8]);
            short8 vl = *(const short8*)(&Vtl[dt * 16 + lr][lg * 8]);
            o[dt] = __builtin_amdgcn_mfma_f32_16x16x32_bf16(vl, pfh, o[dt], 0, 0, 0);
            o[dt] = __builtin_amdgcn_mfma_f32_16x16x32_bf16(vh, pfl, o[dt], 0, 0, 0);
            o[dt] = __builtin_amdgcn_mfma_f32_16x16x32_bf16(vh, pfh, o[dt], 0, 0, 0);
        }
    }
    const float inv = 1.f / l;
    const size_t coff = (tb + q0 + lr) * CH + h * CHD + lg * 4;
    #pragma unroll
    for (int dt = 0; dt < 8; dt++) {
        ushort4v wh, wl;
        #pragma unroll
        for (int r = 0; r < 4; r++) {
            const float v = o[dt][r] * inv;
            uint32 rr = rnebits(v);
            wh[r] = (unsigned short)(rr >> 16);
            wl[r] = f2bf(v - __uint_as_float(rr & 0xffff0000u));
        }
        *(ushort4v*)(ch + coff + dt * 16) = wh;
        *(ushort4v*)(cl + coff + dt * 16) = wl;
    }
}

__global__ void prefix_k(const int* __restrict__ cnt, int* __restrict__ pb) {
    if (threadIdx.x == 0 && blockIdx.x == 0) {
        int s = 0;
        for (int e = 0; e < CE; e++) { pb[e] = s; s += cnt[e]; }
    }
}

// ---------------- launch ----------------
extern "C" void kernel_launch(void* const* d_in, const int* in_sizes, int n_in,
                              void* d_out, int out_size, void* d_ws, size_t ws_size,
                              hipStream_t stream) {
    (void)in_sizes; (void)n_in; (void)out_size; (void)ws_size;
    const float* hidden = (const float*)d_in[0];
    const int*   posids = (const int*)d_in[1];
    const float* rms1w  = (const float*)d_in[2];
    const float* rms2w  = (const float*)d_in[3];
    const float* qw     = (const float*)d_in[4];
    const float* kw     = (const float*)d_in[5];
    const float* vw     = (const float*)d_in[6];
    const float* ow     = (const float*)d_in[7];
    const float* rw     = (const float*)d_in[8];
    const float* w1     = (const float*)d_in[9];
    const float* w2     = (const float*)d_in[10];
    const float* w3     = (const float*)d_in[11];
    float* out = (float*)d_out;

    char* ws = (char*)d_ws;
    unsigned short* h1h = (unsigned short*)ws;
    unsigned short* h1l = (unsigned short*)(ws + 16777216);
    unsigned short* woh = (unsigned short*)ws;
    unsigned short* wol = (unsigned short*)(ws + 8388608);
    unsigned short* h2  = (unsigned short*)ws;
    int*   tok  = (int*)(ws + 16777216);
    float* gate = (float*)(ws + 16777216 + 131072);
    int*   cnt  = (int*)(ws + 16777216 + 262144);
    int*   pb   = cnt + 16;
    unsigned short* qkvh = (unsigned short*)(ws + 33554432);
    unsigned short* qkvl = (unsigned short*)(ws + 83886080);
    unsigned short* wt13 = (unsigned short*)(ws + 33554432);
    unsigned short* wt2  = (unsigned short*)(ws + 33554432);
    unsigned short* wqkvh = (unsigned short*)(ws + 134217728);
    unsigned short* wqkvl = (unsigned short*)(ws + 134217728 + 25165824);
    unsigned short* ctxh = (unsigned short*)(ws + 134217728);
    unsigned short* ctxl = (unsigned short*)(ws + 150994944);
    float*          res2 = (float*)(ws + 167772160);
    unsigned short* Hbuf = (unsigned short*)(ws + 167772160);
    float2*         rtab = (float2*)(ws + 201326592);

    rope_tab_k<<<512, 256, 0, stream>>>(rtab);
    rmsnorm_k<<<CT, 256, 0, stream>>>(hidden, rms1w, h1h, h1l);
    convs_k<3><<<dim3(32, 32, 3), 256, 0, stream>>>(qw, kw, vw, wqkvh, wqkvl);
    sgemm_k<0><<<dim3(32, 48), 256, 0, stream>>>(h1h, h1l, CH, wqkvh, wqkvl, CH,
                                                 qkvh, qkvl, nullptr, CQKV, nullptr, nullptr);
    rope_k<<<2048, 256, 0, stream>>>(qkvh, qkvl, posids, rtab);
    convs_k<1><<<dim3(32, 32, 1), 256, 0, stream>>>(ow, nullptr, nullptr, woh, wol);
    attn_k<<<1024, 256, 0, stream>>>(qkvh, qkvl, ctxh, ctxl);
    sgemm_k<1><<<dim3(32, 16), 256, 0, stream>>>(ctxh, ctxl, CH, woh, wol, CH,
                                                 nullptr, nullptr, res2, CH, hidden, out);
    hipMemsetAsync(cnt, 0, 8 * sizeof(int), stream);
    rmsrouter_k<<<CT, 256, 0, stream>>>(res2, rms2w, rw, h2, cnt, tok, gate);
    prefix_k<<<1, 64, 0, stream>>>(cnt, pb);
    conv_k<2><<<dim3(32, 32, CE), 256, 0, stream>>>(w1, w3, wt13);
    gemm_k<2><<<dim3(32, 32, CE), 256, 0, stream>>>(h2, CH, wt13, CH, 2 * CI, Hbuf, CI,
                                                    cnt, tok, gate, pb);
    conv_k<1><<<dim3(32, 32, CE), 256, 0, stream>>>(w2, nullptr, wt2);
    gemm_k<3><<<dim3(16, 32, CE), 256, 0, stream>>>(Hbuf, CI, wt2, CI, CH, out, CH,
                                                    cnt, tok, gate, pb);
}

// Round 10
// 1382.005 us; speedup vs baseline: 1.1020x; 1.0174x over previous
//
#include <hip/hip_runtime.h>
#include <hip/hip_bf16.h>

// ---------------- constants ----------------
constexpr int CB   = 2;
constexpr int CS   = 2048;
constexpr int CH   = 2048;
constexpr int CNH  = 16;
constexpr int CHD  = 128;
constexpr int CE   = 8;
constexpr int CI   = 2048;
constexpr int CT   = CB * CS;
constexpr int CQKV = 3 * CH;

typedef __attribute__((ext_vector_type(8))) short short8;
typedef __attribute__((ext_vector_type(4))) float float4v;
typedef __attribute__((ext_vector_type(4))) unsigned short ushort4v;
typedef unsigned int uint32;

__device__ __forceinline__ float bf2f(unsigned short u) {
    union { unsigned int i; float f; } x; x.i = ((unsigned int)u) << 16; return x.f;
}
__device__ __forceinline__ unsigned short f2bf(float f) {
    union { float f; unsigned int i; } x; x.f = f;
    unsigned int r = x.i + 0x7fffu + ((x.i >> 16) & 1u);
    return (unsigned short)(r >> 16);
}
__device__ __forceinline__ uint32 packpair(uint32 r0, uint32 r1) {
    return __builtin_amdgcn_perm(r1, r0, 0x07060302u);
}
__device__ __forceinline__ uint32 rnebits(float f) {
    uint32 u = __float_as_uint(f);
    return u + 0x7fffu + ((u >> 16) & 1u);
}
__device__ __forceinline__ void split2(float f0, float f1, uint32& h, uint32& l) {
    uint32 r0 = rnebits(f0), r1 = rnebits(f1);
    h = packpair(r0, r1);
    float d0 = f0 - __uint_as_float(r0 & 0xffff0000u);
    float d1 = f1 - __uint_as_float(r1 & 0xffff0000u);
    l = packpair(rnebits(d0), rnebits(d1));
}
__device__ __forceinline__ void rne16_store(const float* fv, unsigned short* dst) {
    uint32 h[8];
    #pragma unroll
    for (int p = 0; p < 8; p++) h[p] = packpair(rnebits(fv[2 * p]), rnebits(fv[2 * p + 1]));
    ((uint4*)dst)[0] = make_uint4(h[0], h[1], h[2], h[3]);
    ((uint4*)dst)[1] = make_uint4(h[4], h[5], h[6], h[7]);
}
// async global->LDS: 16B per lane, lds dest = uniform base + lane*16
__device__ __forceinline__ void gl16(const void* g, void* l) {
    __builtin_amdgcn_global_load_lds(
        (const __attribute__((address_space(1))) void*)g,
        (__attribute__((address_space(3))) void*)l, 16, 0, 0);
}

// ---------------- RMSNorm (hi/lo split out) ----------
__global__ __launch_bounds__(256) void rmsnorm_k(const float* __restrict__ x,
                                                 const float* __restrict__ w,
                                                 unsigned short* __restrict__ o1,
                                                 unsigned short* __restrict__ o2) {
    const int row = blockIdx.x;
    const float* xr = x + (size_t)row * CH;
    const int base = threadIdx.x * 8;
    float4 v0 = *(const float4*)(xr + base);
    float4 v1 = *(const float4*)(xr + base + 4);
    float ss = v0.x*v0.x + v0.y*v0.y + v0.z*v0.z + v0.w*v0.w
             + v1.x*v1.x + v1.y*v1.y + v1.z*v1.z + v1.w*v1.w;
    #pragma unroll
    for (int o = 1; o < 64; o <<= 1) ss += __shfl_xor(ss, o);
    __shared__ float ps[4];
    if ((threadIdx.x & 63) == 0) ps[threadIdx.x >> 6] = ss;
    __syncthreads();
    const float scale = rsqrtf((ps[0] + ps[1] + ps[2] + ps[3]) / (float)CH + 1e-5f);
    float4 w0 = *(const float4*)(w + base);
    float4 w1 = *(const float4*)(w + base + 4);
    float r[8] = {v0.x * scale * w0.x, v0.y * scale * w0.y, v0.z * scale * w0.z, v0.w * scale * w0.w,
                  v1.x * scale * w1.x, v1.y * scale * w1.y, v1.z * scale * w1.z, v1.w * scale * w1.w};
    uint32 h[4], l[4];
    #pragma unroll
    for (int p = 0; p < 4; p++) split2(r[2 * p], r[2 * p + 1], h[p], l[p]);
    *(uint4*)(o1 + (size_t)row * CH + base) = make_uint4(h[0], h[1], h[2], h[3]);
    *(uint4*)(o2 + (size_t)row * CH + base) = make_uint4(l[0], l[1], l[2], l[3]);
}

// ---------------- fused RMSNorm2 + router ----------------
__global__ __launch_bounds__(256) void rmsrouter_k(const float* __restrict__ x,
                                                   const float* __restrict__ w,
                                                   const float* __restrict__ rw,
                                                   unsigned short* __restrict__ h2,
                                                   int* __restrict__ cnt,
                                                   int* __restrict__ tok,
                                                   float* __restrict__ gate) {
    const int row = blockIdx.x;
    const float* xr = x + (size_t)row * CH;
    const int base = threadIdx.x * 8;
    float4 v0 = *(const float4*)(xr + base);
    float4 v1 = *(const float4*)(xr + base + 4);
    float ss = v0.x*v0.x + v0.y*v0.y + v0.z*v0.z + v0.w*v0.w
             + v1.x*v1.x + v1.y*v1.y + v1.z*v1.z + v1.w*v1.w;
    #pragma unroll
    for (int o = 1; o < 64; o <<= 1) ss += __shfl_xor(ss, o);
    __shared__ float ps[4];
    __shared__ double dacc[4][8];
    const int wave = threadIdx.x >> 6, lane = threadIdx.x & 63;
    if (lane == 0) ps[wave] = ss;
    __syncthreads();
    const float scale = rsqrtf((ps[0] + ps[1] + ps[2] + ps[3]) / (float)CH + 1e-5f);
    float4 w0 = *(const float4*)(w + base);
    float4 w1 = *(const float4*)(w + base + 4);
    float r[8] = {v0.x * scale * w0.x, v0.y * scale * w0.y, v0.z * scale * w0.z, v0.w * scale * w0.w,
                  v1.x * scale * w1.x, v1.y * scale * w1.y, v1.z * scale * w1.z, v1.w * scale * w1.w};
    rne16_store(r, h2 + (size_t)row * CH + base);
    const float vv[8] = {v0.x, v0.y, v0.z, v0.w, v1.x, v1.y, v1.z, v1.w};
    const float ww[8] = {w0.x, w0.y, w0.z, w0.w, w1.x, w1.y, w1.z, w1.w};
    double acc[8] = {0, 0, 0, 0, 0, 0, 0, 0};
    #pragma unroll
    for (int jj = 0; jj < 8; jj++) {
        const double xn = (double)vv[jj] * (double)ww[jj];
        const float* rr = rw + (size_t)(base + jj) * CE;
        #pragma unroll
        for (int e = 0; e < 8; e++) acc[e] += xn * (double)rr[e];
    }
    #pragma unroll
    for (int e = 0; e < 8; e++) {
        #pragma unroll
        for (int o = 1; o < 64; o <<= 1) acc[e] += __shfl_xor(acc[e], o);
    }
    if (lane == 0) {
        #pragma unroll
        for (int e = 0; e < 8; e++) dacc[wave][e] = acc[e];
    }
    __syncthreads();
    if (threadIdx.x == 0) {
        double a[8];
        #pragma unroll
        for (int e = 0; e < 8; e++) a[e] = dacc[0][e] + dacc[1][e] + dacc[2][e] + dacc[3][e];
        int e0 = 0;
        #pragma unroll
        for (int e = 1; e < 8; e++) if (a[e] > a[e0]) e0 = e;
        int e1 = (e0 == 0) ? 1 : 0;
        #pragma unroll
        for (int e = 0; e < 8; e++) if (e != e0 && a[e] > a[e1]) e1 = e;
        const double dl = (double)scale * (a[e1] - a[e0]);   // <= 0
        const double p1r = exp(dl);
        const float g0 = (float)(1.0 / (1.0 + p1r));
        const float g1 = (float)(p1r / (1.0 + p1r));
        int pos0 = atomicAdd(&cnt[e0], 1);
        tok[e0 * 4096 + pos0] = row; gate[e0 * 4096 + pos0] = g0;
        int pos1 = atomicAdd(&cnt[e1], 1);
        tok[e1 * 4096 + pos1] = row; gate[e1 * 4096 + pos1] = g1;
    }
}

// ---------------- RoPE table ----
__global__ void rope_tab_k(float2* __restrict__ tab) {
    int i = blockIdx.x * 256 + threadIdx.x;
    int p = i >> 6, j = i & 63;
    double inv = pow(10000.0, -(double)j / 64.0);
    float invf = (float)inv;
    float angf = (float)p * invf;
    double da = (double)angf;
    tab[i] = make_float2((float)cos(da), (float)sin(da));
}

// ---------------- RoPE vectorized ----------------
__global__ __launch_bounds__(256) void rope_k(unsigned short* __restrict__ qh,
                                              unsigned short* __restrict__ ql,
                                              const int* __restrict__ pos,
                                              const float2* __restrict__ tab) {
    int i = blockIdx.x * 256 + threadIdx.x;  // CT*16*8
    if (i >= CT * CNH * 8) return;
    int t = i >> 7, r = i & 127, hh = r >> 3, jo = (r & 7) << 3;
    const float2* tp = tab + (size_t)pos[t] * 64 + jo;
    float4 tc0 = ((const float4*)tp)[0];
    float4 tc1 = ((const float4*)tp)[1];
    float4 tc2 = ((const float4*)tp)[2];
    float4 tc3 = ((const float4*)tp)[3];
    float cx[8] = {tc0.x, tc0.z, tc1.x, tc1.z, tc2.x, tc2.z, tc3.x, tc3.z};
    float cy[8] = {tc0.y, tc0.w, tc1.y, tc1.w, tc2.y, tc2.w, tc3.y, tc3.w};
    const size_t off = (size_t)t * CQKV + hh * CHD + jo;
    #pragma unroll
    for (int s = 0; s < 2; s++) {
        unsigned short* hp = qh + off + s * CH;
        unsigned short* lp = ql + off + s * CH;
        short8 x1h = *(short8*)hp,        x1l = *(short8*)lp;
        short8 x2h = *(short8*)(hp + 64), x2l = *(short8*)(lp + 64);
        const unsigned short* p1h = (const unsigned short*)&x1h;
        const unsigned short* p1l = (const unsigned short*)&x1l;
        const unsigned short* p2h = (const unsigned short*)&x2h;
        const unsigned short* p2l = (const unsigned short*)&x2l;
        short8 y1h, y1l, y2h, y2l;
        unsigned short* q1h = (unsigned short*)&y1h;
        unsigned short* q1l = (unsigned short*)&y1l;
        unsigned short* q2h = (unsigned short*)&y2h;
        unsigned short* q2l = (unsigned short*)&y2l;
        #pragma unroll
        for (int jj = 0; jj < 8; jj++) {
            const float x1 = bf2f(p1h[jj]) + bf2f(p1l[jj]);
            const float x2 = bf2f(p2h[jj]) + bf2f(p2l[jj]);
            const float yy1 = x1 * cx[jj] - x2 * cy[jj];
            const float yy2 = x2 * cx[jj] + x1 * cy[jj];
            const uint32 r1 = rnebits(yy1), r2 = rnebits(yy2);
            q1h[jj] = (unsigned short)(r1 >> 16);
            q2h[jj] = (unsigned short)(r2 >> 16);
            q1l[jj] = f2bf(yy1 - __uint_as_float(r1 & 0xffff0000u));
            q2l[jj] = f2bf(yy2 - __uint_as_float(r2 & 0xffff0000u));
        }
        *(short8*)hp        = y1h;
        *(short8*)(hp + 64) = y2h;
        *(short8*)lp        = y1l;
        *(short8*)(lp + 64) = y2l;
    }
}

// ---------------- weight transpose+convert: src[K][N] f32 -> dst[N][K] bf16 ----
template<int NMAT>
__global__ __launch_bounds__(256) void conv_k(const float* __restrict__ S0,
                                              const float* __restrict__ S1,
                                              unsigned short* __restrict__ D) {
    __shared__ float t[64][65];
    const int n0 = blockIdx.x * 64, k0 = blockIdx.y * 64, e = blockIdx.z;
    const size_t esrc = (size_t)e * 2048 * 2048;
    const int cc = threadIdx.x & 63, r4 = threadIdx.x >> 6;
    const int nl = threadIdx.x >> 2, q = threadIdx.x & 3;
    #pragma unroll
    for (int s = 0; s < NMAT; s++) {
        const float* S = s ? S1 : S0;
        __syncthreads();
        #pragma unroll
        for (int j = 0; j < 16; j++) {
            const int row = j * 4 + r4;
            t[cc][row] = S[esrc + (size_t)(k0 + row) * 2048 + n0 + cc];
        }
        __syncthreads();
        const int orow = (NMAT == 2) ? (2 * (n0 + nl) + s) : (n0 + nl);
        unsigned short* dp = D + (size_t)e * (NMAT * 2048) * 2048 + (size_t)orow * 2048 + k0 + q * 16;
        float fv[16];
        #pragma unroll
        for (int j = 0; j < 16; j++) fv[j] = t[nl][q * 16 + j];
        rne16_store(fv, dp);
    }
}

// ---------------- weight transpose + hi/lo SPLIT convert --------------------
template<int NMAT>
__global__ __launch_bounds__(256) void convs_k(const float* __restrict__ S0,
                                               const float* __restrict__ S1,
                                               const float* __restrict__ S2,
                                               unsigned short* __restrict__ Dh,
                                               unsigned short* __restrict__ Dl) {
    __shared__ float t[64][65];
    const int n0 = blockIdx.x * 64, k0 = blockIdx.y * 64, z = blockIdx.z;
    const float* S = S0;
    if (NMAT == 3) S = (z == 0) ? S0 : ((z == 1) ? S1 : S2);
    const int cc = threadIdx.x & 63, r4 = threadIdx.x >> 6;
    #pragma unroll
    for (int j = 0; j < 16; j++) {
        const int row = j * 4 + r4;
        t[cc][row] = S[(size_t)(k0 + row) * 2048 + n0 + cc];
    }
    __syncthreads();
    const int nl = threadIdx.x >> 2, q = threadIdx.x & 3;
    float fv[16];
    #pragma unroll
    for (int j = 0; j < 16; j++) fv[j] = t[nl][q * 16 + j];
    uint32 h[8], l[8];
    #pragma unroll
    for (int p = 0; p < 8; p++) split2(fv[2 * p], fv[2 * p + 1], h[p], l[p]);
    const size_t off = (size_t)(z * 2048 + n0 + nl) * 2048 + k0 + q * 16;
    ((uint4*)(Dh + off))[0] = make_uint4(h[0], h[1], h[2], h[3]);
    ((uint4*)(Dh + off))[1] = make_uint4(h[4], h[5], h[6], h[7]);
    ((uint4*)(Dl + off))[0] = make_uint4(l[0], l[1], l[2], l[3]);
    ((uint4*)(Dl + off))[1] = make_uint4(l[4], l[5], l[6], l[7]);
}

// ---------------- precise split-bf16 GEMM, global_load_lds staging ------------
// Linear LDS [128][32] shorts per plane (64B rows) — DMA-written, conflict-free reads.
template<int MODE>
__global__ __launch_bounds__(256) void sgemm_k(
    const unsigned short* __restrict__ Ahg, const unsigned short* __restrict__ Alg, int lda,
    const unsigned short* __restrict__ Bhg, const unsigned short* __restrict__ Blg, int K,
    unsigned short* __restrict__ Ch, unsigned short* __restrict__ Cl,
    float* __restrict__ Cf, int ldc,
    const float* __restrict__ resid, float* __restrict__ C2) {
    __shared__ unsigned short AhS[128 * 32], AlS[128 * 32], BhS[128 * 32], BlS[128 * 32];
    const int mt = blockIdx.x, nt = blockIdx.y, tid = threadIdx.x;
    const int m0 = mt * 128;
    const int wave = tid >> 6, lane = tid & 63;
    const int lr = lane & 15, lg = lane >> 4;
    const int wr = (tid >> 7) & 1, wc = (tid >> 6) & 1;
    // staging geometry: wave handles rows [wave*32, wave*32+32) of each plane
    const int sr = lane >> 2;            // 0..15
    const int sc = (lane & 3) * 8;       // shorts
    const int r0 = wave * 32;
    const unsigned short* gAh = Ahg + (size_t)(m0 + r0 + sr) * lda + sc;
    const unsigned short* gAl = Alg + (size_t)(m0 + r0 + sr) * lda + sc;
    const unsigned short* gBh = Bhg + (size_t)(nt * 128 + r0 + sr) * K + sc;
    const unsigned short* gBl = Blg + (size_t)(nt * 128 + r0 + sr) * K + sc;
    const size_t rstepA = (size_t)16 * lda, rstepB = (size_t)16 * K;
    unsigned short* lAh = AhS + r0 * 32;
    unsigned short* lAl = AlS + r0 * 32;
    unsigned short* lBh = BhS + r0 * 32;
    unsigned short* lBl = BlS + r0 * 32;

    float4v acc[4][4];
    #pragma unroll
    for (int m = 0; m < 4; m++)
        #pragma unroll
        for (int n = 0; n < 4; n++) acc[m][n] = (float4v){0.f, 0.f, 0.f, 0.f};

    for (int k0 = 0; k0 < K; k0 += 32) {
        __syncthreads();
        gl16(gAh + k0, lAh);            gl16(gAh + k0 + rstepA, lAh + 512);
        gl16(gAl + k0, lAl);            gl16(gAl + k0 + rstepA, lAl + 512);
        gl16(gBh + k0, lBh);            gl16(gBh + k0 + rstepB, lBh + 512);
        gl16(gBl + k0, lBl);            gl16(gBl + k0 + rstepB, lBl + 512);
        __syncthreads();
        short8 fah[4], fal[4], fbh[4], fbl[4];
        #pragma unroll
        for (int m = 0; m < 4; m++) {
            fah[m] = *(const short8*)(AhS + (wr * 64 + m * 16 + lr) * 32 + lg * 8);
            fal[m] = *(const short8*)(AlS + (wr * 64 + m * 16 + lr) * 32 + lg * 8);
        }
        #pragma unroll
        for (int n = 0; n < 4; n++) {
            fbh[n] = *(const short8*)(BhS + (wc * 64 + n * 16 + lr) * 32 + lg * 8);
            fbl[n] = *(const short8*)(BlS + (wc * 64 + n * 16 + lr) * 32 + lg * 8);
        }
        #pragma unroll
        for (int n = 0; n < 4; n++)
            #pragma unroll
            for (int m = 0; m < 4; m++) {
                acc[m][n] = __builtin_amdgcn_mfma_f32_16x16x32_bf16(fal[m], fbh[n], acc[m][n], 0, 0, 0);
                acc[m][n] = __builtin_amdgcn_mfma_f32_16x16x32_bf16(fah[m], fbl[n], acc[m][n], 0, 0, 0);
                acc[m][n] = __builtin_amdgcn_mfma_f32_16x16x32_bf16(fah[m], fbh[n], acc[m][n], 0, 0, 0);
            }
    }
    #pragma unroll
    for (int m = 0; m < 4; m++) {
        const int rb = wr * 64 + m * 16 + (lane >> 4) * 4;
        #pragma unroll
        for (int n = 0; n < 4; n++) {
            const int ccol = nt * 128 + wc * 64 + n * 16 + lr;
            #pragma unroll
            for (int r = 0; r < 4; r++) {
                const size_t idx = (size_t)(m0 + rb + r) * ldc + ccol;
                if (MODE == 1) {
                    const float v = acc[m][n][r] + resid[idx];
                    Cf[idx] = v;
                    C2[idx] = v;
                } else {
                    const float v = acc[m][n][r];
                    uint32 rr = rnebits(v);
                    Ch[idx] = (unsigned short)(rr >> 16);
                    Cl[idx] = f2bf(v - __uint_as_float(rr & 0xffff0000u));
                }
            }
        }
    }
}

// ---------------- MoE GEMM, global_load_lds staging ----
template<int MODE>
__global__ __launch_bounds__(256) void gemm_k(
    const unsigned short* __restrict__ A, int lda,
    const unsigned short* __restrict__ Bt, int K, int Ne,
    void* __restrict__ Cp, int ldc,
    const int* __restrict__ cnt, const int* __restrict__ tokl,
    const float* __restrict__ gatel, const int* __restrict__ pb) {
    __shared__ unsigned short As[128 * 32];
    __shared__ unsigned short Bs[128 * 32];
    const int nt = blockIdx.x, mt = blockIdx.y, e = blockIdx.z;
    const int m0 = mt * 128;
    const int c = cnt[e];
    if (m0 >= c) return;
    const int valid = (c - m0 < 128) ? (c - m0) : 128;
    const int tid = threadIdx.x;
    const int wave = tid >> 6, lane = tid & 63;
    const int lr = lane & 15;
    const int wr = (tid >> 7) & 1, wc = (tid >> 6) & 1;
    const int sr = lane >> 2, sc = (lane & 3) * 8;
    const int r0 = wave * 32;
    // gathered A rows (two 16-row groups per wave)
    size_t gr0, gr1;
    {
        int ra = r0 + sr, rb2 = r0 + 16 + sr;
        if (MODE == 2) {
            ra = ra < valid ? ra : valid - 1;
            rb2 = rb2 < valid ? rb2 : valid - 1;
            gr0 = (size_t)tokl[e * 4096 + m0 + ra];
            gr1 = (size_t)tokl[e * 4096 + m0 + rb2];
        } else {
            int x0 = m0 + ra, x1 = m0 + rb2;
            gr0 = (size_t)(pb[e] + (x0 < c ? x0 : c - 1));
            gr1 = (size_t)(pb[e] + (x1 < c ? x1 : c - 1));
        }
    }
    const unsigned short* gA0 = A + gr0 * (size_t)lda + sc;
    const unsigned short* gA1 = A + gr1 * (size_t)lda + sc;
    const unsigned short* gB = Bt + (size_t)e * Ne * K + (size_t)(nt * 128 + r0 + sr) * K + sc;
    const size_t rstepB = (size_t)16 * K;
    unsigned short* lA = As + r0 * 32;
    unsigned short* lB = Bs + r0 * 32;

    float4v acc[4][4];
    #pragma unroll
    for (int m = 0; m < 4; m++)
        #pragma unroll
        for (int n = 0; n < 4; n++) acc[m][n] = (float4v){0.f, 0.f, 0.f, 0.f};

    for (int k0 = 0; k0 < K; k0 += 32) {
        __syncthreads();
        gl16(gA0 + k0, lA);             gl16(gA1 + k0, lA + 512);
        gl16(gB + k0, lB);              gl16(gB + k0 + rstepB, lB + 512);
        __syncthreads();
        short8 af[4], bf[4];
        const int lg = lane >> 4;
        #pragma unroll
        for (int m = 0; m < 4; m++) af[m] = *(const short8*)(As + (wr * 64 + m * 16 + lr) * 32 + lg * 8);
        #pragma unroll
        for (int n = 0; n < 4; n++) bf[n] = *(const short8*)(Bs + (wc * 64 + n * 16 + lr) * 32 + lg * 8);
        #pragma unroll
        for (int n = 0; n < 4; n++)
            #pragma unroll
            for (int m = 0; m < 4; m++)
                acc[m][n] = __builtin_amdgcn_mfma_f32_16x16x32_bf16(af[m], bf[n], acc[m][n], 0, 0, 0);
    }

    #pragma unroll
    for (int m = 0; m < 4; m++) {
        const int rb = wr * 64 + m * 16 + (lane >> 4) * 4;
        #pragma unroll
        for (int n = 0; n < 4; n++) {
            const int col = nt * 128 + wc * 64 + n * 16 + lr;
            #pragma unroll
            for (int r = 0; r < 4; r++) {
                const int row = rb + r;
                const float v = acc[m][n][r];
                if (MODE == 2) {
                    const float other = __shfl_xor(v, 1);
                    if (!(lr & 1) && row < valid) {
                        const float g1 = v, g3 = other;
                        const float hsw = (g1 / (1.f + __expf(-g1))) * g3;
                        ((unsigned short*)Cp)[(size_t)(pb[e] + m0 + row) * ldc + (col >> 1)] = f2bf(hsw);
                    }
                } else {
                    if (row < valid) {
                        const int t = tokl[e * 4096 + m0 + row];
                        const float g = gatel[e * 4096 + m0 + row];
                        atomicAdd(((float*)Cp) + (size_t)t * ldc + col, v * g);
                    }
                }
            }
        }
    }
}

// ---------------- flash attention, split-bf16, XCD-pinned + prefetch ----------
__global__ __launch_bounds__(256) void attn_k(const unsigned short* __restrict__ qh,
                                              const unsigned short* __restrict__ ql,
                                              unsigned short* __restrict__ ch,
                                              unsigned short* __restrict__ cl) {
    __shared__ unsigned short Ksh[32][136], Ksl[32][136];
    __shared__ unsigned short Vth[128][40], Vtl[128][40];
    const int bid = blockIdx.x;          // 1024 blocks
    const int xcd = bid & 7, jj = bid >> 3;
    const int bh  = xcd * 4 + (jj >> 5);
    const int qb  = 31 - (jj & 31);
    const int h   = bh & 15, b = bh >> 4;
    const int tid = threadIdx.x;
    const int wave = tid >> 6, lane = tid & 63, lr = lane & 15, lg = lane >> 4;
    const size_t tb = (size_t)b * CS;
    const int q0 = qb * 64 + wave * 16;

    short8 qfh[4], qfl[4];
    {
        const size_t off = (tb + q0 + lr) * CQKV + h * CHD;
        #pragma unroll
        for (int c = 0; c < 4; c++) {
            qfh[c] = *(const short8*)(qh + off + c * 32 + lg * 8);
            qfl[c] = *(const short8*)(ql + off + c * 32 + lg * 8);
        }
    }
    float4v o[8];
    #pragma unroll
    for (int d = 0; d < 8; d++) o[d] = (float4v){0.f, 0.f, 0.f, 0.f};
    float m = -1e30f, l = 0.f;
    const float scl = 0.08838834764831845f;
    const int ntiles = 2 * (qb + 1);
    const int kk = tid >> 3, slot = tid & 7;
    const int vd = tid & 127, vhalf = tid >> 7;

    short8 pkh0, pkh1, pkl0, pkl1;
    unsigned short pth[16], ptl[16];
    {
        const size_t koff = (tb + kk) * CQKV + CH + h * CHD + slot * 16;
        pkh0 = *(const short8*)(qh + koff);
        pkh1 = *(const short8*)(qh + koff + 8);
        pkl0 = *(const short8*)(ql + koff);
        pkl1 = *(const short8*)(ql + koff + 8);
        const size_t voff = (tb + vhalf * 16) * CQKV + 2 * CH + h * CHD + vd;
        #pragma unroll
        for (int j = 0; j < 16; j++) {
            pth[j] = qh[voff + (size_t)j * CQKV];
            ptl[j] = ql[voff + (size_t)j * CQKV];
        }
    }

    for (int kt = 0; kt < ntiles; ++kt) {
        const int kv0 = kt * 32;
        __syncthreads();
        *(short8*)(&Ksh[kk][slot * 16])     = pkh0;
        *(short8*)(&Ksh[kk][slot * 16 + 8]) = pkh1;
        *(short8*)(&Ksl[kk][slot * 16])     = pkl0;
        *(short8*)(&Ksl[kk][slot * 16 + 8]) = pkl1;
        #pragma unroll
        for (int p = 0; p < 2; p++) {
            *(ushort4v*)(&Vth[vd][vhalf * 16 + p * 8])     = *(ushort4v*)(&pth[p * 8]);
            *(ushort4v*)(&Vth[vd][vhalf * 16 + p * 8 + 4]) = *(ushort4v*)(&pth[p * 8 + 4]);
            *(ushort4v*)(&Vtl[vd][vhalf * 16 + p * 8])     = *(ushort4v*)(&ptl[p * 8]);
            *(ushort4v*)(&Vtl[vd][vhalf * 16 + p * 8 + 4]) = *(ushort4v*)(&ptl[p * 8 + 4]);
        }
        if (kt + 1 < ntiles) {
            const int nv0 = kv0 + 32;
            const size_t koff = (tb + nv0 + kk) * CQKV + CH + h * CHD + slot * 16;
            pkh0 = *(const short8*)(qh + koff);
            pkh1 = *(const short8*)(qh + koff + 8);
            pkl0 = *(const short8*)(ql + koff);
            pkl1 = *(const short8*)(ql + koff + 8);
            const size_t voff = (tb + nv0 + vhalf * 16) * CQKV + 2 * CH + h * CHD + vd;
            #pragma unroll
            for (int j = 0; j < 16; j++) {
                pth[j] = qh[voff + (size_t)j * CQKV];
                ptl[j] = ql[voff + (size_t)j * CQKV];
            }
        }
        __syncthreads();

        float4v st0 = (float4v){0.f,0.f,0.f,0.f}, st1 = st0;
        #pragma unroll
        for (int c = 0; c < 4; c++) {
            short8 kah = *(const short8*)(&Ksh[lr][c * 32 + lg * 8]);
            short8 kal = *(const short8*)(&Ksl[lr][c * 32 + lg * 8]);
            short8 kbh = *(const short8*)(&Ksh[16 + lr][c * 32 + lg * 8]);
            short8 kbl = *(const short8*)(&Ksl[16 + lr][c * 32 + lg * 8]);
            st0 = __builtin_amdgcn_mfma_f32_16x16x32_bf16(kal, qfh[c], st0, 0, 0, 0);
            st0 = __builtin_amdgcn_mfma_f32_16x16x32_bf16(kah, qfl[c], st0, 0, 0, 0);
            st0 = __builtin_amdgcn_mfma_f32_16x16x32_bf16(kah, qfh[c], st0, 0, 0, 0);
            st1 = __builtin_amdgcn_mfma_f32_16x16x32_bf16(kbl, qfh[c], st1, 0, 0, 0);
            st1 = __builtin_amdgcn_mfma_f32_16x16x32_bf16(kbh, qfl[c], st1, 0, 0, 0);
            st1 = __builtin_amdgcn_mfma_f32_16x16x32_bf16(kbh, qfh[c], st1, 0, 0, 0);
        }
        float pv[8]; float pmax = -1e30f;
        const int qg = q0 + lr;
        #pragma unroll
        for (int f = 0; f < 2; f++) {
            #pragma unroll
            for (int r = 0; r < 4; r++) {
                const int kg = kv0 + f * 16 + lg * 4 + r;
                const float s = (kg <= qg) ? ((f ? st1[r] : st0[r]) * scl) : -1e30f;
                pv[f * 4 + r] = s;
                pmax = fmaxf(pmax, s);
            }
        }
        pmax = fmaxf(pmax, __shfl_xor(pmax, 16));
        pmax = fmaxf(pmax, __shfl_xor(pmax, 32));
        if (!__all(pmax <= m)) {
            const float mnew = fmaxf(m, pmax);
            const float alpha = __expf(m - mnew);
            l *= alpha;
            #pragma unroll
            for (int d = 0; d < 8; d++) o[d] *= alpha;
            m = mnew;
        }
        float sum = 0.f;
        #pragma unroll
        for (int i = 0; i < 8; i++) { const float p = __expf(pv[i] - m); pv[i] = p; sum += p; }
        sum += __shfl_xor(sum, 16);
        sum += __shfl_xor(sum, 32);
        l += sum;
        short8 pfh, pfl;
        unsigned short* pfhp = (unsigned short*)&pfh;
        unsigned short* pflp = (unsigned short*)&pfl;
        #pragma unroll
        for (int j = 0; j < 8; j++) {
            const int srcl = (((lg & 1) * 2 + (j >> 2)) << 4) | lr;
            const float a0 = __shfl(pv[j & 3], srcl);
            const float a1 = __shfl(pv[4 + (j & 3)], srcl);
            const float sel = (lg >= 2) ? a1 : a0;
            uint32 r = rnebits(sel);
            pfhp[j] = (unsigned short)(r >> 16);
            float d = sel - __uint_as_float(r & 0xffff0000u);
            pflp[j] = (unsigned short)(rnebits(d) >> 16);
        }
        #pragma unroll
        for (int dt = 0; dt < 8; dt++) {
            short8 vh = *(const short8*)(&Vth[dt * 16 + lr][lg * 8]);
            short8 vl = *(const short8*)(&Vtl[dt * 16 + lr][lg * 8]);
            o[dt] = __builtin_amdgcn_mfma_f32_16x16x32_bf16(vl, pfh, o[dt], 0, 0, 0);
            o[dt] = __builtin_amdgcn_mfma_f32_16x16x32_bf16(vh, pfl, o[dt], 0, 0, 0);
            o[dt] = __builtin_amdgcn_mfma_f32_16x16x32_bf16(vh, pfh, o[dt], 0, 0, 0);
        }
    }
    const float inv = 1.f / l;
    const size_t coff = (tb + q0 + lr) * CH + h * CHD + lg * 4;
    #pragma unroll
    for (int dt = 0; dt < 8; dt++) {
        ushort4v wh, wl;
        #pragma unroll
        for (int r = 0; r < 4; r++) {
            const float v = o[dt][r] * inv;
            uint32 rr = rnebits(v);
            wh[r] = (unsigned short)(rr >> 16);
            wl[r] = f2bf(v - __uint_as_float(rr & 0xffff0000u));
        }
        *(ushort4v*)(ch + coff + dt * 16) = wh;
        *(ushort4v*)(cl + coff + dt * 16) = wl;
    }
}

__global__ void prefix_k(const int* __restrict__ cnt, int* __restrict__ pb) {
    if (threadIdx.x == 0 && blockIdx.x == 0) {
        int s = 0;
        for (int e = 0; e < CE; e++) { pb[e] = s; s += cnt[e]; }
    }
}

// ---------------- launch ----------------
extern "C" void kernel_launch(void* const* d_in, const int* in_sizes, int n_in,
                              void* d_out, int out_size, void* d_ws, size_t ws_size,
                              hipStream_t stream) {
    (void)in_sizes; (void)n_in; (void)out_size; (void)ws_size;
    const float* hidden = (const float*)d_in[0];
    const int*   posids = (const int*)d_in[1];
    const float* rms1w  = (const float*)d_in[2];
    const float* rms2w  = (const float*)d_in[3];
    const float* qw     = (const float*)d_in[4];
    const float* kw     = (const float*)d_in[5];
    const float* vw     = (const float*)d_in[6];
    const float* ow     = (const float*)d_in[7];
    const float* rw     = (const float*)d_in[8];
    const float* w1     = (const float*)d_in[9];
    const float* w2     = (const float*)d_in[10];
    const float* w3     = (const float*)d_in[11];
    float* out = (float*)d_out;

    char* ws = (char*)d_ws;
    unsigned short* h1h = (unsigned short*)ws;
    unsigned short* h1l = (unsigned short*)(ws + 16777216);
    unsigned short* woh = (unsigned short*)ws;
    unsigned short* wol = (unsigned short*)(ws + 8388608);
    unsigned short* h2  = (unsigned short*)ws;
    int*   tok  = (int*)(ws + 16777216);
    float* gate = (float*)(ws + 16777216 + 131072);
    int*   cnt  = (int*)(ws + 16777216 + 262144);
    int*   pb   = cnt + 16;
    unsigned short* qkvh = (unsigned short*)(ws + 33554432);
    unsigned short* qkvl = (unsigned short*)(ws + 83886080);
    unsigned short* wt13 = (unsigned short*)(ws + 33554432);
    unsigned short* wt2  = (unsigned short*)(ws + 33554432);
    unsigned short* wqkvh = (unsigned short*)(ws + 134217728);
    unsigned short* wqkvl = (unsigned short*)(ws + 134217728 + 25165824);
    unsigned short* ctxh = (unsigned short*)(ws + 134217728);
    unsigned short* ctxl = (unsigned short*)(ws + 150994944);
    float*          res2 = (float*)(ws + 167772160);
    unsigned short* Hbuf = (unsigned short*)(ws + 167772160);
    float2*         rtab = (float2*)(ws + 201326592);

    rope_tab_k<<<512, 256, 0, stream>>>(rtab);
    rmsnorm_k<<<CT, 256, 0, stream>>>(hidden, rms1w, h1h, h1l);
    convs_k<3><<<dim3(32, 32, 3), 256, 0, stream>>>(qw, kw, vw, wqkvh, wqkvl);
    sgemm_k<0><<<dim3(32, 48), 256, 0, stream>>>(h1h, h1l, CH, wqkvh, wqkvl, CH,
                                                 qkvh, qkvl, nullptr, CQKV, nullptr, nullptr);
    rope_k<<<2048, 256, 0, stream>>>(qkvh, qkvl, posids, rtab);
    convs_k<1><<<dim3(32, 32, 1), 256, 0, stream>>>(ow, nullptr, nullptr, woh, wol);
    attn_k<<<1024, 256, 0, stream>>>(qkvh, qkvl, ctxh, ctxl);
    sgemm_k<1><<<dim3(32, 16), 256, 0, stream>>>(ctxh, ctxl, CH, woh, wol, CH,
                                                 nullptr, nullptr, res2, CH, hidden, out);
    hipMemsetAsync(cnt, 0, 8 * sizeof(int), stream);
    rmsrouter_k<<<CT, 256, 0, stream>>>(res2, rms2w, rw, h2, cnt, tok, gate);
    prefix_k<<<1, 64, 0, stream>>>(cnt, pb);
    conv_k<2><<<dim3(32, 32, CE), 256, 0, stream>>>(w1, w3, wt13);
    gemm_k<2><<<dim3(32, 32, CE), 256, 0, stream>>>(h2, CH, wt13, CH, 2 * CI, Hbuf, CI,
                                                    cnt, tok, gate, pb);
    conv_k<1><<<dim3(32, 32, CE), 256, 0, stream>>>(w2, nullptr, wt2);
    gemm_k<3><<<dim3(16, 32, CE), 256, 0, stream>>>(Hbuf, CI, wt2, CI, CH, out, CH,
                                                    cnt, tok, gate, pb);
}

// Round 11
// 1314.893 us; speedup vs baseline: 1.1582x; 1.0510x over previous
//
#include <hip/hip_runtime.h>
#include <hip/hip_bf16.h>

// ---------------- constants ----------------
constexpr int CB   = 2;
constexpr int CS   = 2048;
constexpr int CH   = 2048;
constexpr int CNH  = 16;
constexpr int CHD  = 128;
constexpr int CE   = 8;
constexpr int CI   = 2048;
constexpr int CT   = CB * CS;
constexpr int CQKV = 3 * CH;

typedef __attribute__((ext_vector_type(8))) short short8;
typedef __attribute__((ext_vector_type(4))) float float4v;
typedef __attribute__((ext_vector_type(4))) unsigned short ushort4v;
typedef unsigned int uint32;

__device__ __forceinline__ float bf2f(unsigned short u) {
    union { unsigned int i; float f; } x; x.i = ((unsigned int)u) << 16; return x.f;
}
__device__ __forceinline__ unsigned short f2bf(float f) {
    union { float f; unsigned int i; } x; x.f = f;
    unsigned int r = x.i + 0x7fffu + ((x.i >> 16) & 1u);
    return (unsigned short)(r >> 16);
}
__device__ __forceinline__ uint32 packpair(uint32 r0, uint32 r1) {
    return __builtin_amdgcn_perm(r1, r0, 0x07060302u);
}
__device__ __forceinline__ uint32 rnebits(float f) {
    uint32 u = __float_as_uint(f);
    return u + 0x7fffu + ((u >> 16) & 1u);
}
__device__ __forceinline__ void split2(float f0, float f1, uint32& h, uint32& l) {
    uint32 r0 = rnebits(f0), r1 = rnebits(f1);
    h = packpair(r0, r1);
    float d0 = f0 - __uint_as_float(r0 & 0xffff0000u);
    float d1 = f1 - __uint_as_float(r1 & 0xffff0000u);
    l = packpair(rnebits(d0), rnebits(d1));
}
__device__ __forceinline__ void rne16_store(const float* fv, unsigned short* dst) {
    uint32 h[8];
    #pragma unroll
    for (int p = 0; p < 8; p++) h[p] = packpair(rnebits(fv[2 * p]), rnebits(fv[2 * p + 1]));
    ((uint4*)dst)[0] = make_uint4(h[0], h[1], h[2], h[3]);
    ((uint4*)dst)[1] = make_uint4(h[4], h[5], h[6], h[7]);
}
// async global->LDS: 16B per lane, lds dest = uniform base + lane*16
__device__ __forceinline__ void gl16(const void* g, void* l) {
    __builtin_amdgcn_global_load_lds(
        (const __attribute__((address_space(1))) void*)g,
        (__attribute__((address_space(3))) void*)l, 16, 0, 0);
}

// ---------------- RMSNorm (hi/lo split out) ----------
__global__ __launch_bounds__(256) void rmsnorm_k(const float* __restrict__ x,
                                                 const float* __restrict__ w,
                                                 unsigned short* __restrict__ o1,
                                                 unsigned short* __restrict__ o2) {
    const int row = blockIdx.x;
    const float* xr = x + (size_t)row * CH;
    const int base = threadIdx.x * 8;
    float4 v0 = *(const float4*)(xr + base);
    float4 v1 = *(const float4*)(xr + base + 4);
    float ss = v0.x*v0.x + v0.y*v0.y + v0.z*v0.z + v0.w*v0.w
             + v1.x*v1.x + v1.y*v1.y + v1.z*v1.z + v1.w*v1.w;
    #pragma unroll
    for (int o = 1; o < 64; o <<= 1) ss += __shfl_xor(ss, o);
    __shared__ float ps[4];
    if ((threadIdx.x & 63) == 0) ps[threadIdx.x >> 6] = ss;
    __syncthreads();
    const float scale = rsqrtf((ps[0] + ps[1] + ps[2] + ps[3]) / (float)CH + 1e-5f);
    float4 w0 = *(const float4*)(w + base);
    float4 w1 = *(const float4*)(w + base + 4);
    float r[8] = {v0.x * scale * w0.x, v0.y * scale * w0.y, v0.z * scale * w0.z, v0.w * scale * w0.w,
                  v1.x * scale * w1.x, v1.y * scale * w1.y, v1.z * scale * w1.z, v1.w * scale * w1.w};
    uint32 h[4], l[4];
    #pragma unroll
    for (int p = 0; p < 4; p++) split2(r[2 * p], r[2 * p + 1], h[p], l[p]);
    *(uint4*)(o1 + (size_t)row * CH + base) = make_uint4(h[0], h[1], h[2], h[3]);
    *(uint4*)(o2 + (size_t)row * CH + base) = make_uint4(l[0], l[1], l[2], l[3]);
}

// ---------------- fused RMSNorm2 + router ----------------
__global__ __launch_bounds__(256) void rmsrouter_k(const float* __restrict__ x,
                                                   const float* __restrict__ w,
                                                   const float* __restrict__ rw,
                                                   unsigned short* __restrict__ h2,
                                                   int* __restrict__ cnt,
                                                   int* __restrict__ tok,
                                                   float* __restrict__ gate) {
    const int row = blockIdx.x;
    const float* xr = x + (size_t)row * CH;
    const int base = threadIdx.x * 8;
    float4 v0 = *(const float4*)(xr + base);
    float4 v1 = *(const float4*)(xr + base + 4);
    float ss = v0.x*v0.x + v0.y*v0.y + v0.z*v0.z + v0.w*v0.w
             + v1.x*v1.x + v1.y*v1.y + v1.z*v1.z + v1.w*v1.w;
    #pragma unroll
    for (int o = 1; o < 64; o <<= 1) ss += __shfl_xor(ss, o);
    __shared__ float ps[4];
    __shared__ double dacc[4][8];
    const int wave = threadIdx.x >> 6, lane = threadIdx.x & 63;
    if (lane == 0) ps[wave] = ss;
    __syncthreads();
    const float scale = rsqrtf((ps[0] + ps[1] + ps[2] + ps[3]) / (float)CH + 1e-5f);
    float4 w0 = *(const float4*)(w + base);
    float4 w1 = *(const float4*)(w + base + 4);
    float r[8] = {v0.x * scale * w0.x, v0.y * scale * w0.y, v0.z * scale * w0.z, v0.w * scale * w0.w,
                  v1.x * scale * w1.x, v1.y * scale * w1.y, v1.z * scale * w1.z, v1.w * scale * w1.w};
    rne16_store(r, h2 + (size_t)row * CH + base);
    const float vv[8] = {v0.x, v0.y, v0.z, v0.w, v1.x, v1.y, v1.z, v1.w};
    const float ww[8] = {w0.x, w0.y, w0.z, w0.w, w1.x, w1.y, w1.z, w1.w};
    double acc[8] = {0, 0, 0, 0, 0, 0, 0, 0};
    #pragma unroll
    for (int jj = 0; jj < 8; jj++) {
        const double xn = (double)vv[jj] * (double)ww[jj];
        const float* rr = rw + (size_t)(base + jj) * CE;
        #pragma unroll
        for (int e = 0; e < 8; e++) acc[e] += xn * (double)rr[e];
    }
    #pragma unroll
    for (int e = 0; e < 8; e++) {
        #pragma unroll
        for (int o = 1; o < 64; o <<= 1) acc[e] += __shfl_xor(acc[e], o);
    }
    if (lane == 0) {
        #pragma unroll
        for (int e = 0; e < 8; e++) dacc[wave][e] = acc[e];
    }
    __syncthreads();
    if (threadIdx.x == 0) {
        double a[8];
        #pragma unroll
        for (int e = 0; e < 8; e++) a[e] = dacc[0][e] + dacc[1][e] + dacc[2][e] + dacc[3][e];
        int e0 = 0;
        #pragma unroll
        for (int e = 1; e < 8; e++) if (a[e] > a[e0]) e0 = e;
        int e1 = (e0 == 0) ? 1 : 0;
        #pragma unroll
        for (int e = 0; e < 8; e++) if (e != e0 && a[e] > a[e1]) e1 = e;
        const double dl = (double)scale * (a[e1] - a[e0]);   // <= 0
        const double p1r = exp(dl);
        const float g0 = (float)(1.0 / (1.0 + p1r));
        const float g1 = (float)(p1r / (1.0 + p1r));
        int pos0 = atomicAdd(&cnt[e0], 1);
        tok[e0 * 4096 + pos0] = row; gate[e0 * 4096 + pos0] = g0;
        int pos1 = atomicAdd(&cnt[e1], 1);
        tok[e1 * 4096 + pos1] = row; gate[e1 * 4096 + pos1] = g1;
    }
}

// ---------------- RoPE table ----
__global__ void rope_tab_k(float2* __restrict__ tab) {
    int i = blockIdx.x * 256 + threadIdx.x;
    int p = i >> 6, j = i & 63;
    double inv = pow(10000.0, -(double)j / 64.0);
    float invf = (float)inv;
    float angf = (float)p * invf;
    double da = (double)angf;
    tab[i] = make_float2((float)cos(da), (float)sin(da));
}

// ---------------- RoPE vectorized ----------------
__global__ __launch_bounds__(256) void rope_k(unsigned short* __restrict__ qh,
                                              unsigned short* __restrict__ ql,
                                              const int* __restrict__ pos,
                                              const float2* __restrict__ tab) {
    int i = blockIdx.x * 256 + threadIdx.x;  // CT*16*8
    if (i >= CT * CNH * 8) return;
    int t = i >> 7, r = i & 127, hh = r >> 3, jo = (r & 7) << 3;
    const float2* tp = tab + (size_t)pos[t] * 64 + jo;
    float4 tc0 = ((const float4*)tp)[0];
    float4 tc1 = ((const float4*)tp)[1];
    float4 tc2 = ((const float4*)tp)[2];
    float4 tc3 = ((const float4*)tp)[3];
    float cx[8] = {tc0.x, tc0.z, tc1.x, tc1.z, tc2.x, tc2.z, tc3.x, tc3.z};
    float cy[8] = {tc0.y, tc0.w, tc1.y, tc1.w, tc2.y, tc2.w, tc3.y, tc3.w};
    const size_t off = (size_t)t * CQKV + hh * CHD + jo;
    #pragma unroll
    for (int s = 0; s < 2; s++) {
        unsigned short* hp = qh + off + s * CH;
        unsigned short* lp = ql + off + s * CH;
        short8 x1h = *(short8*)hp,        x1l = *(short8*)lp;
        short8 x2h = *(short8*)(hp + 64), x2l = *(short8*)(lp + 64);
        const unsigned short* p1h = (const unsigned short*)&x1h;
        const unsigned short* p1l = (const unsigned short*)&x1l;
        const unsigned short* p2h = (const unsigned short*)&x2h;
        const unsigned short* p2l = (const unsigned short*)&x2l;
        short8 y1h, y1l, y2h, y2l;
        unsigned short* q1h = (unsigned short*)&y1h;
        unsigned short* q1l = (unsigned short*)&y1l;
        unsigned short* q2h = (unsigned short*)&y2h;
        unsigned short* q2l = (unsigned short*)&y2l;
        #pragma unroll
        for (int jj = 0; jj < 8; jj++) {
            const float x1 = bf2f(p1h[jj]) + bf2f(p1l[jj]);
            const float x2 = bf2f(p2h[jj]) + bf2f(p2l[jj]);
            const float yy1 = x1 * cx[jj] - x2 * cy[jj];
            const float yy2 = x2 * cx[jj] + x1 * cy[jj];
            const uint32 r1 = rnebits(yy1), r2 = rnebits(yy2);
            q1h[jj] = (unsigned short)(r1 >> 16);
            q2h[jj] = (unsigned short)(r2 >> 16);
            q1l[jj] = f2bf(yy1 - __uint_as_float(r1 & 0xffff0000u));
            q2l[jj] = f2bf(yy2 - __uint_as_float(r2 & 0xffff0000u));
        }
        *(short8*)hp        = y1h;
        *(short8*)(hp + 64) = y2h;
        *(short8*)lp        = y1l;
        *(short8*)(lp + 64) = y2l;
    }
}

// ---------------- weight transpose+convert: src[K][N] f32 -> dst[N][K] bf16 ----
template<int NMAT>
__global__ __launch_bounds__(256) void conv_k(const float* __restrict__ S0,
                                              const float* __restrict__ S1,
                                              unsigned short* __restrict__ D) {
    __shared__ float t[64][65];
    const int n0 = blockIdx.x * 64, k0 = blockIdx.y * 64, e = blockIdx.z;
    const size_t esrc = (size_t)e * 2048 * 2048;
    const int cc = threadIdx.x & 63, r4 = threadIdx.x >> 6;
    const int nl = threadIdx.x >> 2, q = threadIdx.x & 3;
    #pragma unroll
    for (int s = 0; s < NMAT; s++) {
        const float* S = s ? S1 : S0;
        __syncthreads();
        #pragma unroll
        for (int j = 0; j < 16; j++) {
            const int row = j * 4 + r4;
            t[cc][row] = S[esrc + (size_t)(k0 + row) * 2048 + n0 + cc];
        }
        __syncthreads();
        const int orow = (NMAT == 2) ? (2 * (n0 + nl) + s) : (n0 + nl);
        unsigned short* dp = D + (size_t)e * (NMAT * 2048) * 2048 + (size_t)orow * 2048 + k0 + q * 16;
        float fv[16];
        #pragma unroll
        for (int j = 0; j < 16; j++) fv[j] = t[nl][q * 16 + j];
        rne16_store(fv, dp);
    }
}

// ---------------- weight transpose + hi/lo SPLIT convert --------------------
template<int NMAT>
__global__ __launch_bounds__(256) void convs_k(const float* __restrict__ S0,
                                               const float* __restrict__ S1,
                                               const float* __restrict__ S2,
                                               unsigned short* __restrict__ Dh,
                                               unsigned short* __restrict__ Dl) {
    __shared__ float t[64][65];
    const int n0 = blockIdx.x * 64, k0 = blockIdx.y * 64, z = blockIdx.z;
    const float* S = S0;
    if (NMAT == 3) S = (z == 0) ? S0 : ((z == 1) ? S1 : S2);
    const int cc = threadIdx.x & 63, r4 = threadIdx.x >> 6;
    #pragma unroll
    for (int j = 0; j < 16; j++) {
        const int row = j * 4 + r4;
        t[cc][row] = S[(size_t)(k0 + row) * 2048 + n0 + cc];
    }
    __syncthreads();
    const int nl = threadIdx.x >> 2, q = threadIdx.x & 3;
    float fv[16];
    #pragma unroll
    for (int j = 0; j < 16; j++) fv[j] = t[nl][q * 16 + j];
    uint32 h[8], l[8];
    #pragma unroll
    for (int p = 0; p < 8; p++) split2(fv[2 * p], fv[2 * p + 1], h[p], l[p]);
    const size_t off = (size_t)(z * 2048 + n0 + nl) * 2048 + k0 + q * 16;
    ((uint4*)(Dh + off))[0] = make_uint4(h[0], h[1], h[2], h[3]);
    ((uint4*)(Dh + off))[1] = make_uint4(h[4], h[5], h[6], h[7]);
    ((uint4*)(Dl + off))[0] = make_uint4(l[0], l[1], l[2], l[3]);
    ((uint4*)(Dl + off))[1] = make_uint4(l[4], l[5], l[6], l[7]);
}

// ---------------- precise split-bf16 GEMM, gl16 + LDS double-buffer -----------
// planes: 0=Ah 1=Al 2=Bh 3=Bl. Issue tile t+1 -> buf^1, compute tile t, one barrier.
template<int MODE>
__global__ __launch_bounds__(256) void sgemm_k(
    const unsigned short* __restrict__ Ahg, const unsigned short* __restrict__ Alg, int lda,
    const unsigned short* __restrict__ Bhg, const unsigned short* __restrict__ Blg, int K,
    unsigned short* __restrict__ Ch, unsigned short* __restrict__ Cl,
    float* __restrict__ Cf, int ldc,
    const float* __restrict__ resid, float* __restrict__ C2) {
    __shared__ unsigned short SS[2][4][128 * 32];
    const int mt = blockIdx.x, nt = blockIdx.y, tid = threadIdx.x;
    const int m0 = mt * 128;
    const int wave = tid >> 6, lane = tid & 63;
    const int lr = lane & 15, lg = lane >> 4;
    const int wr = (tid >> 7) & 1, wc = (tid >> 6) & 1;
    const int sr = lane >> 2;            // 0..15
    const int sc = (lane & 3) * 8;       // shorts
    const int r0 = wave * 32;
    const int lofs = r0 * 32;            // element offset within a plane
    const unsigned short* gAh = Ahg + (size_t)(m0 + r0 + sr) * lda + sc;
    const unsigned short* gAl = Alg + (size_t)(m0 + r0 + sr) * lda + sc;
    const unsigned short* gBh = Bhg + (size_t)(nt * 128 + r0 + sr) * K + sc;
    const unsigned short* gBl = Blg + (size_t)(nt * 128 + r0 + sr) * K + sc;
    const size_t rstepA = (size_t)16 * lda, rstepB = (size_t)16 * K;

    float4v acc[4][4];
    #pragma unroll
    for (int m = 0; m < 4; m++)
        #pragma unroll
        for (int n = 0; n < 4; n++) acc[m][n] = (float4v){0.f, 0.f, 0.f, 0.f};

    // prologue: stage tile 0 into buffer 0
    gl16(gAh, &SS[0][0][lofs]);           gl16(gAh + rstepA, &SS[0][0][lofs + 512]);
    gl16(gAl, &SS[0][1][lofs]);           gl16(gAl + rstepA, &SS[0][1][lofs + 512]);
    gl16(gBh, &SS[0][2][lofs]);           gl16(gBh + rstepB, &SS[0][2][lofs + 512]);
    gl16(gBl, &SS[0][3][lofs]);           gl16(gBl + rstepB, &SS[0][3][lofs + 512]);
    __syncthreads();

    int cur = 0;
    for (int k0 = 0; k0 < K; k0 += 32) {
        if (k0 + 32 < K) {   // issue next tile into other buffer (drains at loop-end barrier)
            const int nb = cur ^ 1;
            const int kn = k0 + 32;
            gl16(gAh + kn, &SS[nb][0][lofs]);          gl16(gAh + kn + rstepA, &SS[nb][0][lofs + 512]);
            gl16(gAl + kn, &SS[nb][1][lofs]);          gl16(gAl + kn + rstepA, &SS[nb][1][lofs + 512]);
            gl16(gBh + kn, &SS[nb][2][lofs]);          gl16(gBh + kn + rstepB, &SS[nb][2][lofs + 512]);
            gl16(gBl + kn, &SS[nb][3][lofs]);          gl16(gBl + kn + rstepB, &SS[nb][3][lofs + 512]);
        }
        const unsigned short* PAh = SS[cur][0];
        const unsigned short* PAl = SS[cur][1];
        const unsigned short* PBh = SS[cur][2];
        const unsigned short* PBl = SS[cur][3];
        short8 fah[4], fal[4], fbh[4], fbl[4];
        #pragma unroll
        for (int m = 0; m < 4; m++) {
            fah[m] = *(const short8*)(PAh + (wr * 64 + m * 16 + lr) * 32 + lg * 8);
            fal[m] = *(const short8*)(PAl + (wr * 64 + m * 16 + lr) * 32 + lg * 8);
        }
        #pragma unroll
        for (int n = 0; n < 4; n++) {
            fbh[n] = *(const short8*)(PBh + (wc * 64 + n * 16 + lr) * 32 + lg * 8);
            fbl[n] = *(const short8*)(PBl + (wc * 64 + n * 16 + lr) * 32 + lg * 8);
        }
        #pragma unroll
        for (int n = 0; n < 4; n++)
            #pragma unroll
            for (int m = 0; m < 4; m++) {
                acc[m][n] = __builtin_amdgcn_mfma_f32_16x16x32_bf16(fal[m], fbh[n], acc[m][n], 0, 0, 0);
                acc[m][n] = __builtin_amdgcn_mfma_f32_16x16x32_bf16(fah[m], fbl[n], acc[m][n], 0, 0, 0);
                acc[m][n] = __builtin_amdgcn_mfma_f32_16x16x32_bf16(fah[m], fbh[n], acc[m][n], 0, 0, 0);
            }
        __syncthreads();
        cur ^= 1;
    }
    #pragma unroll
    for (int m = 0; m < 4; m++) {
        const int rb = wr * 64 + m * 16 + (lane >> 4) * 4;
        #pragma unroll
        for (int n = 0; n < 4; n++) {
            const int ccol = nt * 128 + wc * 64 + n * 16 + lr;
            #pragma unroll
            for (int r = 0; r < 4; r++) {
                const size_t idx = (size_t)(m0 + rb + r) * ldc + ccol;
                if (MODE == 1) {
                    const float v = acc[m][n][r] + resid[idx];
                    Cf[idx] = v;
                    C2[idx] = v;
                } else {
                    const float v = acc[m][n][r];
                    uint32 rr = rnebits(v);
                    Ch[idx] = (unsigned short)(rr >> 16);
                    Cl[idx] = f2bf(v - __uint_as_float(rr & 0xffff0000u));
                }
            }
        }
    }
}

// ---------------- MoE GEMM, gl16 + LDS double-buffer ----
template<int MODE>
__global__ __launch_bounds__(256) void gemm_k(
    const unsigned short* __restrict__ A, int lda,
    const unsigned short* __restrict__ Bt, int K, int Ne,
    void* __restrict__ Cp, int ldc,
    const int* __restrict__ cnt, const int* __restrict__ tokl,
    const float* __restrict__ gatel, const int* __restrict__ pb) {
    __shared__ unsigned short SS[2][2][128 * 32];
    const int nt = blockIdx.x, mt = blockIdx.y, e = blockIdx.z;
    const int m0 = mt * 128;
    const int c = cnt[e];
    if (m0 >= c) return;
    const int valid = (c - m0 < 128) ? (c - m0) : 128;
    const int tid = threadIdx.x;
    const int wave = tid >> 6, lane = tid & 63;
    const int lr = lane & 15;
    const int wr = (tid >> 7) & 1, wc = (tid >> 6) & 1;
    const int sr = lane >> 2, sc = (lane & 3) * 8;
    const int r0 = wave * 32;
    const int lofs = r0 * 32;
    size_t gr0, gr1;
    {
        int ra = r0 + sr, rb2 = r0 + 16 + sr;
        if (MODE == 2) {
            ra = ra < valid ? ra : valid - 1;
            rb2 = rb2 < valid ? rb2 : valid - 1;
            gr0 = (size_t)tokl[e * 4096 + m0 + ra];
            gr1 = (size_t)tokl[e * 4096 + m0 + rb2];
        } else {
            int x0 = m0 + ra, x1 = m0 + rb2;
            gr0 = (size_t)(pb[e] + (x0 < c ? x0 : c - 1));
            gr1 = (size_t)(pb[e] + (x1 < c ? x1 : c - 1));
        }
    }
    const unsigned short* gA0 = A + gr0 * (size_t)lda + sc;
    const unsigned short* gA1 = A + gr1 * (size_t)lda + sc;
    const unsigned short* gB = Bt + (size_t)e * Ne * K + (size_t)(nt * 128 + r0 + sr) * K + sc;
    const size_t rstepB = (size_t)16 * K;

    float4v acc[4][4];
    #pragma unroll
    for (int m = 0; m < 4; m++)
        #pragma unroll
        for (int n = 0; n < 4; n++) acc[m][n] = (float4v){0.f, 0.f, 0.f, 0.f};

    gl16(gA0, &SS[0][0][lofs]);           gl16(gA1, &SS[0][0][lofs + 512]);
    gl16(gB, &SS[0][1][lofs]);            gl16(gB + rstepB, &SS[0][1][lofs + 512]);
    __syncthreads();

    int cur = 0;
    for (int k0 = 0; k0 < K; k0 += 32) {
        if (k0 + 32 < K) {
            const int nb = cur ^ 1;
            const int kn = k0 + 32;
            gl16(gA0 + kn, &SS[nb][0][lofs]);          gl16(gA1 + kn, &SS[nb][0][lofs + 512]);
            gl16(gB + kn, &SS[nb][1][lofs]);           gl16(gB + kn + rstepB, &SS[nb][1][lofs + 512]);
        }
        const unsigned short* PA = SS[cur][0];
        const unsigned short* PB = SS[cur][1];
        short8 af[4], bf[4];
        const int lg = lane >> 4;
        #pragma unroll
        for (int m = 0; m < 4; m++) af[m] = *(const short8*)(PA + (wr * 64 + m * 16 + lr) * 32 + lg * 8);
        #pragma unroll
        for (int n = 0; n < 4; n++) bf[n] = *(const short8*)(PB + (wc * 64 + n * 16 + lr) * 32 + lg * 8);
        #pragma unroll
        for (int n = 0; n < 4; n++)
            #pragma unroll
            for (int m = 0; m < 4; m++)
                acc[m][n] = __builtin_amdgcn_mfma_f32_16x16x32_bf16(af[m], bf[n], acc[m][n], 0, 0, 0);
        __syncthreads();
        cur ^= 1;
    }

    #pragma unroll
    for (int m = 0; m < 4; m++) {
        const int rb = wr * 64 + m * 16 + (lane >> 4) * 4;
        #pragma unroll
        for (int n = 0; n < 4; n++) {
            const int col = nt * 128 + wc * 64 + n * 16 + lr;
            #pragma unroll
            for (int r = 0; r < 4; r++) {
                const int row = rb + r;
                const float v = acc[m][n][r];
                if (MODE == 2) {
                    const float other = __shfl_xor(v, 1);
                    if (!(lr & 1) && row < valid) {
                        const float g1 = v, g3 = other;
                        const float hsw = (g1 / (1.f + __expf(-g1))) * g3;
                        ((unsigned short*)Cp)[(size_t)(pb[e] + m0 + row) * ldc + (col >> 1)] = f2bf(hsw);
                    }
                } else {
                    if (row < valid) {
                        const int t = tokl[e * 4096 + m0 + row];
                        const float g = gatel[e * 4096 + m0 + row];
                        atomicAdd(((float*)Cp) + (size_t)t * ldc + col, v * g);
                    }
                }
            }
        }
    }
}

// ---------------- flash attention, split-bf16, XCD-pinned + prefetch ----------
__global__ __launch_bounds__(256) void attn_k(const unsigned short* __restrict__ qh,
                                              const unsigned short* __restrict__ ql,
                                              unsigned short* __restrict__ ch,
                                              unsigned short* __restrict__ cl) {
    __shared__ unsigned short Ksh[32][136], Ksl[32][136];
    __shared__ unsigned short Vth[128][40], Vtl[128][40];
    const int bid = blockIdx.x;          // 1024 blocks
    const int xcd = bid & 7, jj = bid >> 3;
    const int bh  = xcd * 4 + (jj >> 5);
    const int qb  = 31 - (jj & 31);
    const int h   = bh & 15, b = bh >> 4;
    const int tid = threadIdx.x;
    const int wave = tid >> 6, lane = tid & 63, lr = lane & 15, lg = lane >> 4;
    const size_t tb = (size_t)b * CS;
    const int q0 = qb * 64 + wave * 16;

    short8 qfh[4], qfl[4];
    {
        const size_t off = (tb + q0 + lr) * CQKV + h * CHD;
        #pragma unroll
        for (int c = 0; c < 4; c++) {
            qfh[c] = *(const short8*)(qh + off + c * 32 + lg * 8);
            qfl[c] = *(const short8*)(ql + off + c * 32 + lg * 8);
        }
    }
    float4v o[8];
    #pragma unroll
    for (int d = 0; d < 8; d++) o[d] = (float4v){0.f, 0.f, 0.f, 0.f};
    float m = -1e30f, l = 0.f;
    const float scl = 0.08838834764831845f;
    const int ntiles = 2 * (qb + 1);
    const int kk = tid >> 3, slot = tid & 7;
    const int vd = tid & 127, vhalf = tid >> 7;

    short8 pkh0, pkh1, pkl0, pkl1;
    unsigned short pth[16], ptl[16];
    {
        const size_t koff = (tb + kk) * CQKV + CH + h * CHD + slot * 16;
        pkh0 = *(const short8*)(qh + koff);
        pkh1 = *(const short8*)(qh + koff + 8);
        pkl0 = *(const short8*)(ql + koff);
        pkl1 = *(const short8*)(ql + koff + 8);
        const size_t voff = (tb + vhalf * 16) * CQKV + 2 * CH + h * CHD + vd;
        #pragma unroll
        for (int j = 0; j < 16; j++) {
            pth[j] = qh[voff + (size_t)j * CQKV];
            ptl[j] = ql[voff + (size_t)j * CQKV];
        }
    }

    for (int kt = 0; kt < ntiles; ++kt) {
        const int kv0 = kt * 32;
        __syncthreads();
        *(short8*)(&Ksh[kk][slot * 16])     = pkh0;
        *(short8*)(&Ksh[kk][slot * 16 + 8]) = pkh1;
        *(short8*)(&Ksl[kk][slot * 16])     = pkl0;
        *(short8*)(&Ksl[kk][slot * 16 + 8]) = pkl1;
        #pragma unroll
        for (int p = 0; p < 2; p++) {
            *(ushort4v*)(&Vth[vd][vhalf * 16 + p * 8])     = *(ushort4v*)(&pth[p * 8]);
            *(ushort4v*)(&Vth[vd][vhalf * 16 + p * 8 + 4]) = *(ushort4v*)(&pth[p * 8 + 4]);
            *(ushort4v*)(&Vtl[vd][vhalf * 16 + p * 8])     = *(ushort4v*)(&ptl[p * 8]);
            *(ushort4v*)(&Vtl[vd][vhalf * 16 + p * 8 + 4]) = *(ushort4v*)(&ptl[p * 8 + 4]);
        }
        if (kt + 1 < ntiles) {
            const int nv0 = kv0 + 32;
            const size_t koff = (tb + nv0 + kk) * CQKV + CH + h * CHD + slot * 16;
            pkh0 = *(const short8*)(qh + koff);
            pkh1 = *(const short8*)(qh + koff + 8);
            pkl0 = *(const short8*)(ql + koff);
            pkl1 = *(const short8*)(ql + koff + 8);
            const size_t voff = (tb + nv0 + vhalf * 16) * CQKV + 2 * CH + h * CHD + vd;
            #pragma unroll
            for (int j = 0; j < 16; j++) {
                pth[j] = qh[voff + (size_t)j * CQKV];
                ptl[j] = ql[voff + (size_t)j * CQKV];
            }
        }
        __syncthreads();

        float4v st0 = (float4v){0.f,0.f,0.f,0.f}, st1 = st0;
        #pragma unroll
        for (int c = 0; c < 4; c++) {
            short8 kah = *(const short8*)(&Ksh[lr][c * 32 + lg * 8]);
            short8 kal = *(const short8*)(&Ksl[lr][c * 32 + lg * 8]);
            short8 kbh = *(const short8*)(&Ksh[16 + lr][c * 32 + lg * 8]);
            short8 kbl = *(const short8*)(&Ksl[16 + lr][c * 32 + lg * 8]);
            st0 = __builtin_amdgcn_mfma_f32_16x16x32_bf16(kal, qfh[c], st0, 0, 0, 0);
            st0 = __builtin_amdgcn_mfma_f32_16x16x32_bf16(kah, qfl[c], st0, 0, 0, 0);
            st0 = __builtin_amdgcn_mfma_f32_16x16x32_bf16(kah, qfh[c], st0, 0, 0, 0);
            st1 = __builtin_amdgcn_mfma_f32_16x16x32_bf16(kbl, qfh[c], st1, 0, 0, 0);
            st1 = __builtin_amdgcn_mfma_f32_16x16x32_bf16(kbh, qfl[c], st1, 0, 0, 0);
            st1 = __builtin_amdgcn_mfma_f32_16x16x32_bf16(kbh, qfh[c], st1, 0, 0, 0);
        }
        float pv[8]; float pmax = -1e30f;
        const int qg = q0 + lr;
        #pragma unroll
        for (int f = 0; f < 2; f++) {
            #pragma unroll
            for (int r = 0; r < 4; r++) {
                const int kg = kv0 + f * 16 + lg * 4 + r;
                const float s = (kg <= qg) ? ((f ? st1[r] : st0[r]) * scl) : -1e30f;
                pv[f * 4 + r] = s;
                pmax = fmaxf(pmax, s);
            }
        }
        pmax = fmaxf(pmax, __shfl_xor(pmax, 16));
        pmax = fmaxf(pmax, __shfl_xor(pmax, 32));
        if (!__all(pmax <= m)) {
            const float mnew = fmaxf(m, pmax);
            const float alpha = __expf(m - mnew);
            l *= alpha;
            #pragma unroll
            for (int d = 0; d < 8; d++) o[d] *= alpha;
            m = mnew;
        }
        float sum = 0.f;
        #pragma unroll
        for (int i = 0; i < 8; i++) { const float p = __expf(pv[i] - m); pv[i] = p; sum += p; }
        sum += __shfl_xor(sum, 16);
        sum += __shfl_xor(sum, 32);
        l += sum;
        short8 pfh, pfl;
        unsigned short* pfhp = (unsigned short*)&pfh;
        unsigned short* pflp = (unsigned short*)&pfl;
        #pragma unroll
        for (int j = 0; j < 8; j++) {
            const int srcl = (((lg & 1) * 2 + (j >> 2)) << 4) | lr;
            const float a0 = __shfl(pv[j & 3], srcl);
            const float a1 = __shfl(pv[4 + (j & 3)], srcl);
            const float sel = (lg >= 2) ? a1 : a0;
            uint32 r = rnebits(sel);
            pfhp[j] = (unsigned short)(r >> 16);
            float d = sel - __uint_as_float(r & 0xffff0000u);
            pflp[j] = (unsigned short)(rnebits(d) >> 16);
        }
        #pragma unroll
        for (int dt = 0; dt < 8; dt++) {
            short8 vh = *(const short8*)(&Vth[dt * 16 + lr][lg * 8]);
            short8 vl = *(const short8*)(&Vtl[dt * 16 + lr][lg * 8]);
            o[dt] = __builtin_amdgcn_mfma_f32_16x16x32_bf16(vl, pfh, o[dt], 0, 0, 0);
            o[dt] = __builtin_amdgcn_mfma_f32_16x16x32_bf16(vh, pfl, o[dt], 0, 0, 0);
            o[dt] = __builtin_amdgcn_mfma_f32_16x16x32_bf16(vh, pfh, o[dt], 0, 0, 0);
        }
    }
    const float inv = 1.f / l;
    const size_t coff = (tb + q0 + lr) * CH + h * CHD + lg * 4;
    #pragma unroll
    for (int dt = 0; dt < 8; dt++) {
        ushort4v wh, wl;
        #pragma unroll
        for (int r = 0; r < 4; r++) {
            const float v = o[dt][r] * inv;
            uint32 rr = rnebits(v);
            wh[r] = (unsigned short)(rr >> 16);
            wl[r] = f2bf(v - __uint_as_float(rr & 0xffff0000u));
        }
        *(ushort4v*)(ch + coff + dt * 16) = wh;
        *(ushort4v*)(cl + coff + dt * 16) = wl;
    }
}

__global__ void prefix_k(const int* __restrict__ cnt, int* __restrict__ pb) {
    if (threadIdx.x == 0 && blockIdx.x == 0) {
        int s = 0;
        for (int e = 0; e < CE; e++) { pb[e] = s; s += cnt[e]; }
    }
}

// ---------------- launch ----------------
extern "C" void kernel_launch(void* const* d_in, const int* in_sizes, int n_in,
                              void* d_out, int out_size, void* d_ws, size_t ws_size,
                              hipStream_t stream) {
    (void)in_sizes; (void)n_in; (void)out_size; (void)ws_size;
    const float* hidden = (const float*)d_in[0];
    const int*   posids = (const int*)d_in[1];
    const float* rms1w  = (const float*)d_in[2];
    const float* rms2w  = (const float*)d_in[3];
    const float* qw     = (const float*)d_in[4];
    const float* kw     = (const float*)d_in[5];
    const float* vw     = (const float*)d_in[6];
    const float* ow     = (const float*)d_in[7];
    const float* rw     = (const float*)d_in[8];
    const float* w1     = (const float*)d_in[9];
    const float* w2     = (const float*)d_in[10];
    const float* w3     = (const float*)d_in[11];
    float* out = (float*)d_out;

    char* ws = (char*)d_ws;
    unsigned short* h1h = (unsigned short*)ws;
    unsigned short* h1l = (unsigned short*)(ws + 16777216);
    unsigned short* woh = (unsigned short*)ws;
    unsigned short* wol = (unsigned short*)(ws + 8388608);
    unsigned short* h2  = (unsigned short*)ws;
    int*   tok  = (int*)(ws + 16777216);
    float* gate = (float*)(ws + 16777216 + 131072);
    int*   cnt  = (int*)(ws + 16777216 + 262144);
    int*   pb   = cnt + 16;
    unsigned short* qkvh = (unsigned short*)(ws + 33554432);
    unsigned short* qkvl = (unsigned short*)(ws + 83886080);
    unsigned short* wt13 = (unsigned short*)(ws + 33554432);
    unsigned short* wt2  = (unsigned short*)(ws + 33554432);
    unsigned short* wqkvh = (unsigned short*)(ws + 134217728);
    unsigned short* wqkvl = (unsigned short*)(ws + 134217728 + 25165824);
    unsigned short* ctxh = (unsigned short*)(ws + 134217728);
    unsigned short* ctxl = (unsigned short*)(ws + 150994944);
    float*          res2 = (float*)(ws + 167772160);
    unsigned short* Hbuf = (unsigned short*)(ws + 167772160);
    float2*         rtab = (float2*)(ws + 201326592);

    rope_tab_k<<<512, 256, 0, stream>>>(rtab);
    rmsnorm_k<<<CT, 256, 0, stream>>>(hidden, rms1w, h1h, h1l);
    convs_k<3><<<dim3(32, 32, 3), 256, 0, stream>>>(qw, kw, vw, wqkvh, wqkvl);
    sgemm_k<0><<<dim3(32, 48), 256, 0, stream>>>(h1h, h1l, CH, wqkvh, wqkvl, CH,
                                                 qkvh, qkvl, nullptr, CQKV, nullptr, nullptr);
    rope_k<<<2048, 256, 0, stream>>>(qkvh, qkvl, posids, rtab);
    convs_k<1><<<dim3(32, 32, 1), 256, 0, stream>>>(ow, nullptr, nullptr, woh, wol);
    attn_k<<<1024, 256, 0, stream>>>(qkvh, qkvl, ctxh, ctxl);
    sgemm_k<1><<<dim3(32, 16), 256, 0, stream>>>(ctxh, ctxl, CH, woh, wol, CH,
                                                 nullptr, nullptr, res2, CH, hidden, out);
    hipMemsetAsync(cnt, 0, 8 * sizeof(int), stream);
    rmsrouter_k<<<CT, 256, 0, stream>>>(res2, rms2w, rw, h2, cnt, tok, gate);
    prefix_k<<<1, 64, 0, stream>>>(cnt, pb);
    conv_k<2><<<dim3(32, 32, CE), 256, 0, stream>>>(w1, w3, wt13);
    gemm_k<2><<<dim3(32, 32, CE), 256, 0, stream>>>(h2, CH, wt13, CH, 2 * CI, Hbuf, CI,
                                                    cnt, tok, gate, pb);
    conv_k<1><<<dim3(32, 32, CE), 256, 0, stream>>>(w2, nullptr, wt2);
    gemm_k<3><<<dim3(16, 32, CE), 256, 0, stream>>>(Hbuf, CI, wt2, CI, CH, out, CH,
                                                    cnt, tok, gate, pb);
}

// Round 12
// 1286.111 us; speedup vs baseline: 1.1841x; 1.0224x over previous
//
#include <hip/hip_runtime.h>
#include <hip/hip_bf16.h>

// ---------------- constants ----------------
constexpr int CB   = 2;
constexpr int CS   = 2048;
constexpr int CH   = 2048;
constexpr int CNH  = 16;
constexpr int CHD  = 128;
constexpr int CE   = 8;
constexpr int CI   = 2048;
constexpr int CT   = CB * CS;
constexpr int CQK  = 4096;   // q|k row stride

typedef __attribute__((ext_vector_type(8))) short short8;
typedef __attribute__((ext_vector_type(4))) float float4v;
typedef __attribute__((ext_vector_type(4))) unsigned short ushort4v;
typedef unsigned int uint32;

__device__ __forceinline__ float bf2f(unsigned short u) {
    union { unsigned int i; float f; } x; x.i = ((unsigned int)u) << 16; return x.f;
}
__device__ __forceinline__ unsigned short f2bf(float f) {
    union { float f; unsigned int i; } x; x.f = f;
    unsigned int r = x.i + 0x7fffu + ((x.i >> 16) & 1u);
    return (unsigned short)(r >> 16);
}
__device__ __forceinline__ uint32 packpair(uint32 r0, uint32 r1) {
    return __builtin_amdgcn_perm(r1, r0, 0x07060302u);
}
__device__ __forceinline__ uint32 rnebits(float f) {
    uint32 u = __float_as_uint(f);
    return u + 0x7fffu + ((u >> 16) & 1u);
}
__device__ __forceinline__ void split2(float f0, float f1, uint32& h, uint32& l) {
    uint32 r0 = rnebits(f0), r1 = rnebits(f1);
    h = packpair(r0, r1);
    float d0 = f0 - __uint_as_float(r0 & 0xffff0000u);
    float d1 = f1 - __uint_as_float(r1 & 0xffff0000u);
    l = packpair(rnebits(d0), rnebits(d1));
}
__device__ __forceinline__ void rne16_store(const float* fv, unsigned short* dst) {
    uint32 h[8];
    #pragma unroll
    for (int p = 0; p < 8; p++) h[p] = packpair(rnebits(fv[2 * p]), rnebits(fv[2 * p + 1]));
    ((uint4*)dst)[0] = make_uint4(h[0], h[1], h[2], h[3]);
    ((uint4*)dst)[1] = make_uint4(h[4], h[5], h[6], h[7]);
}
// async global->LDS: 16B per lane, lds dest = wave-uniform base + lane*16
__device__ __forceinline__ void gl16(const void* g, void* l) {
    __builtin_amdgcn_global_load_lds(
        (const __attribute__((address_space(1))) void*)g,
        (__attribute__((address_space(3))) void*)l, 16, 0, 0);
}

// ---------------- RMSNorm (hi/lo split out) ----------
__global__ __launch_bounds__(256) void rmsnorm_k(const float* __restrict__ x,
                                                 const float* __restrict__ w,
                                                 unsigned short* __restrict__ o1,
                                                 unsigned short* __restrict__ o2) {
    const int row = blockIdx.x;
    const float* xr = x + (size_t)row * CH;
    const int base = threadIdx.x * 8;
    float4 v0 = *(const float4*)(xr + base);
    float4 v1 = *(const float4*)(xr + base + 4);
    float ss = v0.x*v0.x + v0.y*v0.y + v0.z*v0.z + v0.w*v0.w
             + v1.x*v1.x + v1.y*v1.y + v1.z*v1.z + v1.w*v1.w;
    #pragma unroll
    for (int o = 1; o < 64; o <<= 1) ss += __shfl_xor(ss, o);
    __shared__ float ps[4];
    if ((threadIdx.x & 63) == 0) ps[threadIdx.x >> 6] = ss;
    __syncthreads();
    const float scale = rsqrtf((ps[0] + ps[1] + ps[2] + ps[3]) / (float)CH + 1e-5f);
    float4 w0 = *(const float4*)(w + base);
    float4 w1 = *(const float4*)(w + base + 4);
    float r[8] = {v0.x * scale * w0.x, v0.y * scale * w0.y, v0.z * scale * w0.z, v0.w * scale * w0.w,
                  v1.x * scale * w1.x, v1.y * scale * w1.y, v1.z * scale * w1.z, v1.w * scale * w1.w};
    uint32 h[4], l[4];
    #pragma unroll
    for (int p = 0; p < 4; p++) split2(r[2 * p], r[2 * p + 1], h[p], l[p]);
    *(uint4*)(o1 + (size_t)row * CH + base) = make_uint4(h[0], h[1], h[2], h[3]);
    *(uint4*)(o2 + (size_t)row * CH + base) = make_uint4(l[0], l[1], l[2], l[3]);
}

// ---------------- fused RMSNorm2 + router ----------------
__global__ __launch_bounds__(256) void rmsrouter_k(const float* __restrict__ x,
                                                   const float* __restrict__ w,
                                                   const float* __restrict__ rw,
                                                   unsigned short* __restrict__ h2,
                                                   int* __restrict__ cnt,
                                                   int* __restrict__ tok,
                                                   float* __restrict__ gate) {
    const int row = blockIdx.x;
    const float* xr = x + (size_t)row * CH;
    const int base = threadIdx.x * 8;
    float4 v0 = *(const float4*)(xr + base);
    float4 v1 = *(const float4*)(xr + base + 4);
    float ss = v0.x*v0.x + v0.y*v0.y + v0.z*v0.z + v0.w*v0.w
             + v1.x*v1.x + v1.y*v1.y + v1.z*v1.z + v1.w*v1.w;
    #pragma unroll
    for (int o = 1; o < 64; o <<= 1) ss += __shfl_xor(ss, o);
    __shared__ float ps[4];
    __shared__ double dacc[4][8];
    const int wave = threadIdx.x >> 6, lane = threadIdx.x & 63;
    if (lane == 0) ps[wave] = ss;
    __syncthreads();
    const float scale = rsqrtf((ps[0] + ps[1] + ps[2] + ps[3]) / (float)CH + 1e-5f);
    float4 w0 = *(const float4*)(w + base);
    float4 w1 = *(const float4*)(w + base + 4);
    float r[8] = {v0.x * scale * w0.x, v0.y * scale * w0.y, v0.z * scale * w0.z, v0.w * scale * w0.w,
                  v1.x * scale * w1.x, v1.y * scale * w1.y, v1.z * scale * w1.z, v1.w * scale * w1.w};
    rne16_store(r, h2 + (size_t)row * CH + base);
    const float vv[8] = {v0.x, v0.y, v0.z, v0.w, v1.x, v1.y, v1.z, v1.w};
    const float ww[8] = {w0.x, w0.y, w0.z, w0.w, w1.x, w1.y, w1.z, w1.w};
    double acc[8] = {0, 0, 0, 0, 0, 0, 0, 0};
    #pragma unroll
    for (int jj = 0; jj < 8; jj++) {
        const double xn = (double)vv[jj] * (double)ww[jj];
        const float* rr = rw + (size_t)(base + jj) * CE;
        #pragma unroll
        for (int e = 0; e < 8; e++) acc[e] += xn * (double)rr[e];
    }
    #pragma unroll
    for (int e = 0; e < 8; e++) {
        #pragma unroll
        for (int o = 1; o < 64; o <<= 1) acc[e] += __shfl_xor(acc[e], o);
    }
    if (lane == 0) {
        #pragma unroll
        for (int e = 0; e < 8; e++) dacc[wave][e] = acc[e];
    }
    __syncthreads();
    if (threadIdx.x == 0) {
        double a[8];
        #pragma unroll
        for (int e = 0; e < 8; e++) a[e] = dacc[0][e] + dacc[1][e] + dacc[2][e] + dacc[3][e];
        int e0 = 0;
        #pragma unroll
        for (int e = 1; e < 8; e++) if (a[e] > a[e0]) e0 = e;
        int e1 = (e0 == 0) ? 1 : 0;
        #pragma unroll
        for (int e = 0; e < 8; e++) if (e != e0 && a[e] > a[e1]) e1 = e;
        const double dl = (double)scale * (a[e1] - a[e0]);   // <= 0
        const double p1r = exp(dl);
        const float g0 = (float)(1.0 / (1.0 + p1r));
        const float g1 = (float)(p1r / (1.0 + p1r));
        int pos0 = atomicAdd(&cnt[e0], 1);
        tok[e0 * 4096 + pos0] = row; gate[e0 * 4096 + pos0] = g0;
        int pos1 = atomicAdd(&cnt[e1], 1);
        tok[e1 * 4096 + pos1] = row; gate[e1 * 4096 + pos1] = g1;
    }
}

// ---------------- RoPE table ----
__global__ void rope_tab_k(float2* __restrict__ tab) {
    int i = blockIdx.x * 256 + threadIdx.x;
    int p = i >> 6, j = i & 63;
    double inv = pow(10000.0, -(double)j / 64.0);
    float invf = (float)inv;
    float angf = (float)p * invf;
    double da = (double)angf;
    tab[i] = make_float2((float)cos(da), (float)sin(da));
}

// ---------------- RoPE vectorized (qk buffer, stride 4096) ----------------
__global__ __launch_bounds__(256) void rope_k(unsigned short* __restrict__ qh,
                                              unsigned short* __restrict__ ql,
                                              const int* __restrict__ pos,
                                              const float2* __restrict__ tab) {
    int i = blockIdx.x * 256 + threadIdx.x;  // CT*16*8
    if (i >= CT * CNH * 8) return;
    int t = i >> 7, r = i & 127, hh = r >> 3, jo = (r & 7) << 3;
    const float2* tp = tab + (size_t)pos[t] * 64 + jo;
    float4 tc0 = ((const float4*)tp)[0];
    float4 tc1 = ((const float4*)tp)[1];
    float4 tc2 = ((const float4*)tp)[2];
    float4 tc3 = ((const float4*)tp)[3];
    float cx[8] = {tc0.x, tc0.z, tc1.x, tc1.z, tc2.x, tc2.z, tc3.x, tc3.z};
    float cy[8] = {tc0.y, tc0.w, tc1.y, tc1.w, tc2.y, tc2.w, tc3.y, tc3.w};
    const size_t off = (size_t)t * CQK + hh * CHD + jo;
    #pragma unroll
    for (int s = 0; s < 2; s++) {
        unsigned short* hp = qh + off + s * CH;
        unsigned short* lp = ql + off + s * CH;
        short8 x1h = *(short8*)hp,        x1l = *(short8*)lp;
        short8 x2h = *(short8*)(hp + 64), x2l = *(short8*)(lp + 64);
        const unsigned short* p1h = (const unsigned short*)&x1h;
        const unsigned short* p1l = (const unsigned short*)&x1l;
        const unsigned short* p2h = (const unsigned short*)&x2h;
        const unsigned short* p2l = (const unsigned short*)&x2l;
        short8 y1h, y1l, y2h, y2l;
        unsigned short* q1h = (unsigned short*)&y1h;
        unsigned short* q1l = (unsigned short*)&y1l;
        unsigned short* q2h = (unsigned short*)&y2h;
        unsigned short* q2l = (unsigned short*)&y2l;
        #pragma unroll
        for (int jj = 0; jj < 8; jj++) {
            const float x1 = bf2f(p1h[jj]) + bf2f(p1l[jj]);
            const float x2 = bf2f(p2h[jj]) + bf2f(p2l[jj]);
            const float yy1 = x1 * cx[jj] - x2 * cy[jj];
            const float yy2 = x2 * cx[jj] + x1 * cy[jj];
            const uint32 r1 = rnebits(yy1), r2 = rnebits(yy2);
            q1h[jj] = (unsigned short)(r1 >> 16);
            q2h[jj] = (unsigned short)(r2 >> 16);
            q1l[jj] = f2bf(yy1 - __uint_as_float(r1 & 0xffff0000u));
            q2l[jj] = f2bf(yy2 - __uint_as_float(r2 & 0xffff0000u));
        }
        *(short8*)hp        = y1h;
        *(short8*)(hp + 64) = y2h;
        *(short8*)lp        = y1l;
        *(short8*)(lp + 64) = y2l;
    }
}

// ---------------- weight transpose+convert: src[K][N] f32 -> dst[N][K] bf16 ----
template<int NMAT>
__global__ __launch_bounds__(256) void conv_k(const float* __restrict__ S0,
                                              const float* __restrict__ S1,
                                              unsigned short* __restrict__ D) {
    __shared__ float t[64][65];
    const int n0 = blockIdx.x * 64, k0 = blockIdx.y * 64, e = blockIdx.z;
    const size_t esrc = (size_t)e * 2048 * 2048;
    const int cc = threadIdx.x & 63, r4 = threadIdx.x >> 6;
    const int nl = threadIdx.x >> 2, q = threadIdx.x & 3;
    #pragma unroll
    for (int s = 0; s < NMAT; s++) {
        const float* S = s ? S1 : S0;
        __syncthreads();
        #pragma unroll
        for (int j = 0; j < 16; j++) {
            const int row = j * 4 + r4;
            t[cc][row] = S[esrc + (size_t)(k0 + row) * 2048 + n0 + cc];
        }
        __syncthreads();
        const int orow = (NMAT == 2) ? (2 * (n0 + nl) + s) : (n0 + nl);
        unsigned short* dp = D + (size_t)e * (NMAT * 2048) * 2048 + (size_t)orow * 2048 + k0 + q * 16;
        float fv[16];
        #pragma unroll
        for (int j = 0; j < 16; j++) fv[j] = t[nl][q * 16 + j];
        rne16_store(fv, dp);
    }
}

// ---------------- weight transpose + hi/lo SPLIT convert --------------------
template<int NMAT>
__global__ __launch_bounds__(256) void convs_k(const float* __restrict__ S0,
                                               const float* __restrict__ S1,
                                               const float* __restrict__ S2,
                                               unsigned short* __restrict__ Dh,
                                               unsigned short* __restrict__ Dl) {
    __shared__ float t[64][65];
    const int n0 = blockIdx.x * 64, k0 = blockIdx.y * 64, z = blockIdx.z;
    const float* S = S0;
    if (NMAT == 3) S = (z == 0) ? S0 : ((z == 1) ? S1 : S2);
    const int cc = threadIdx.x & 63, r4 = threadIdx.x >> 6;
    #pragma unroll
    for (int j = 0; j < 16; j++) {
        const int row = j * 4 + r4;
        t[cc][row] = S[(size_t)(k0 + row) * 2048 + n0 + cc];
    }
    __syncthreads();
    const int nl = threadIdx.x >> 2, q = threadIdx.x & 3;
    float fv[16];
    #pragma unroll
    for (int j = 0; j < 16; j++) fv[j] = t[nl][q * 16 + j];
    uint32 h[8], l[8];
    #pragma unroll
    for (int p = 0; p < 8; p++) split2(fv[2 * p], fv[2 * p + 1], h[p], l[p]);
    const size_t off = (size_t)(z * 2048 + n0 + nl) * 2048 + k0 + q * 16;
    ((uint4*)(Dh + off))[0] = make_uint4(h[0], h[1], h[2], h[3]);
    ((uint4*)(Dh + off))[1] = make_uint4(h[4], h[5], h[6], h[7]);
    ((uint4*)(Dl + off))[0] = make_uint4(l[0], l[1], l[2], l[3]);
    ((uint4*)(Dl + off))[1] = make_uint4(l[4], l[5], l[6], l[7]);
}

// ---------------- precise split-bf16 GEMM, gl16 + LDS double-buffer -----------
// MODE 0 (QKV): q,k cols -> Ch/Cl (stride 4096); v cols -> Vh/Vl transposed [vcol][token]
// MODE 1 (O-proj): C f32 + resid, dual-store
template<int MODE>
__global__ __launch_bounds__(256) void sgemm_k(
    const unsigned short* __restrict__ Ahg, const unsigned short* __restrict__ Alg, int lda,
    const unsigned short* __restrict__ Bhg, const unsigned short* __restrict__ Blg, int K,
    unsigned short* __restrict__ Ch, unsigned short* __restrict__ Cl,
    float* __restrict__ Cf, int ldc,
    const float* __restrict__ resid, float* __restrict__ C2,
    unsigned short* __restrict__ Vh, unsigned short* __restrict__ Vl) {
    __shared__ unsigned short SS[2][4][128 * 32];
    const int mt = blockIdx.x, nt = blockIdx.y, tid = threadIdx.x;
    const int m0 = mt * 128;
    const int wave = tid >> 6, lane = tid & 63;
    const int lr = lane & 15, lg = lane >> 4;
    const int wr = (tid >> 7) & 1, wc = (tid >> 6) & 1;
    const int sr = lane >> 2;
    const int sc = (lane & 3) * 8;
    const int r0 = wave * 32;
    const int lofs = r0 * 32;
    const unsigned short* gAh = Ahg + (size_t)(m0 + r0 + sr) * lda + sc;
    const unsigned short* gAl = Alg + (size_t)(m0 + r0 + sr) * lda + sc;
    const unsigned short* gBh = Bhg + (size_t)(nt * 128 + r0 + sr) * K + sc;
    const unsigned short* gBl = Blg + (size_t)(nt * 128 + r0 + sr) * K + sc;
    const size_t rstepA = (size_t)16 * lda, rstepB = (size_t)16 * K;

    float4v acc[4][4];
    #pragma unroll
    for (int m = 0; m < 4; m++)
        #pragma unroll
        for (int n = 0; n < 4; n++) acc[m][n] = (float4v){0.f, 0.f, 0.f, 0.f};

    gl16(gAh, &SS[0][0][lofs]);           gl16(gAh + rstepA, &SS[0][0][lofs + 512]);
    gl16(gAl, &SS[0][1][lofs]);           gl16(gAl + rstepA, &SS[0][1][lofs + 512]);
    gl16(gBh, &SS[0][2][lofs]);           gl16(gBh + rstepB, &SS[0][2][lofs + 512]);
    gl16(gBl, &SS[0][3][lofs]);           gl16(gBl + rstepB, &SS[0][3][lofs + 512]);
    __syncthreads();

    int cur = 0;
    for (int k0 = 0; k0 < K; k0 += 32) {
        if (k0 + 32 < K) {
            const int nb = cur ^ 1;
            const int kn = k0 + 32;
            gl16(gAh + kn, &SS[nb][0][lofs]);          gl16(gAh + kn + rstepA, &SS[nb][0][lofs + 512]);
            gl16(gAl + kn, &SS[nb][1][lofs]);          gl16(gAl + kn + rstepA, &SS[nb][1][lofs + 512]);
            gl16(gBh + kn, &SS[nb][2][lofs]);          gl16(gBh + kn + rstepB, &SS[nb][2][lofs + 512]);
            gl16(gBl + kn, &SS[nb][3][lofs]);          gl16(gBl + kn + rstepB, &SS[nb][3][lofs + 512]);
        }
        const unsigned short* PAh = SS[cur][0];
        const unsigned short* PAl = SS[cur][1];
        const unsigned short* PBh = SS[cur][2];
        const unsigned short* PBl = SS[cur][3];
        short8 fah[4], fal[4], fbh[4], fbl[4];
        #pragma unroll
        for (int m = 0; m < 4; m++) {
            fah[m] = *(const short8*)(PAh + (wr * 64 + m * 16 + lr) * 32 + lg * 8);
            fal[m] = *(const short8*)(PAl + (wr * 64 + m * 16 + lr) * 32 + lg * 8);
        }
        #pragma unroll
        for (int n = 0; n < 4; n++) {
            fbh[n] = *(const short8*)(PBh + (wc * 64 + n * 16 + lr) * 32 + lg * 8);
            fbl[n] = *(const short8*)(PBl + (wc * 64 + n * 16 + lr) * 32 + lg * 8);
        }
        #pragma unroll
        for (int n = 0; n < 4; n++)
            #pragma unroll
            for (int m = 0; m < 4; m++) {
                acc[m][n] = __builtin_amdgcn_mfma_f32_16x16x32_bf16(fal[m], fbh[n], acc[m][n], 0, 0, 0);
                acc[m][n] = __builtin_amdgcn_mfma_f32_16x16x32_bf16(fah[m], fbl[n], acc[m][n], 0, 0, 0);
                acc[m][n] = __builtin_amdgcn_mfma_f32_16x16x32_bf16(fah[m], fbh[n], acc[m][n], 0, 0, 0);
            }
        __syncthreads();
        cur ^= 1;
    }
    if (MODE == 0 && nt >= 32) {
        // V columns: transposed packed store vT[vcol][token]
        #pragma unroll
        for (int m = 0; m < 4; m++) {
            const int rb = wr * 64 + m * 16 + lg * 4;
            #pragma unroll
            for (int n = 0; n < 4; n++) {
                const int vcol = nt * 128 + wc * 64 + n * 16 + lr - 4096;
                ushort4v wh4, wl4;
                #pragma unroll
                for (int r = 0; r < 4; r++) {
                    const float v = acc[m][n][r];
                    uint32 rr = rnebits(v);
                    wh4[r] = (unsigned short)(rr >> 16);
                    wl4[r] = f2bf(v - __uint_as_float(rr & 0xffff0000u));
                }
                *(ushort4v*)(Vh + (size_t)vcol * (size_t)CT + (m0 + rb)) = wh4;
                *(ushort4v*)(Vl + (size_t)vcol * (size_t)CT + (m0 + rb)) = wl4;
            }
        }
        return;
    }
    #pragma unroll
    for (int m = 0; m < 4; m++) {
        const int rb = wr * 64 + m * 16 + lg * 4;
        #pragma unroll
        for (int n = 0; n < 4; n++) {
            const int ccol = nt * 128 + wc * 64 + n * 16 + lr;
            #pragma unroll
            for (int r = 0; r < 4; r++) {
                const size_t idx = (size_t)(m0 + rb + r) * ldc + ccol;
                if (MODE == 1) {
                    const float v = acc[m][n][r] + resid[idx];
                    Cf[idx] = v;
                    C2[idx] = v;
                } else {
                    const float v = acc[m][n][r];
                    uint32 rr = rnebits(v);
                    Ch[idx] = (unsigned short)(rr >> 16);
                    Cl[idx] = f2bf(v - __uint_as_float(rr & 0xffff0000u));
                }
            }
        }
    }
}

// ---------------- MoE GEMM, gl16 + LDS double-buffer ----
template<int MODE>
__global__ __launch_bounds__(256) void gemm_k(
    const unsigned short* __restrict__ A, int lda,
    const unsigned short* __restrict__ Bt, int K, int Ne,
    void* __restrict__ Cp, int ldc,
    const int* __restrict__ cnt, const int* __restrict__ tokl,
    const float* __restrict__ gatel, const int* __restrict__ pb) {
    __shared__ unsigned short SS[2][2][128 * 32];
    const int nt = blockIdx.x, mt = blockIdx.y, e = blockIdx.z;
    const int m0 = mt * 128;
    const int c = cnt[e];
    if (m0 >= c) return;
    const int valid = (c - m0 < 128) ? (c - m0) : 128;
    const int tid = threadIdx.x;
    const int wave = tid >> 6, lane = tid & 63;
    const int lr = lane & 15;
    const int wr = (tid >> 7) & 1, wc = (tid >> 6) & 1;
    const int sr = lane >> 2, sc = (lane & 3) * 8;
    const int r0 = wave * 32;
    const int lofs = r0 * 32;
    size_t gr0, gr1;
    {
        int ra = r0 + sr, rb2 = r0 + 16 + sr;
        if (MODE == 2) {
            ra = ra < valid ? ra : valid - 1;
            rb2 = rb2 < valid ? rb2 : valid - 1;
            gr0 = (size_t)tokl[e * 4096 + m0 + ra];
            gr1 = (size_t)tokl[e * 4096 + m0 + rb2];
        } else {
            int x0 = m0 + ra, x1 = m0 + rb2;
            gr0 = (size_t)(pb[e] + (x0 < c ? x0 : c - 1));
            gr1 = (size_t)(pb[e] + (x1 < c ? x1 : c - 1));
        }
    }
    const unsigned short* gA0 = A + gr0 * (size_t)lda + sc;
    const unsigned short* gA1 = A + gr1 * (size_t)lda + sc;
    const unsigned short* gB = Bt + (size_t)e * Ne * K + (size_t)(nt * 128 + r0 + sr) * K + sc;
    const size_t rstepB = (size_t)16 * K;

    float4v acc[4][4];
    #pragma unroll
    for (int m = 0; m < 4; m++)
        #pragma unroll
        for (int n = 0; n < 4; n++) acc[m][n] = (float4v){0.f, 0.f, 0.f, 0.f};

    gl16(gA0, &SS[0][0][lofs]);           gl16(gA1, &SS[0][0][lofs + 512]);
    gl16(gB, &SS[0][1][lofs]);            gl16(gB + rstepB, &SS[0][1][lofs + 512]);
    __syncthreads();

    int cur = 0;
    for (int k0 = 0; k0 < K; k0 += 32) {
        if (k0 + 32 < K) {
            const int nb = cur ^ 1;
            const int kn = k0 + 32;
            gl16(gA0 + kn, &SS[nb][0][lofs]);          gl16(gA1 + kn, &SS[nb][0][lofs + 512]);
            gl16(gB + kn, &SS[nb][1][lofs]);           gl16(gB + kn + rstepB, &SS[nb][1][lofs + 512]);
        }
        const unsigned short* PA = SS[cur][0];
        const unsigned short* PB = SS[cur][1];
        short8 af[4], bf[4];
        const int lg = lane >> 4;
        #pragma unroll
        for (int m = 0; m < 4; m++) af[m] = *(const short8*)(PA + (wr * 64 + m * 16 + lr) * 32 + lg * 8);
        #pragma unroll
        for (int n = 0; n < 4; n++) bf[n] = *(const short8*)(PB + (wc * 64 + n * 16 + lr) * 32 + lg * 8);
        #pragma unroll
        for (int n = 0; n < 4; n++)
            #pragma unroll
            for (int m = 0; m < 4; m++)
                acc[m][n] = __builtin_amdgcn_mfma_f32_16x16x32_bf16(af[m], bf[n], acc[m][n], 0, 0, 0);
        __syncthreads();
        cur ^= 1;
    }

    #pragma unroll
    for (int m = 0; m < 4; m++) {
        const int rb = wr * 64 + m * 16 + (lane >> 4) * 4;
        #pragma unroll
        for (int n = 0; n < 4; n++) {
            const int col = nt * 128 + wc * 64 + n * 16 + lr;
            #pragma unroll
            for (int r = 0; r < 4; r++) {
                const int row = rb + r;
                const float v = acc[m][n][r];
                if (MODE == 2) {
                    const float other = __shfl_xor(v, 1);
                    if (!(lr & 1) && row < valid) {
                        const float g1 = v, g3 = other;
                        const float hsw = (g1 / (1.f + __expf(-g1))) * g3;
                        ((unsigned short*)Cp)[(size_t)(pb[e] + m0 + row) * ldc + (col >> 1)] = f2bf(hsw);
                    }
                } else {
                    if (row < valid) {
                        const int t = tokl[e * 4096 + m0 + row];
                        const float g = gatel[e * 4096 + m0 + row];
                        atomicAdd(((float*)Cp) + (size_t)t * ldc + col, v * g);
                    }
                }
            }
        }
    }
}

// ---------------- flash attention: XCD-pinned, single-barrier dbuf, gl16 V ----
__global__ __launch_bounds__(256) void attn_k(const unsigned short* __restrict__ qkh,
                                              const unsigned short* __restrict__ qkl,
                                              const unsigned short* __restrict__ vth,
                                              const unsigned short* __restrict__ vtl,
                                              unsigned short* __restrict__ ch,
                                              unsigned short* __restrict__ cl) {
    __shared__ unsigned short Kb[2][2][32][136];
    __shared__ unsigned short Vb[2][2][128 * 32];
    const int bid = blockIdx.x;          // 1024 blocks
    const int xcd = bid & 7, jj = bid >> 3;
    const int bh  = xcd * 4 + (jj >> 5);
    const int qb  = 31 - (jj & 31);
    const int h   = bh & 15, b = bh >> 4;
    const int tid = threadIdx.x;
    const int wave = tid >> 6, lane = tid & 63, lr = lane & 15, lg = lane >> 4;
    const size_t tb = (size_t)b * CS;
    const int q0 = qb * 64 + wave * 16;

    short8 qfh[4], qfl[4];
    {
        const size_t off = (tb + q0 + lr) * CQK + h * CHD;
        #pragma unroll
        for (int c = 0; c < 4; c++) {
            qfh[c] = *(const short8*)(qkh + off + c * 32 + lg * 8);
            qfl[c] = *(const short8*)(qkl + off + c * 32 + lg * 8);
        }
    }
    float4v o[8];
    #pragma unroll
    for (int d = 0; d < 8; d++) o[d] = (float4v){0.f, 0.f, 0.f, 0.f};
    float m = -1e30f, l = 0.f;
    const float scl = 0.08838834764831845f;
    const int ntiles = 2 * (qb + 1);
    const int kk = tid >> 3, slot = tid & 7;

    // K reg staging (row kk, 16 shorts at slot*16) / V gl16 staging geometry
    short8 kh0, kh1, kl0, kl1;
    const size_t vrow = (size_t)(h * 128 + wave * 32 + (lane >> 2));
    const unsigned short* gV0 = vth + vrow * (size_t)CT + tb + (lane & 3) * 8;
    const unsigned short* gV1 = vtl + vrow * (size_t)CT + tb + (lane & 3) * 8;

    #define LOADK(KV0) { \
        const size_t koff = (tb + (KV0) + kk) * CQK + CH + h * CHD + slot * 16; \
        kh0 = *(const short8*)(qkh + koff);     kh1 = *(const short8*)(qkh + koff + 8); \
        kl0 = *(const short8*)(qkl + koff);     kl1 = *(const short8*)(qkl + koff + 8); }
    #define WRITEK(BUF) { \
        *(short8*)(&Kb[BUF][0][kk][slot * 16])     = kh0; \
        *(short8*)(&Kb[BUF][0][kk][slot * 16 + 8]) = kh1; \
        *(short8*)(&Kb[BUF][1][kk][slot * 16])     = kl0; \
        *(short8*)(&Kb[BUF][1][kk][slot * 16 + 8]) = kl1; }
    #define ISSUEV(BUF, KV0) { \
        gl16(gV0 + (KV0), &Vb[BUF][0][wave * 32 * 32]); \
        gl16(gV0 + (KV0) + (size_t)16 * CT, &Vb[BUF][0][wave * 32 * 32 + 512]); \
        gl16(gV1 + (KV0), &Vb[BUF][1][wave * 32 * 32]); \
        gl16(gV1 + (KV0) + (size_t)16 * CT, &Vb[BUF][1][wave * 32 * 32 + 512]); }

    LOADK(0);
    WRITEK(0);
    ISSUEV(0, 0);
    LOADK(32);
    __syncthreads();

    int cur = 0;
    for (int kt = 0; kt < ntiles; ++kt) {
        const int kv0 = kt * 32;
        if (kt + 1 < ntiles) {
            WRITEK(cur ^ 1);
            ISSUEV(cur ^ 1, kv0 + 32);
        }
        if (kt + 2 < ntiles) LOADK(kv0 + 64);

        const unsigned short* KH = &Kb[cur][0][0][0];
        const unsigned short* KL = &Kb[cur][1][0][0];
        const unsigned short* VH = Vb[cur][0];
        const unsigned short* VL = Vb[cur][1];

        float4v st0 = (float4v){0.f,0.f,0.f,0.f}, st1 = st0;
        #pragma unroll
        for (int c = 0; c < 4; c++) {
            short8 kah = *(const short8*)(KH + lr * 136 + c * 32 + lg * 8);
            short8 kal = *(const short8*)(KL + lr * 136 + c * 32 + lg * 8);
            short8 kbh = *(const short8*)(KH + (16 + lr) * 136 + c * 32 + lg * 8);
            short8 kbl = *(const short8*)(KL + (16 + lr) * 136 + c * 32 + lg * 8);
            st0 = __builtin_amdgcn_mfma_f32_16x16x32_bf16(kal, qfh[c], st0, 0, 0, 0);
            st0 = __builtin_amdgcn_mfma_f32_16x16x32_bf16(kah, qfl[c], st0, 0, 0, 0);
            st0 = __builtin_amdgcn_mfma_f32_16x16x32_bf16(kah, qfh[c], st0, 0, 0, 0);
            st1 = __builtin_amdgcn_mfma_f32_16x16x32_bf16(kbl, qfh[c], st1, 0, 0, 0);
            st1 = __builtin_amdgcn_mfma_f32_16x16x32_bf16(kbh, qfl[c], st1, 0, 0, 0);
            st1 = __builtin_amdgcn_mfma_f32_16x16x32_bf16(kbh, qfh[c], st1, 0, 0, 0);
        }
        float pv[8]; float pmax = -1e30f;
        const int qg = q0 + lr;
        #pragma unroll
        for (int f = 0; f < 2; f++) {
            #pragma unroll
            for (int r = 0; r < 4; r++) {
                const int kg = kv0 + f * 16 + lg * 4 + r;
                const float s = (kg <= qg) ? ((f ? st1[r] : st0[r]) * scl) : -1e30f;
                pv[f * 4 + r] = s;
                pmax = fmaxf(pmax, s);
            }
        }
        pmax = fmaxf(pmax, __shfl_xor(pmax, 16));
        pmax = fmaxf(pmax, __shfl_xor(pmax, 32));
        if (!__all(pmax <= m)) {
            const float mnew = fmaxf(m, pmax);
            const float alpha = __expf(m - mnew);
            l *= alpha;
            #pragma unroll
            for (int d = 0; d < 8; d++) o[d] *= alpha;
            m = mnew;
        }
        float sum = 0.f;
        #pragma unroll
        for (int i = 0; i < 8; i++) { const float p = __expf(pv[i] - m); pv[i] = p; sum += p; }
        sum += __shfl_xor(sum, 16);
        sum += __shfl_xor(sum, 32);
        l += sum;
        short8 pfh, pfl;
        unsigned short* pfhp = (unsigned short*)&pfh;
        unsigned short* pflp = (unsigned short*)&pfl;
        #pragma unroll
        for (int j = 0; j < 8; j++) {
            const int srcl = (((lg & 1) * 2 + (j >> 2)) << 4) | lr;
            const float a0 = __shfl(pv[j & 3], srcl);
            const float a1 = __shfl(pv[4 + (j & 3)], srcl);
            const float sel = (lg >= 2) ? a1 : a0;
            uint32 r = rnebits(sel);
            pfhp[j] = (unsigned short)(r >> 16);
            float d = sel - __uint_as_float(r & 0xffff0000u);
            pflp[j] = (unsigned short)(rnebits(d) >> 16);
        }
        #pragma unroll
        for (int dt = 0; dt < 8; dt++) {
            short8 vh = *(const short8*)(VH + (dt * 16 + lr) * 32 + lg * 8);
            short8 vl = *(const short8*)(VL + (dt * 16 + lr) * 32 + lg * 8);
            o[dt] = __builtin_amdgcn_mfma_f32_16x16x32_bf16(vl, pfh, o[dt], 0, 0, 0);
            o[dt] = __builtin_amdgcn_mfma_f32_16x16x32_bf16(vh, pfl, o[dt], 0, 0, 0);
            o[dt] = __builtin_amdgcn_mfma_f32_16x16x32_bf16(vh, pfh, o[dt], 0, 0, 0);
        }
        __syncthreads();
        cur ^= 1;
    }
    #undef LOADK
    #undef WRITEK
    #undef ISSUEV
    const float inv = 1.f / l;
    const size_t coff = (tb + q0 + lr) * CH + h * CHD + lg * 4;
    #pragma unroll
    for (int dt = 0; dt < 8; dt++) {
        ushort4v wh, wl;
        #pragma unroll
        for (int r = 0; r < 4; r++) {
            const float v = o[dt][r] * inv;
            uint32 rr = rnebits(v);
            wh[r] = (unsigned short)(rr >> 16);
            wl[r] = f2bf(v - __uint_as_float(rr & 0xffff0000u));
        }
        *(ushort4v*)(ch + coff + dt * 16) = wh;
        *(ushort4v*)(cl + coff + dt * 16) = wl;
    }
}

__global__ void prefix_k(const int* __restrict__ cnt, int* __restrict__ pb) {
    if (threadIdx.x == 0 && blockIdx.x == 0) {
        int s = 0;
        for (int e = 0; e < CE; e++) { pb[e] = s; s += cnt[e]; }
    }
}

// ---------------- launch ----------------
extern "C" void kernel_launch(void* const* d_in, const int* in_sizes, int n_in,
                              void* d_out, int out_size, void* d_ws, size_t ws_size,
                              hipStream_t stream) {
    (void)in_sizes; (void)n_in; (void)out_size; (void)ws_size;
    const float* hidden = (const float*)d_in[0];
    const int*   posids = (const int*)d_in[1];
    const float* rms1w  = (const float*)d_in[2];
    const float* rms2w  = (const float*)d_in[3];
    const float* qw     = (const float*)d_in[4];
    const float* kw     = (const float*)d_in[5];
    const float* vw     = (const float*)d_in[6];
    const float* ow     = (const float*)d_in[7];
    const float* rw     = (const float*)d_in[8];
    const float* w1     = (const float*)d_in[9];
    const float* w2     = (const float*)d_in[10];
    const float* w3     = (const float*)d_in[11];
    float* out = (float*)d_out;

    char* ws = (char*)d_ws;
    unsigned short* h1h = (unsigned short*)ws;
    unsigned short* h1l = (unsigned short*)(ws + 16777216);
    unsigned short* woh = (unsigned short*)ws;
    unsigned short* wol = (unsigned short*)(ws + 8388608);
    unsigned short* h2  = (unsigned short*)ws;
    int*   tok  = (int*)(ws + 16777216);
    float* gate = (float*)(ws + 16777216 + 131072);
    int*   cnt  = (int*)(ws + 16777216 + 262144);
    int*   pb   = cnt + 16;
    // [33.6M,134.2M): qkh(32M) qkl(32M) vth(16M) vtl(16M)  -> later wt13/wt2
    unsigned short* qkh = (unsigned short*)(ws + 33554432);
    unsigned short* qkl = (unsigned short*)(ws + 67108864);
    unsigned short* vth = (unsigned short*)(ws + 100663296);
    unsigned short* vtl = (unsigned short*)(ws + 117440512);
    unsigned short* wt13 = (unsigned short*)(ws + 33554432);
    unsigned short* wt2  = (unsigned short*)(ws + 33554432);
    unsigned short* wqkvh = (unsigned short*)(ws + 134217728);
    unsigned short* wqkvl = (unsigned short*)(ws + 134217728 + 25165824);
    unsigned short* ctxh = (unsigned short*)(ws + 134217728);
    unsigned short* ctxl = (unsigned short*)(ws + 150994944);
    float*          res2 = (float*)(ws + 167772160);
    unsigned short* Hbuf = (unsigned short*)(ws + 167772160);
    float2*         rtab = (float2*)(ws + 201326592);

    rope_tab_k<<<512, 256, 0, stream>>>(rtab);
    rmsnorm_k<<<CT, 256, 0, stream>>>(hidden, rms1w, h1h, h1l);
    convs_k<3><<<dim3(32, 32, 3), 256, 0, stream>>>(qw, kw, vw, wqkvh, wqkvl);
    sgemm_k<0><<<dim3(32, 48), 256, 0, stream>>>(h1h, h1l, CH, wqkvh, wqkvl, CH,
                                                 qkh, qkl, nullptr, CQK, nullptr, nullptr,
                                                 vth, vtl);
    rope_k<<<2048, 256, 0, stream>>>(qkh, qkl, posids, rtab);
    convs_k<1><<<dim3(32, 32, 1), 256, 0, stream>>>(ow, nullptr, nullptr, woh, wol);
    attn_k<<<1024, 256, 0, stream>>>(qkh, qkl, vth, vtl, ctxh, ctxl);
    sgemm_k<1><<<dim3(32, 16), 256, 0, stream>>>(ctxh, ctxl, CH, woh, wol, CH,
                                                 nullptr, nullptr, res2, CH, hidden, out,
                                                 nullptr, nullptr);
    hipMemsetAsync(cnt, 0, 8 * sizeof(int), stream);
    rmsrouter_k<<<CT, 256, 0, stream>>>(res2, rms2w, rw, h2, cnt, tok, gate);
    prefix_k<<<1, 64, 0, stream>>>(cnt, pb);
    conv_k<2><<<dim3(32, 32, CE), 256, 0, stream>>>(w1, w3, wt13);
    gemm_k<2><<<dim3(32, 32, CE), 256, 0, stream>>>(h2, CH, wt13, CH, 2 * CI, Hbuf, CI,
                                                    cnt, tok, gate, pb);
    conv_k<1><<<dim3(32, 32, CE), 256, 0, stream>>>(w2, nullptr, wt2);
    gemm_k<3><<<dim3(16, 32, CE), 256, 0, stream>>>(Hbuf, CI, wt2, CI, CH, out, CH,
                                                    cnt, tok, gate, pb);
}